// Round 5
// baseline (583.938 us; speedup 1.0000x reference)
//
#include <hip/hip_runtime.h>
#include <cstddef>
#include <cstdint>

#define NM  50000
#define HID 160
#define NEI 8
#define AST 168   // LDS row stride (ushorts): 336B rows, conflict-benign b128 reads
#define FTM 32    // fused_iter row tile

// packed-weight offsets (ushort units)
#define WPX_HI    0        // [30nt][5ks][64l][8] x-proj weights (Wzx, Wr, Whx)
#define WPX_LO    76800
#define WPU_BASE  153600   // Ur   hi, lo at +25600
#define WPZH_BASE 204800   // Wzh  hi, lo at +25600
#define WPHH_BASE 256000   // Whh  hi, lo at +25600

typedef __attribute__((ext_vector_type(8))) short  short8;
typedef __attribute__((ext_vector_type(4))) float  f32x4;

__device__ __forceinline__ ushort f2bf(float f) {
    union { float f; uint32_t u; } v; v.f = f;
    const uint32_t r = v.u + 0x7fffu + ((v.u >> 16) & 1u);   // RNE
    return (ushort)(r >> 16);
}
__device__ __forceinline__ float bf2f(ushort h) {
    union { uint32_t u; float f; } v; v.u = ((uint32_t)h) << 16;
    return v.f;
}
__device__ __forceinline__ float sigf(float v)     { return 1.f / (1.f + __expf(-v)); }
__device__ __forceinline__ float tanhfast(float v) { return 2.f / (1.f + __expf(-2.f * v)) - 1.f; }

// ---------------- weight pre-pack into MFMA B-fragment-linear order (hi/lo bf16)
__global__ __launch_bounds__(256) void pack_weights(
    const float* __restrict__ Wz, const float* __restrict__ Wr,
    const float* __restrict__ Ur, const float* __restrict__ Wh,
    ushort* __restrict__ dst)
{
    const float* src; int off, stride, ntb = 0; ushort *hi, *lo;
    switch (blockIdx.x) {
        case 0:  src = Wz; off = 0;   stride = 320; hi = dst + WPX_HI;    lo = dst + WPX_LO;  ntb = 0;  break;
        case 1:  src = Wr; off = 0;   stride = 160; hi = dst + WPX_HI;    lo = dst + WPX_LO;  ntb = 10; break;
        case 2:  src = Wh; off = 0;   stride = 320; hi = dst + WPX_HI;    lo = dst + WPX_LO;  ntb = 20; break;
        case 3:  src = Ur; off = 0;   stride = 160; hi = dst + WPU_BASE;  lo = hi + 25600;    break;
        case 4:  src = Wz; off = 160; stride = 320; hi = dst + WPZH_BASE; lo = hi + 25600;    break;
        default: src = Wh; off = 160; stride = 320; hi = dst + WPHH_BASE; lo = hi + 25600;    break;
    }
    const int t = threadIdx.x, l = t & 63;
    for (int tile = t >> 6; tile < 50; tile += 4) {
        const int ntl = tile / 5, ks = tile % 5;
        const int n = ntl * 16 + (l & 15);
        const int k = ks * 32 + (l >> 4) * 8;
        const float* s = &src[(size_t)n * stride + off + k];
        const size_t o = ((size_t)((ntb + ntl) * 5 + ks) * 64 + l) * 8;
        #pragma unroll
        for (int j = 0; j < 8; ++j) {
            const float a  = s[j];
            const ushort hb = f2bf(a);
            hi[o + j] = hb;
            lo[o + j] = f2bf(a - bf2f(hb));
        }
    }
}

// ---------------- x projections, grid (782,3): y picks {xz, xr, xh} chunk
__global__ __launch_bounds__(256) void xproj_gemm(
    const float* __restrict__ x, const ushort* __restrict__ wpack,
    const float* __restrict__ Wz_b, const float* __restrict__ Wh_b,
    ushort* __restrict__ xproj, int M)
{
    __shared__ ushort As[64 * AST];
    const int t = threadIdx.x, m0 = blockIdx.x * 64, cy = blockIdx.y;

    for (int idx = t; idx < 64 * 40; idx += 256) {
        const int m = idx / 40, k4 = (idx % 40) * 4;
        float4 v = make_float4(0.f, 0.f, 0.f, 0.f);
        if (m0 + m < M) v = *reinterpret_cast<const float4*>(&x[(size_t)(m0 + m) * HID + k4]);
        ushort4 hv;
        hv.x = f2bf(v.x); hv.y = f2bf(v.y); hv.z = f2bf(v.z); hv.w = f2bf(v.w);
        *reinterpret_cast<ushort4*>(&As[m * AST + k4]) = hv;
    }
    __syncthreads();

    const int w = t >> 6, l = t & 63;
    const int ar = (w << 4) + (l & 15);
    const int kg = (l >> 4) << 3;

    f32x4 acc[10];
    #pragma unroll
    for (int nt = 0; nt < 10; ++nt) acc[nt] = (f32x4){0.f, 0.f, 0.f, 0.f};

    const short8* WH = reinterpret_cast<const short8*>(wpack + WPX_HI + cy * 25600);
    const short8* WL = reinterpret_cast<const short8*>(wpack + WPX_LO + cy * 25600);

    #pragma unroll
    for (int ks = 0; ks < 5; ++ks) {
        const short8 a = *reinterpret_cast<const short8*>(&As[ar * AST + ks * 32 + kg]);
        #pragma unroll
        for (int nt = 0; nt < 10; ++nt) {
            const short8 bh = WH[(nt * 5 + ks) * 64 + l];
            const short8 bl = WL[(nt * 5 + ks) * 64 + l];
            acc[nt] = __builtin_amdgcn_mfma_f32_16x16x32_bf16(a, bh, acc[nt], 0, 0, 0);
            acc[nt] = __builtin_amdgcn_mfma_f32_16x16x32_bf16(a, bl, acc[nt], 0, 0, 0);
        }
    }
    __syncthreads();

    const int r0l = (w << 4) + ((l >> 4) << 2);
    const int cb = l & 15;
    const float* bias = (cy == 0) ? Wz_b : (cy == 2) ? Wh_b : nullptr;
    #pragma unroll
    for (int nt = 0; nt < 10; ++nt) {
        const int col = nt * 16 + cb;
        const float b = bias ? bias[col] : 0.f;
        #pragma unroll
        for (int r = 0; r < 4; ++r)
            As[(r0l + r) * AST + col] = f2bf(acc[nt][r] + b);
    }
    __syncthreads();
    for (int idx = t; idx < 64 * 20; idx += 256) {
        const int m = idx / 20, g8 = (idx % 20) * 8;
        if (m0 + m < M)
            *reinterpret_cast<short8*>(&xproj[(size_t)(m0 + m) * 480 + cy * 160 + g8]) =
                *reinterpret_cast<const short8*>(&As[m * AST + g8]);
    }
}

// ---------------- hU0: hh[n] = [bf16(h0) | bf16(h0 @ Ur^T + Ur_b)]
__global__ __launch_bounds__(256, 3) void hU0_gemm(
    const float* __restrict__ h0, const ushort* __restrict__ wpack,
    const float* __restrict__ Ur_b, ushort* __restrict__ hh, int M)
{
    __shared__ ushort As[64 * AST];
    __shared__ ushort Hu[64 * AST];
    const int t = threadIdx.x, m0 = blockIdx.x * 64;

    for (int idx = t; idx < 64 * 40; idx += 256) {
        const int m = idx / 40, k4 = (idx % 40) * 4;
        float4 v = make_float4(0.f, 0.f, 0.f, 0.f);
        if (m0 + m < M) v = *reinterpret_cast<const float4*>(&h0[(size_t)(m0 + m) * HID + k4]);
        ushort4 hv;
        hv.x = f2bf(v.x); hv.y = f2bf(v.y); hv.z = f2bf(v.z); hv.w = f2bf(v.w);
        *reinterpret_cast<ushort4*>(&As[m * AST + k4]) = hv;
    }
    __syncthreads();

    for (int idx = t; idx < 64 * 20; idx += 256) {
        const int m = idx / 20, g8 = (idx % 20) * 8;
        if (m0 + m < M)
            *reinterpret_cast<short8*>(&hh[(size_t)(m0 + m) * 320 + g8]) =
                *reinterpret_cast<const short8*>(&As[m * AST + g8]);
    }

    const int w = t >> 6, l = t & 63;
    const int ar = (w << 4) + (l & 15);
    const int kg = (l >> 4) << 3;

    f32x4 acc[10];
    #pragma unroll
    for (int nt = 0; nt < 10; ++nt) acc[nt] = (f32x4){0.f, 0.f, 0.f, 0.f};

    const short8* WH = reinterpret_cast<const short8*>(wpack + WPU_BASE);
    const short8* WL = reinterpret_cast<const short8*>(wpack + WPU_BASE + 25600);

    #pragma unroll
    for (int ks = 0; ks < 5; ++ks) {
        const short8 a = *reinterpret_cast<const short8*>(&As[ar * AST + ks * 32 + kg]);
        #pragma unroll
        for (int nt = 0; nt < 10; ++nt) {
            const short8 bh = WH[(nt * 5 + ks) * 64 + l];
            const short8 bl = WL[(nt * 5 + ks) * 64 + l];
            acc[nt] = __builtin_amdgcn_mfma_f32_16x16x32_bf16(a, bh, acc[nt], 0, 0, 0);
            acc[nt] = __builtin_amdgcn_mfma_f32_16x16x32_bf16(a, bl, acc[nt], 0, 0, 0);
        }
    }

    const int r0l = (w << 4) + ((l >> 4) << 2);
    const int cb = l & 15;
    #pragma unroll
    for (int nt = 0; nt < 10; ++nt) {
        const int col = nt * 16 + cb;
        const float b = Ur_b[col];
        #pragma unroll
        for (int r = 0; r < 4; ++r)
            Hu[(r0l + r) * AST + col] = f2bf(acc[nt][r] + b);
    }
    __syncthreads();
    for (int idx = t; idx < 64 * 20; idx += 256) {
        const int m = idx / 20, g8 = (idx % 20) * 8;
        if (m0 + m < M)
            *reinterpret_cast<short8*>(&hh[(size_t)(m0 + m) * 320 + 160 + g8]) =
                *reinterpret_cast<const short8*>(&Hu[m * AST + g8]);
    }
}

// ---------------- fused iteration: gather -> zh-GEMM -> update -> (Ur-GEMM for next)
// 32-row tiles, 22.5 KB LDS -> 6 blocks/CU (vs 64-row/45KB/3): latency-bound gather
// needs the waves, not the tile size.
__global__ __launch_bounds__(256, 6) void fused_iter(
    const ushort* __restrict__ hh,      // [N][320] bf16: h | hU
    const ushort* __restrict__ xproj,   // [N][480] bf16: xz | xr | xh
    const int*    __restrict__ graph,
    const ushort* __restrict__ wpack,
    const float*  __restrict__ Ur_b,
    float*  __restrict__ out,           // [N][160] f32
    ushort* __restrict__ hh_next,       // [N][320] bf16 (ping-pong, != hh)
    int do_next, int M)
{
    __shared__ ushort Az[FTM * AST];    // bf16 sumh, later bf16 h_out
    __shared__ ushort Ag[FTM * AST];    // bf16 sgh,  later bf16 hU_out
    __shared__ int    gl[FTM][NEI];
    const int t = threadIdx.x, m0 = blockIdx.x * FTM;

    {   // FTM*NEI == 256: one load per thread
        const int r = t >> 3, k = t & 7;
        gl[r][k] = (m0 + r < M) ? graph[(size_t)(m0 + r) * NEI + k] : 0;
    }
    __syncthreads();

    // gather phase: 32 rows x 20 groups of 8 elems = 640 tasks
    for (int idx = t; idx < FTM * 20; idx += 256) {
        const int r = idx / 20, g8 = (idx % 20) * 8;
        const int n = m0 + r;
        float s[8], g[8];
        #pragma unroll
        for (int j = 0; j < 8; ++j) { s[j] = 0.f; g[j] = 0.f; }
        if (n < M) {
            const short8 xr8 = *reinterpret_cast<const short8*>(&xproj[(size_t)n * 480 + 160 + g8]);
            #pragma unroll
            for (int k = 0; k < NEI; ++k) {
                const int gg = gl[r][k];
                const short8 hv = *reinterpret_cast<const short8*>(&hh[(size_t)gg * 320 + g8]);
                const short8 hu = *reinterpret_cast<const short8*>(&hh[(size_t)gg * 320 + 160 + g8]);
                #pragma unroll
                for (int j = 0; j < 8; ++j) {
                    const float h = bf2f((ushort)hv[j]);
                    const float rg = sigf(bf2f((ushort)xr8[j]) + bf2f((ushort)hu[j]));
                    s[j] += h;
                    g[j] = fmaf(rg, h, g[j]);
                }
            }
        }
        short8 sv, gv;
        #pragma unroll
        for (int j = 0; j < 8; ++j) { sv[j] = (short)f2bf(s[j]); gv[j] = (short)f2bf(g[j]); }
        *reinterpret_cast<short8*>(&Az[r * AST + g8]) = sv;
        *reinterpret_cast<short8*>(&Ag[r * AST + g8]) = gv;
    }
    __syncthreads();

    const int w = t >> 6, l = t & 63;
    const int wrow = w & 1, wcol = w >> 1;          // wave -> 16 rows x 80 cols
    const int ar = wrow * 16 + (l & 15);
    const int kg = (l >> 4) << 3;

    f32x4 accz[5], acch[5];
    #pragma unroll
    for (int nt = 0; nt < 5; ++nt) {
        accz[nt] = (f32x4){0.f, 0.f, 0.f, 0.f};
        acch[nt] = (f32x4){0.f, 0.f, 0.f, 0.f};
    }

    {
        const short8* ZH = reinterpret_cast<const short8*>(wpack + WPZH_BASE);
        const short8* ZL = reinterpret_cast<const short8*>(wpack + WPZH_BASE + 25600);
        const short8* HH = reinterpret_cast<const short8*>(wpack + WPHH_BASE);
        const short8* HL = reinterpret_cast<const short8*>(wpack + WPHH_BASE + 25600);
        #pragma unroll
        for (int ks = 0; ks < 5; ++ks) {
            const short8 az = *reinterpret_cast<const short8*>(&Az[ar * AST + ks * 32 + kg]);
            const short8 ag = *reinterpret_cast<const short8*>(&Ag[ar * AST + ks * 32 + kg]);
            #pragma unroll
            for (int nt = 0; nt < 5; ++nt) {
                const int bi = (((wcol * 5 + nt) * 5 + ks) << 6) + l;
                accz[nt] = __builtin_amdgcn_mfma_f32_16x16x32_bf16(az, ZH[bi], accz[nt], 0, 0, 0);
                accz[nt] = __builtin_amdgcn_mfma_f32_16x16x32_bf16(az, ZL[bi], accz[nt], 0, 0, 0);
                acch[nt] = __builtin_amdgcn_mfma_f32_16x16x32_bf16(ag, HH[bi], acch[nt], 0, 0, 0);
                acch[nt] = __builtin_amdgcn_mfma_f32_16x16x32_bf16(ag, HL[bi], acch[nt], 0, 0, 0);
            }
        }
    }

    // epilogue: v = (1-z)*sumh + z*tanh(.)  (v kept in accz for the Ur tail)
    const int r0l = wrow * 16 + ((l >> 4) << 2);
    const int cb = l & 15;
    #pragma unroll
    for (int nt = 0; nt < 5; ++nt) {
        const int col = (wcol * 5 + nt) * 16 + cb;
        #pragma unroll
        for (int r = 0; r < 4; ++r) {
            const int m = m0 + r0l + r;
            float v = 0.f;
            if (m < M) {
                const float z = sigf(accz[nt][r] + bf2f(xproj[(size_t)m * 480 + col]));
                const float p = tanhfast(acch[nt][r] + bf2f(xproj[(size_t)m * 480 + 320 + col]));
                const float s = bf2f(Az[(r0l + r) * AST + col]);
                v = (1.f - z) * s + z * p;
                if (m == 0) v = 0.f;
                out[(size_t)m * HID + col] = v;
            }
            accz[nt][r] = v;
        }
    }

    if (!do_next) return;

    __syncthreads();   // all Az(sumh) reads done
    #pragma unroll
    for (int nt = 0; nt < 5; ++nt) {
        const int col = (wcol * 5 + nt) * 16 + cb;
        #pragma unroll
        for (int r = 0; r < 4; ++r)
            Az[(r0l + r) * AST + col] = f2bf(accz[nt][r]);   // bf16 h_out
    }
    __syncthreads();

    // coalesced h-half stores + Ur-GEMM from Az
    for (int idx = t; idx < FTM * 20; idx += 256) {
        const int m = idx / 20, g8 = (idx % 20) * 8;
        if (m0 + m < M)
            *reinterpret_cast<short8*>(&hh_next[(size_t)(m0 + m) * 320 + g8]) =
                *reinterpret_cast<const short8*>(&Az[m * AST + g8]);
    }

    #pragma unroll
    for (int nt = 0; nt < 5; ++nt) acch[nt] = (f32x4){0.f, 0.f, 0.f, 0.f};
    {
        const short8* WH = reinterpret_cast<const short8*>(wpack + WPU_BASE);
        const short8* WL = reinterpret_cast<const short8*>(wpack + WPU_BASE + 25600);
        #pragma unroll
        for (int ks = 0; ks < 5; ++ks) {
            const short8 a = *reinterpret_cast<const short8*>(&Az[ar * AST + ks * 32 + kg]);
            #pragma unroll
            for (int nt = 0; nt < 5; ++nt) {
                const int bi = (((wcol * 5 + nt) * 5 + ks) << 6) + l;
                acch[nt] = __builtin_amdgcn_mfma_f32_16x16x32_bf16(a, WH[bi], acch[nt], 0, 0, 0);
                acch[nt] = __builtin_amdgcn_mfma_f32_16x16x32_bf16(a, WL[bi], acch[nt], 0, 0, 0);
            }
        }
    }
    #pragma unroll
    for (int nt = 0; nt < 5; ++nt) {
        const int col = (wcol * 5 + nt) * 16 + cb;
        const float b = Ur_b[col];
        #pragma unroll
        for (int r = 0; r < 4; ++r)
            Ag[(r0l + r) * AST + col] = f2bf(acch[nt][r] + b);
    }
    __syncthreads();
    for (int idx = t; idx < FTM * 20; idx += 256) {
        const int m = idx / 20, g8 = (idx % 20) * 8;
        if (m0 + m < M)
            *reinterpret_cast<short8*>(&hh_next[(size_t)(m0 + m) * 320 + 160 + g8]) =
                *reinterpret_cast<const short8*>(&Ag[m * AST + g8]);
    }
}

extern "C" void kernel_launch(void* const* d_in, const int* in_sizes, int n_in,
                              void* d_out, int out_size, void* d_ws, size_t ws_size,
                              hipStream_t stream)
{
    const float* h0   = (const float*)d_in[0];
    const float* x    = (const float*)d_in[1];
    const int*   grf  = (const int*)  d_in[2];
    const float* Wz_w = (const float*)d_in[3];
    const float* Wz_b = (const float*)d_in[4];
    const float* Wr_w = (const float*)d_in[5];
    const float* Ur_w = (const float*)d_in[6];
    const float* Ur_b = (const float*)d_in[7];
    const float* Wh_w = (const float*)d_in[8];
    const float* Wh_b = (const float*)d_in[9];
    float* out = (float*)d_out;

    const size_t per = (size_t)NM * HID;
    ushort* xproj = (ushort*)d_ws;            // 48 MB
    ushort* hh_a  = xproj + per * 3;          // 32 MB
    ushort* hh_b  = hh_a + per * 2;           // 32 MB
    ushort* wpack = hh_b + per * 2;           // 0.6 MB

    const dim3 gb((NM + 63) / 64), gt(256);         // 782 blocks
    const dim3 fb((NM + FTM - 1) / FTM);            // 1563 blocks

    pack_weights<<<6, 256, 0, stream>>>(Wz_w, Wr_w, Ur_w, Wh_w, wpack);
    xproj_gemm<<<dim3(gb.x, 3), gt, 0, stream>>>(x, wpack, Wz_b, Wh_b, xproj, NM);
    hU0_gemm<<<gb, gt, 0, stream>>>(h0, wpack, Ur_b, hh_a, NM);

    fused_iter<<<fb, gt, 0, stream>>>(hh_a, xproj, grf, wpack, Ur_b, out, hh_b, 1, NM);
    fused_iter<<<fb, gt, 0, stream>>>(hh_b, xproj, grf, wpack, Ur_b, out, hh_a, 1, NM);
    fused_iter<<<fb, gt, 0, stream>>>(hh_a, xproj, grf, wpack, Ur_b, out, hh_b, 0, NM);
}

// Round 6
// 471.790 us; speedup vs baseline: 1.2377x; 1.2377x over previous
//
#include <hip/hip_runtime.h>
#include <hip/hip_fp16.h>
#include <cstddef>
#include <cstdint>

#define NM  50000
#define HID 160
#define NEI 8
#define AST 168     // LDS row stride (ushorts): 336B rows, conflict-benign b128 reads
#define HHROW 480   // hh row bytes: 320 B bf16 h | 160 B fp8(e5m2) hU

// packed-weight offsets (ushort units)
#define WPX_HI    0        // [30nt][5ks][64l][8] x-proj weights (Wzx, Wr, Whx)
#define WPX_LO    76800
#define WPU_BASE  153600   // Ur   hi, lo at +25600
#define WPZH_BASE 204800   // Wzh  hi, lo at +25600
#define WPHH_BASE 256000   // Whh  hi, lo at +25600

typedef __attribute__((ext_vector_type(8))) short  short8;
typedef __attribute__((ext_vector_type(4))) float  f32x4;

__device__ __forceinline__ ushort f2bf(float f) {
    union { float f; uint32_t u; } v; v.f = f;
    const uint32_t r = v.u + 0x7fffu + ((v.u >> 16) & 1u);   // RNE
    return (ushort)(r >> 16);
}
__device__ __forceinline__ float bf2f(ushort h) {
    union { uint32_t u; float f; } v; v.u = ((uint32_t)h) << 16;
    return v.f;
}
// fp8 e5m2 == truncated f16: encode f32->f16 (RNE) -> round mantissa to 2 bits
__device__ __forceinline__ uint32_t f2e5(float v) {
    union { __half h; ushort u; } c; c.h = __float2half(v);
    const ushort r = c.u + 0x7F + ((c.u >> 8) & 1);
    return (uint32_t)(r >> 8) & 0xFF;
}
__device__ __forceinline__ float e5m2f(uint32_t byte) {
    union { ushort u; __half h; } c; c.u = (ushort)(byte << 8);
    return __half2float(c.h);
}
__device__ __forceinline__ float sigf(float v)     { return 1.f / (1.f + __expf(-v)); }
__device__ __forceinline__ float tanhfast(float v) { return 2.f / (1.f + __expf(-2.f * v)) - 1.f; }

// ---------------- weight pre-pack into MFMA B-fragment-linear order (hi/lo bf16)
__global__ __launch_bounds__(256) void pack_weights(
    const float* __restrict__ Wz, const float* __restrict__ Wr,
    const float* __restrict__ Ur, const float* __restrict__ Wh,
    ushort* __restrict__ dst)
{
    const float* src; int off, stride, ntb = 0; ushort *hi, *lo;
    switch (blockIdx.x) {
        case 0:  src = Wz; off = 0;   stride = 320; hi = dst + WPX_HI;    lo = dst + WPX_LO;  ntb = 0;  break;
        case 1:  src = Wr; off = 0;   stride = 160; hi = dst + WPX_HI;    lo = dst + WPX_LO;  ntb = 10; break;
        case 2:  src = Wh; off = 0;   stride = 320; hi = dst + WPX_HI;    lo = dst + WPX_LO;  ntb = 20; break;
        case 3:  src = Ur; off = 0;   stride = 160; hi = dst + WPU_BASE;  lo = hi + 25600;    break;
        case 4:  src = Wz; off = 160; stride = 320; hi = dst + WPZH_BASE; lo = hi + 25600;    break;
        default: src = Wh; off = 160; stride = 320; hi = dst + WPHH_BASE; lo = hi + 25600;    break;
    }
    const int t = threadIdx.x, l = t & 63;
    for (int tile = t >> 6; tile < 50; tile += 4) {
        const int ntl = tile / 5, ks = tile % 5;
        const int n = ntl * 16 + (l & 15);
        const int k = ks * 32 + (l >> 4) * 8;
        const float* s = &src[(size_t)n * stride + off + k];
        const size_t o = ((size_t)((ntb + ntl) * 5 + ks) * 64 + l) * 8;
        #pragma unroll
        for (int j = 0; j < 8; ++j) {
            const float a  = s[j];
            const ushort hb = f2bf(a);
            hi[o + j] = hb;
            lo[o + j] = f2bf(a - bf2f(hb));
        }
    }
}

// ---------------- x projections, grid (782,3): y picks {xz, xr, xh} chunk
__global__ __launch_bounds__(256) void xproj_gemm(
    const float* __restrict__ x, const ushort* __restrict__ wpack,
    const float* __restrict__ Wz_b, const float* __restrict__ Wh_b,
    ushort* __restrict__ xproj, int M)
{
    __shared__ ushort As[64 * AST];
    const int t = threadIdx.x, m0 = blockIdx.x * 64, cy = blockIdx.y;

    for (int idx = t; idx < 64 * 40; idx += 256) {
        const int m = idx / 40, k4 = (idx % 40) * 4;
        float4 v = make_float4(0.f, 0.f, 0.f, 0.f);
        if (m0 + m < M) v = *reinterpret_cast<const float4*>(&x[(size_t)(m0 + m) * HID + k4]);
        ushort4 hv;
        hv.x = f2bf(v.x); hv.y = f2bf(v.y); hv.z = f2bf(v.z); hv.w = f2bf(v.w);
        *reinterpret_cast<ushort4*>(&As[m * AST + k4]) = hv;
    }
    __syncthreads();

    const int w = t >> 6, l = t & 63;
    const int ar = (w << 4) + (l & 15);
    const int kg = (l >> 4) << 3;

    f32x4 acc[10];
    #pragma unroll
    for (int nt = 0; nt < 10; ++nt) acc[nt] = (f32x4){0.f, 0.f, 0.f, 0.f};

    const short8* WH = reinterpret_cast<const short8*>(wpack + WPX_HI + cy * 25600);
    const short8* WL = reinterpret_cast<const short8*>(wpack + WPX_LO + cy * 25600);

    #pragma unroll
    for (int ks = 0; ks < 5; ++ks) {
        const short8 a = *reinterpret_cast<const short8*>(&As[ar * AST + ks * 32 + kg]);
        #pragma unroll
        for (int nt = 0; nt < 10; ++nt) {
            const short8 bh = WH[(nt * 5 + ks) * 64 + l];
            const short8 bl = WL[(nt * 5 + ks) * 64 + l];
            acc[nt] = __builtin_amdgcn_mfma_f32_16x16x32_bf16(a, bh, acc[nt], 0, 0, 0);
            acc[nt] = __builtin_amdgcn_mfma_f32_16x16x32_bf16(a, bl, acc[nt], 0, 0, 0);
        }
    }
    __syncthreads();

    const int r0l = (w << 4) + ((l >> 4) << 2);
    const int cb = l & 15;
    const float* bias = (cy == 0) ? Wz_b : (cy == 2) ? Wh_b : nullptr;
    #pragma unroll
    for (int nt = 0; nt < 10; ++nt) {
        const int col = nt * 16 + cb;
        const float b = bias ? bias[col] : 0.f;
        #pragma unroll
        for (int r = 0; r < 4; ++r)
            As[(r0l + r) * AST + col] = f2bf(acc[nt][r] + b);
    }
    __syncthreads();
    for (int idx = t; idx < 64 * 20; idx += 256) {
        const int m = idx / 20, g8 = (idx % 20) * 8;
        if (m0 + m < M)
            *reinterpret_cast<short8*>(&xproj[(size_t)(m0 + m) * 480 + cy * 160 + g8]) =
                *reinterpret_cast<const short8*>(&As[m * AST + g8]);
    }
}

// ---------------- hU0: hh[n] = [bf16(h0) | e5m2(h0 @ Ur^T + Ur_b)]
__global__ __launch_bounds__(256, 3) void hU0_gemm(
    const float* __restrict__ h0, const ushort* __restrict__ wpack,
    const float* __restrict__ Ur_b, uint8_t* __restrict__ hh, int M)
{
    __shared__ ushort As[64 * AST];
    __shared__ uint8_t HuB[64 * 160];
    const int t = threadIdx.x, m0 = blockIdx.x * 64;

    for (int idx = t; idx < 64 * 40; idx += 256) {
        const int m = idx / 40, k4 = (idx % 40) * 4;
        float4 v = make_float4(0.f, 0.f, 0.f, 0.f);
        if (m0 + m < M) v = *reinterpret_cast<const float4*>(&h0[(size_t)(m0 + m) * HID + k4]);
        ushort4 hv;
        hv.x = f2bf(v.x); hv.y = f2bf(v.y); hv.z = f2bf(v.z); hv.w = f2bf(v.w);
        *reinterpret_cast<ushort4*>(&As[m * AST + k4]) = hv;
    }
    __syncthreads();

    // coalesced h-half stores
    for (int idx = t; idx < 64 * 20; idx += 256) {
        const int m = idx / 20, g8 = (idx % 20) * 8;
        if (m0 + m < M)
            *reinterpret_cast<short8*>(hh + (size_t)(m0 + m) * HHROW + g8 * 2) =
                *reinterpret_cast<const short8*>(&As[m * AST + g8]);
    }

    const int w = t >> 6, l = t & 63;
    const int ar = (w << 4) + (l & 15);
    const int kg = (l >> 4) << 3;

    f32x4 acc[10];
    #pragma unroll
    for (int nt = 0; nt < 10; ++nt) acc[nt] = (f32x4){0.f, 0.f, 0.f, 0.f};

    const short8* WH = reinterpret_cast<const short8*>(wpack + WPU_BASE);
    const short8* WL = reinterpret_cast<const short8*>(wpack + WPU_BASE + 25600);

    #pragma unroll
    for (int ks = 0; ks < 5; ++ks) {
        const short8 a = *reinterpret_cast<const short8*>(&As[ar * AST + ks * 32 + kg]);
        #pragma unroll
        for (int nt = 0; nt < 10; ++nt) {
            const short8 bh = WH[(nt * 5 + ks) * 64 + l];
            const short8 bl = WL[(nt * 5 + ks) * 64 + l];
            acc[nt] = __builtin_amdgcn_mfma_f32_16x16x32_bf16(a, bh, acc[nt], 0, 0, 0);
            acc[nt] = __builtin_amdgcn_mfma_f32_16x16x32_bf16(a, bl, acc[nt], 0, 0, 0);
        }
    }

    const int r0l = (w << 4) + ((l >> 4) << 2);
    const int cb = l & 15;
    #pragma unroll
    for (int nt = 0; nt < 10; ++nt) {
        const int col = nt * 16 + cb;
        const float b = Ur_b[col];
        #pragma unroll
        for (int r = 0; r < 4; ++r)
            HuB[(r0l + r) * 160 + col] = (uint8_t)f2e5(acc[nt][r] + b);
    }
    __syncthreads();
    for (int idx = t; idx < 64 * 10; idx += 256) {
        const int m = idx / 10, g16 = (idx % 10) * 16;
        if (m0 + m < M)
            *reinterpret_cast<uint4*>(hh + (size_t)(m0 + m) * HHROW + 320 + g16) =
                *reinterpret_cast<const uint4*>(&HuB[m * 160 + g16]);
    }
}

// ---------------- fused iteration: gather -> zh-GEMM -> update -> (Ur-GEMM for next)
// 64-row tile (round-4 concurrency: gather is L2-locality-bound, not occupancy-bound).
__global__ __launch_bounds__(256, 3) void fused_iter(
    const uint8_t* __restrict__ hh,     // [N][480B]: bf16 h | e5m2 hU
    const ushort* __restrict__ xproj,   // [N][480] bf16: xz | xr | xh
    const int*    __restrict__ graph,
    const ushort* __restrict__ wpack,
    const float*  __restrict__ Ur_b,
    float*   __restrict__ out,          // [N][160] f32 (written only if write_out)
    uint8_t* __restrict__ hh_next,      // ping-pong, != hh
    int write_out, int do_next, int M)
{
    __shared__ ushort Az[64 * AST];     // bf16 sumh, later bf16 h_out
    __shared__ ushort Ag[64 * AST];     // bf16 sgh,  later fp8 hU_out (byte view)
    __shared__ int    gl[64][NEI];
    const int t = threadIdx.x, m0 = blockIdx.x * 64;

    for (int idx = t; idx < 64 * NEI; idx += 256) {
        const int r = idx >> 3, k = idx & 7;
        gl[r][k] = (m0 + r < M) ? graph[(size_t)(m0 + r) * NEI + k] : 0;
    }
    __syncthreads();

    // gather phase: 64 rows x 20 groups of 8 elems; all 16 loads per task
    // issued before any compute (MLP: batch the random 16B/8B reads).
    for (int idx = t; idx < 64 * 20; idx += 256) {
        const int r = idx / 20, g8 = (idx % 20) * 8;
        const int n = m0 + r;
        float s[8], g[8];
        #pragma unroll
        for (int j = 0; j < 8; ++j) { s[j] = 0.f; g[j] = 0.f; }
        if (n < M) {
            const short8 xr8 = *reinterpret_cast<const short8*>(&xproj[(size_t)n * 480 + 160 + g8]);
            short8 hv[NEI]; uint2 hu[NEI];
            #pragma unroll
            for (int k = 0; k < NEI; ++k) {
                const uint8_t* row = hh + (size_t)gl[r][k] * HHROW;
                hv[k] = *reinterpret_cast<const short8*>(row + g8 * 2);
                hu[k] = *reinterpret_cast<const uint2*>(row + 320 + g8);
            }
            #pragma unroll
            for (int k = 0; k < NEI; ++k) {
                #pragma unroll
                for (int j = 0; j < 8; ++j) {
                    const uint32_t hub = ((j < 4 ? hu[k].x >> (8 * j) : hu[k].y >> (8 * (j - 4))) & 0xFFu);
                    const float h = bf2f((ushort)hv[k][j]);
                    const float rg = sigf(bf2f((ushort)xr8[j]) + e5m2f(hub));
                    s[j] += h;
                    g[j] = fmaf(rg, h, g[j]);
                }
            }
        }
        short8 sv, gv;
        #pragma unroll
        for (int j = 0; j < 8; ++j) { sv[j] = (short)f2bf(s[j]); gv[j] = (short)f2bf(g[j]); }
        *reinterpret_cast<short8*>(&Az[r * AST + g8]) = sv;
        *reinterpret_cast<short8*>(&Ag[r * AST + g8]) = gv;
    }
    __syncthreads();

    const int w = t >> 6, l = t & 63;
    const int ar = (w << 4) + (l & 15);
    const int kg = (l >> 4) << 3;

    f32x4 accz[10], acch[10];
    #pragma unroll
    for (int nt = 0; nt < 10; ++nt) {
        accz[nt] = (f32x4){0.f, 0.f, 0.f, 0.f};
        acch[nt] = (f32x4){0.f, 0.f, 0.f, 0.f};
    }

    {
        const short8* ZH = reinterpret_cast<const short8*>(wpack + WPZH_BASE);
        const short8* ZL = reinterpret_cast<const short8*>(wpack + WPZH_BASE + 25600);
        const short8* HH = reinterpret_cast<const short8*>(wpack + WPHH_BASE);
        const short8* HL = reinterpret_cast<const short8*>(wpack + WPHH_BASE + 25600);
        #pragma unroll
        for (int ks = 0; ks < 5; ++ks) {
            const short8 az = *reinterpret_cast<const short8*>(&Az[ar * AST + ks * 32 + kg]);
            const short8 ag = *reinterpret_cast<const short8*>(&Ag[ar * AST + ks * 32 + kg]);
            #pragma unroll
            for (int nt = 0; nt < 10; ++nt) {
                const int bi = (nt * 5 + ks) * 64 + l;
                accz[nt] = __builtin_amdgcn_mfma_f32_16x16x32_bf16(az, ZH[bi], accz[nt], 0, 0, 0);
                accz[nt] = __builtin_amdgcn_mfma_f32_16x16x32_bf16(az, ZL[bi], accz[nt], 0, 0, 0);
                acch[nt] = __builtin_amdgcn_mfma_f32_16x16x32_bf16(ag, HH[bi], acch[nt], 0, 0, 0);
                acch[nt] = __builtin_amdgcn_mfma_f32_16x16x32_bf16(ag, HL[bi], acch[nt], 0, 0, 0);
            }
        }
    }

    // epilogue: v = (1-z)*sumh + z*tanh(.)  (v kept in accz for the Ur tail)
    const int r0l = (w << 4) + ((l >> 4) << 2);
    const int cb = l & 15;
    #pragma unroll
    for (int nt = 0; nt < 10; ++nt) {
        const int col = nt * 16 + cb;
        #pragma unroll
        for (int r = 0; r < 4; ++r) {
            const int m = m0 + r0l + r;
            float v = 0.f;
            if (m < M) {
                const float z = sigf(accz[nt][r] + bf2f(xproj[(size_t)m * 480 + col]));
                const float p = tanhfast(acch[nt][r] + bf2f(xproj[(size_t)m * 480 + 320 + col]));
                const float s = bf2f(Az[(r0l + r) * AST + col]);
                v = (1.f - z) * s + z * p;
                if (m == 0) v = 0.f;
                if (write_out) out[(size_t)m * HID + col] = v;
            }
            accz[nt][r] = v;
        }
    }

    if (!do_next) return;

    __syncthreads();   // all Az(sumh) reads done
    #pragma unroll
    for (int nt = 0; nt < 10; ++nt) {
        const int col = nt * 16 + cb;
        #pragma unroll
        for (int r = 0; r < 4; ++r)
            Az[(r0l + r) * AST + col] = f2bf(accz[nt][r]);   // bf16 h_out
    }
    __syncthreads();

    // coalesced h-half stores + Ur-GEMM from Az
    for (int idx = t; idx < 64 * 20; idx += 256) {
        const int m = idx / 20, g8 = (idx % 20) * 8;
        if (m0 + m < M)
            *reinterpret_cast<short8*>(hh_next + (size_t)(m0 + m) * HHROW + g8 * 2) =
                *reinterpret_cast<const short8*>(&Az[m * AST + g8]);
    }

    #pragma unroll
    for (int nt = 0; nt < 10; ++nt) acch[nt] = (f32x4){0.f, 0.f, 0.f, 0.f};
    {
        const short8* WH = reinterpret_cast<const short8*>(wpack + WPU_BASE);
        const short8* WL = reinterpret_cast<const short8*>(wpack + WPU_BASE + 25600);
        #pragma unroll
        for (int ks = 0; ks < 5; ++ks) {
            const short8 a = *reinterpret_cast<const short8*>(&Az[ar * AST + ks * 32 + kg]);
            #pragma unroll
            for (int nt = 0; nt < 10; ++nt) {
                const int bi = (nt * 5 + ks) * 64 + l;
                acch[nt] = __builtin_amdgcn_mfma_f32_16x16x32_bf16(a, WH[bi], acch[nt], 0, 0, 0);
                acch[nt] = __builtin_amdgcn_mfma_f32_16x16x32_bf16(a, WL[bi], acch[nt], 0, 0, 0);
            }
        }
    }
    __syncthreads();   // Ag MFMA reads done; reuse Ag as byte buffer
    uint8_t* Agb = reinterpret_cast<uint8_t*>(Ag);
    #pragma unroll
    for (int nt = 0; nt < 10; ++nt) {
        const int col = nt * 16 + cb;
        const float b = Ur_b[col];
        #pragma unroll
        for (int r = 0; r < 4; ++r)
            Agb[(r0l + r) * 160 + col] = (uint8_t)f2e5(acch[nt][r] + b);
    }
    __syncthreads();
    for (int idx = t; idx < 64 * 10; idx += 256) {
        const int m = idx / 10, g16 = (idx % 10) * 16;
        if (m0 + m < M)
            *reinterpret_cast<uint4*>(hh_next + (size_t)(m0 + m) * HHROW + 320 + g16) =
                *reinterpret_cast<const uint4*>(&Agb[m * 160 + g16]);
    }
}

extern "C" void kernel_launch(void* const* d_in, const int* in_sizes, int n_in,
                              void* d_out, int out_size, void* d_ws, size_t ws_size,
                              hipStream_t stream)
{
    const float* h0   = (const float*)d_in[0];
    const float* x    = (const float*)d_in[1];
    const int*   grf  = (const int*)  d_in[2];
    const float* Wz_w = (const float*)d_in[3];
    const float* Wz_b = (const float*)d_in[4];
    const float* Wr_w = (const float*)d_in[5];
    const float* Ur_w = (const float*)d_in[6];
    const float* Ur_b = (const float*)d_in[7];
    const float* Wh_w = (const float*)d_in[8];
    const float* Wh_b = (const float*)d_in[9];
    float* out = (float*)d_out;

    const size_t per = (size_t)NM * HID;
    ushort*  xproj = (ushort*)d_ws;                       // 48 MB
    uint8_t* hh_a  = (uint8_t*)(xproj + per * 3);         // 24 MB
    uint8_t* hh_b  = hh_a + (size_t)NM * HHROW;           // 24 MB
    ushort*  wpack = (ushort*)(hh_b + (size_t)NM * HHROW);// 0.6 MB

    const dim3 gb((NM + 63) / 64), gt(256);               // 782 blocks

    pack_weights<<<6, 256, 0, stream>>>(Wz_w, Wr_w, Ur_w, Wh_w, wpack);
    xproj_gemm<<<dim3(gb.x, 3), gt, 0, stream>>>(x, wpack, Wz_b, Wh_b, xproj, NM);
    hU0_gemm<<<gb, gt, 0, stream>>>(h0, wpack, Ur_b, hh_a, NM);

    fused_iter<<<gb, gt, 0, stream>>>(hh_a, xproj, grf, wpack, Ur_b, out, hh_b, 0, 1, NM);
    fused_iter<<<gb, gt, 0, stream>>>(hh_b, xproj, grf, wpack, Ur_b, out, hh_a, 0, 1, NM);
    fused_iter<<<gb, gt, 0, stream>>>(hh_a, xproj, grf, wpack, Ur_b, out, hh_b, 1, 0, NM);
}

// Round 7
// 398.622 us; speedup vs baseline: 1.4649x; 1.1836x over previous
//
#include <hip/hip_runtime.h>
#include <hip/hip_fp16.h>
#include <cstddef>
#include <cstdint>

#define NM  50000
#define HID 160
#define NEI 8
#define AST 168     // padded LDS row stride (xproj/hU0 kernels only)
#define HHROW 480   // hh row bytes: 320 B bf16 h | 160 B fp8(e5m2) hU

// packed-weight offsets (ushort units), bf16 hi-only
#define WPX   0        // [30nt][5ks][64l][8]: Wzx | Wr | Whx
#define WPU   76800    // Ur
#define WPZH  102400   // Wzh
#define WPHH  128000   // Whh

// fused_iter LDS swizzle: 16B-granule XOR within 32-ushort groups (20 slots = 16+4 -> closed)
#define SW(r, c) ((c) ^ (((r) & 3) << 3))

typedef __attribute__((ext_vector_type(8))) short  short8;
typedef __attribute__((ext_vector_type(4))) float  f32x4;

__device__ __forceinline__ ushort f2bf(float f) {
    union { float f; uint32_t u; } v; v.f = f;
    const uint32_t r = v.u + 0x7fffu + ((v.u >> 16) & 1u);   // RNE
    return (ushort)(r >> 16);
}
__device__ __forceinline__ float bf2f(ushort h) {
    union { uint32_t u; float f; } v; v.u = ((uint32_t)h) << 16;
    return v.f;
}
// fp8 e5m2 == truncated f16: encode f32->f16 (RNE) -> round mantissa to 2 bits
__device__ __forceinline__ uint32_t f2e5(float v) {
    union { __half h; ushort u; } c; c.h = __float2half(v);
    const ushort r = c.u + 0x7F + ((c.u >> 8) & 1);
    return (uint32_t)(r >> 8) & 0xFF;
}
__device__ __forceinline__ float e5m2f(uint32_t byte) {
    union { ushort u; __half h; } c; c.u = (ushort)(byte << 8);
    return __half2float(c.h);
}
__device__ __forceinline__ float sigf(float v)     { return 1.f / (1.f + __expf(-v)); }
__device__ __forceinline__ float tanhfast(float v) { return 2.f / (1.f + __expf(-2.f * v)) - 1.f; }

// ---------------- weight pre-pack into MFMA B-fragment-linear order (bf16 hi only)
__global__ __launch_bounds__(256) void pack_weights(
    const float* __restrict__ Wz, const float* __restrict__ Wr,
    const float* __restrict__ Ur, const float* __restrict__ Wh,
    ushort* __restrict__ dst)
{
    const float* src; int off, stride, ntb = 0; ushort* hi;
    switch (blockIdx.x) {
        case 0:  src = Wz; off = 0;   stride = 320; hi = dst + WPX;  ntb = 0;  break;
        case 1:  src = Wr; off = 0;   stride = 160; hi = dst + WPX;  ntb = 10; break;
        case 2:  src = Wh; off = 0;   stride = 320; hi = dst + WPX;  ntb = 20; break;
        case 3:  src = Ur; off = 0;   stride = 160; hi = dst + WPU;  break;
        case 4:  src = Wz; off = 160; stride = 320; hi = dst + WPZH; break;
        default: src = Wh; off = 160; stride = 320; hi = dst + WPHH; break;
    }
    const int t = threadIdx.x, l = t & 63;
    for (int tile = t >> 6; tile < 50; tile += 4) {
        const int ntl = tile / 5, ks = tile % 5;
        const int n = ntl * 16 + (l & 15);
        const int k = ks * 32 + (l >> 4) * 8;
        const float* s = &src[(size_t)n * stride + off + k];
        const size_t o = ((size_t)((ntb + ntl) * 5 + ks) * 64 + l) * 8;
        #pragma unroll
        for (int j = 0; j < 8; ++j) hi[o + j] = f2bf(s[j]);
    }
}

// ---------------- x projections, grid (782,3): y picks {xz, xr, xh} chunk
__global__ __launch_bounds__(256) void xproj_gemm(
    const float* __restrict__ x, const ushort* __restrict__ wpack,
    const float* __restrict__ Wz_b, const float* __restrict__ Wh_b,
    ushort* __restrict__ xproj, int M)
{
    __shared__ ushort As[64 * AST];
    const int t = threadIdx.x, m0 = blockIdx.x * 64, cy = blockIdx.y;

    for (int idx = t; idx < 64 * 40; idx += 256) {
        const int m = idx / 40, k4 = (idx % 40) * 4;
        float4 v = make_float4(0.f, 0.f, 0.f, 0.f);
        if (m0 + m < M) v = *reinterpret_cast<const float4*>(&x[(size_t)(m0 + m) * HID + k4]);
        ushort4 hv;
        hv.x = f2bf(v.x); hv.y = f2bf(v.y); hv.z = f2bf(v.z); hv.w = f2bf(v.w);
        *reinterpret_cast<ushort4*>(&As[m * AST + k4]) = hv;
    }
    __syncthreads();

    const int w = t >> 6, l = t & 63;
    const int ar = (w << 4) + (l & 15);
    const int kg = (l >> 4) << 3;

    f32x4 acc[10];
    #pragma unroll
    for (int nt = 0; nt < 10; ++nt) acc[nt] = (f32x4){0.f, 0.f, 0.f, 0.f};

    const short8* WH = reinterpret_cast<const short8*>(wpack + WPX + cy * 25600);

    #pragma unroll
    for (int ks = 0; ks < 5; ++ks) {
        const short8 a = *reinterpret_cast<const short8*>(&As[ar * AST + ks * 32 + kg]);
        #pragma unroll
        for (int nt = 0; nt < 10; ++nt)
            acc[nt] = __builtin_amdgcn_mfma_f32_16x16x32_bf16(a, WH[(nt * 5 + ks) * 64 + l], acc[nt], 0, 0, 0);
    }
    __syncthreads();

    const int r0l = (w << 4) + ((l >> 4) << 2);
    const int cb = l & 15;
    const float* bias = (cy == 0) ? Wz_b : (cy == 2) ? Wh_b : nullptr;
    #pragma unroll
    for (int nt = 0; nt < 10; ++nt) {
        const int col = nt * 16 + cb;
        const float b = bias ? bias[col] : 0.f;
        #pragma unroll
        for (int r = 0; r < 4; ++r)
            As[(r0l + r) * AST + col] = f2bf(acc[nt][r] + b);
    }
    __syncthreads();
    for (int idx = t; idx < 64 * 20; idx += 256) {
        const int m = idx / 20, g8 = (idx % 20) * 8;
        if (m0 + m < M)
            *reinterpret_cast<short8*>(&xproj[(size_t)(m0 + m) * 480 + cy * 160 + g8]) =
                *reinterpret_cast<const short8*>(&As[m * AST + g8]);
    }
}

// ---------------- hU0: hh[n] = [bf16(h0) | e5m2(h0 @ Ur^T + Ur_b)]
__global__ __launch_bounds__(256, 3) void hU0_gemm(
    const float* __restrict__ h0, const ushort* __restrict__ wpack,
    const float* __restrict__ Ur_b, uint8_t* __restrict__ hh, int M)
{
    __shared__ ushort As[64 * AST];
    __shared__ uint8_t HuB[64 * 160];
    const int t = threadIdx.x, m0 = blockIdx.x * 64;

    for (int idx = t; idx < 64 * 40; idx += 256) {
        const int m = idx / 40, k4 = (idx % 40) * 4;
        float4 v = make_float4(0.f, 0.f, 0.f, 0.f);
        if (m0 + m < M) v = *reinterpret_cast<const float4*>(&h0[(size_t)(m0 + m) * HID + k4]);
        ushort4 hv;
        hv.x = f2bf(v.x); hv.y = f2bf(v.y); hv.z = f2bf(v.z); hv.w = f2bf(v.w);
        *reinterpret_cast<ushort4*>(&As[m * AST + k4]) = hv;
    }
    __syncthreads();

    for (int idx = t; idx < 64 * 20; idx += 256) {
        const int m = idx / 20, g8 = (idx % 20) * 8;
        if (m0 + m < M)
            *reinterpret_cast<short8*>(hh + (size_t)(m0 + m) * HHROW + g8 * 2) =
                *reinterpret_cast<const short8*>(&As[m * AST + g8]);
    }

    const int w = t >> 6, l = t & 63;
    const int ar = (w << 4) + (l & 15);
    const int kg = (l >> 4) << 3;

    f32x4 acc[10];
    #pragma unroll
    for (int nt = 0; nt < 10; ++nt) acc[nt] = (f32x4){0.f, 0.f, 0.f, 0.f};

    const short8* WH = reinterpret_cast<const short8*>(wpack + WPU);

    #pragma unroll
    for (int ks = 0; ks < 5; ++ks) {
        const short8 a = *reinterpret_cast<const short8*>(&As[ar * AST + ks * 32 + kg]);
        #pragma unroll
        for (int nt = 0; nt < 10; ++nt)
            acc[nt] = __builtin_amdgcn_mfma_f32_16x16x32_bf16(a, WH[(nt * 5 + ks) * 64 + l], acc[nt], 0, 0, 0);
    }

    const int r0l = (w << 4) + ((l >> 4) << 2);
    const int cb = l & 15;
    #pragma unroll
    for (int nt = 0; nt < 10; ++nt) {
        const int col = nt * 16 + cb;
        const float b = Ur_b[col];
        #pragma unroll
        for (int r = 0; r < 4; ++r)
            HuB[(r0l + r) * 160 + col] = (uint8_t)f2e5(acc[nt][r] + b);
    }
    __syncthreads();
    for (int idx = t; idx < 64 * 10; idx += 256) {
        const int m = idx / 10, g16 = (idx % 10) * 16;
        if (m0 + m < M)
            *reinterpret_cast<uint4*>(hh + (size_t)(m0 + m) * HHROW + 320 + g16) =
                *reinterpret_cast<const uint4*>(&HuB[m * 160 + g16]);
    }
}

// ---------------- fused iteration: gather -> zh-GEMM -> update -> (Ur-GEMM for next)
// 40960 B LDS (unpadded rows + XOR swizzle, no graph LDS) -> 4 blocks/CU.
__global__ __launch_bounds__(256, 4) void fused_iter(
    const uint8_t* __restrict__ hh,     // [N][480B]: bf16 h | e5m2 hU
    const ushort* __restrict__ xproj,   // [N][480] bf16: xz | xr | xh
    const int*    __restrict__ graph,
    const ushort* __restrict__ wpack,
    const float*  __restrict__ Ur_b,
    float*   __restrict__ out,          // [N][160] f32 (written only if write_out)
    uint8_t* __restrict__ hh_next,      // ping-pong, != hh
    int write_out, int do_next, int M)
{
    __shared__ ushort Az[64 * HID];     // bf16 sumh, later bf16 h_out (swizzled)
    __shared__ ushort Ag[64 * HID];     // bf16 sgh, later fp8 hU_out bytes (swizzled)
    const int t = threadIdx.x, m0 = blockIdx.x * 64;

    // gather: 5 tasks/thread (64 rows x 20 slots); graph read direct (L1 broadcast)
    #pragma unroll
    for (int task = 0; task < 5; ++task) {
        const int idx = t + task * 256;
        const int r = idx / 20, g8 = (idx % 20) * 8;
        const int n = m0 + r;
        float s[8], g[8];
        #pragma unroll
        for (int j = 0; j < 8; ++j) { s[j] = 0.f; g[j] = 0.f; }
        if (n < M) {
            const short8 xr8 = *reinterpret_cast<const short8*>(&xproj[(size_t)n * 480 + 160 + g8]);
            const int4 ga = *reinterpret_cast<const int4*>(&graph[(size_t)n * NEI]);
            const int4 gb = *reinterpret_cast<const int4*>(&graph[(size_t)n * NEI + 4]);
            const int gi[8] = {ga.x, ga.y, ga.z, ga.w, gb.x, gb.y, gb.z, gb.w};
            short8 hv[NEI]; uint2 hu[NEI];
            #pragma unroll
            for (int k = 0; k < NEI; ++k) {
                const uint8_t* row = hh + (size_t)gi[k] * HHROW;
                hv[k] = *reinterpret_cast<const short8*>(row + g8 * 2);
                hu[k] = *reinterpret_cast<const uint2*>(row + 320 + g8);
            }
            #pragma unroll
            for (int k = 0; k < NEI; ++k) {
                #pragma unroll
                for (int j = 0; j < 8; ++j) {
                    const uint32_t hub = ((j < 4 ? hu[k].x >> (8 * j) : hu[k].y >> (8 * (j - 4))) & 0xFFu);
                    const float h = bf2f((ushort)hv[k][j]);
                    const float rg = sigf(bf2f((ushort)xr8[j]) + e5m2f(hub));
                    s[j] += h;
                    g[j] = fmaf(rg, h, g[j]);
                }
            }
        }
        short8 sv, gv;
        #pragma unroll
        for (int j = 0; j < 8; ++j) { sv[j] = (short)f2bf(s[j]); gv[j] = (short)f2bf(g[j]); }
        const int c = SW(r, g8);
        *reinterpret_cast<short8*>(&Az[r * HID + c]) = sv;
        *reinterpret_cast<short8*>(&Ag[r * HID + c]) = gv;
    }
    __syncthreads();

    const int w = t >> 6, l = t & 63;
    const int ar = (w << 4) + (l & 15);
    const int kg = (l >> 4) << 3;

    f32x4 accz[10], acch[10];
    #pragma unroll
    for (int nt = 0; nt < 10; ++nt) {
        accz[nt] = (f32x4){0.f, 0.f, 0.f, 0.f};
        acch[nt] = (f32x4){0.f, 0.f, 0.f, 0.f};
    }

    {
        const short8* ZH = reinterpret_cast<const short8*>(wpack + WPZH);
        const short8* HHm = reinterpret_cast<const short8*>(wpack + WPHH);
        #pragma unroll
        for (int ks = 0; ks < 5; ++ks) {
            const int c = SW(ar, ks * 32 + kg);
            const short8 az = *reinterpret_cast<const short8*>(&Az[ar * HID + c]);
            const short8 ag = *reinterpret_cast<const short8*>(&Ag[ar * HID + c]);
            #pragma unroll
            for (int nt = 0; nt < 10; ++nt) {
                const int bi = (nt * 5 + ks) * 64 + l;
                accz[nt] = __builtin_amdgcn_mfma_f32_16x16x32_bf16(az, ZH[bi], accz[nt], 0, 0, 0);
                acch[nt] = __builtin_amdgcn_mfma_f32_16x16x32_bf16(ag, HHm[bi], acch[nt], 0, 0, 0);
            }
        }
    }

    // epilogue: v = (1-z)*sumh + z*tanh(.)  (v kept in accz for the Ur tail)
    const int r0l = (w << 4) + ((l >> 4) << 2);
    const int cb = l & 15;
    #pragma unroll
    for (int nt = 0; nt < 10; ++nt) {
        const int col = nt * 16 + cb;
        #pragma unroll
        for (int r = 0; r < 4; ++r) {
            const int m = m0 + r0l + r;
            float v = 0.f;
            if (m < M) {
                const float z = sigf(accz[nt][r] + bf2f(xproj[(size_t)m * 480 + col]));
                const float p = tanhfast(acch[nt][r] + bf2f(xproj[(size_t)m * 480 + 320 + col]));
                const float s = bf2f(Az[(r0l + r) * HID + SW(r0l + r, col)]);
                v = (1.f - z) * s + z * p;
                if (m == 0) v = 0.f;
                if (write_out) out[(size_t)m * HID + col] = v;
            }
            accz[nt][r] = v;
        }
    }

    if (!do_next) return;

    __syncthreads();   // all Az(sumh) reads done
    #pragma unroll
    for (int nt = 0; nt < 10; ++nt) {
        const int col = nt * 16 + cb;
        #pragma unroll
        for (int r = 0; r < 4; ++r)
            Az[(r0l + r) * HID + SW(r0l + r, col)] = f2bf(accz[nt][r]);   // bf16 h_out
    }
    __syncthreads();

    // coalesced h-half stores + Ur-GEMM from Az
    for (int idx = t; idx < 64 * 20; idx += 256) {
        const int m = idx / 20, g8 = (idx % 20) * 8;
        if (m0 + m < M)
            *reinterpret_cast<short8*>(hh_next + (size_t)(m0 + m) * HHROW + g8 * 2) =
                *reinterpret_cast<const short8*>(&Az[m * HID + SW(m, g8)]);
    }

    #pragma unroll
    for (int nt = 0; nt < 10; ++nt) acch[nt] = (f32x4){0.f, 0.f, 0.f, 0.f};
    {
        const short8* WH = reinterpret_cast<const short8*>(wpack + WPU);
        #pragma unroll
        for (int ks = 0; ks < 5; ++ks) {
            const short8 a = *reinterpret_cast<const short8*>(&Az[ar * HID + SW(ar, ks * 32 + kg)]);
            #pragma unroll
            for (int nt = 0; nt < 10; ++nt)
                acch[nt] = __builtin_amdgcn_mfma_f32_16x16x32_bf16(a, WH[(nt * 5 + ks) * 64 + l], acch[nt], 0, 0, 0);
        }
    }
    __syncthreads();   // Ag MFMA reads done; reuse Ag as byte buffer
    uint8_t* Agb = reinterpret_cast<uint8_t*>(Ag);
    #pragma unroll
    for (int nt = 0; nt < 10; ++nt) {
        const int col = nt * 16 + cb;
        const float b = Ur_b[col];
        #pragma unroll
        for (int r = 0; r < 4; ++r)
            Agb[(r0l + r) * 160 + col] = (uint8_t)f2e5(acch[nt][r] + b);
    }
    __syncthreads();
    for (int idx = t; idx < 64 * 10; idx += 256) {
        const int m = idx / 10, g16 = (idx % 10) * 16;
        if (m0 + m < M)
            *reinterpret_cast<uint4*>(hh_next + (size_t)(m0 + m) * HHROW + 320 + g16) =
                *reinterpret_cast<const uint4*>(&Agb[m * 160 + g16]);
    }
}

extern "C" void kernel_launch(void* const* d_in, const int* in_sizes, int n_in,
                              void* d_out, int out_size, void* d_ws, size_t ws_size,
                              hipStream_t stream)
{
    const float* h0   = (const float*)d_in[0];
    const float* x    = (const float*)d_in[1];
    const int*   grf  = (const int*)  d_in[2];
    const float* Wz_w = (const float*)d_in[3];
    const float* Wz_b = (const float*)d_in[4];
    const float* Wr_w = (const float*)d_in[5];
    const float* Ur_w = (const float*)d_in[6];
    const float* Ur_b = (const float*)d_in[7];
    const float* Wh_w = (const float*)d_in[8];
    const float* Wh_b = (const float*)d_in[9];
    float* out = (float*)d_out;

    const size_t per = (size_t)NM * HID;
    ushort*  xproj = (ushort*)d_ws;                       // 48 MB
    uint8_t* hh_a  = (uint8_t*)(xproj + per * 3);         // 24 MB
    uint8_t* hh_b  = hh_a + (size_t)NM * HHROW;           // 24 MB
    ushort*  wpack = (ushort*)(hh_b + (size_t)NM * HHROW);// 0.3 MB

    const dim3 gb((NM + 63) / 64), gt(256);               // 782 blocks

    pack_weights<<<6, 256, 0, stream>>>(Wz_w, Wr_w, Ur_w, Wh_w, wpack);
    xproj_gemm<<<dim3(gb.x, 3), gt, 0, stream>>>(x, wpack, Wz_b, Wh_b, xproj, NM);
    hU0_gemm<<<gb, gt, 0, stream>>>(h0, wpack, Ur_b, hh_a, NM);

    fused_iter<<<gb, gt, 0, stream>>>(hh_a, xproj, grf, wpack, Ur_b, out, hh_b, 0, 1, NM);
    fused_iter<<<gb, gt, 0, stream>>>(hh_b, xproj, grf, wpack, Ur_b, out, hh_a, 0, 1, NM);
    fused_iter<<<gb, gt, 0, stream>>>(hh_a, xproj, grf, wpack, Ur_b, out, hh_b, 1, 0, NM);
}

// Round 8
// 393.852 us; speedup vs baseline: 1.4826x; 1.0121x over previous
//
#include <hip/hip_runtime.h>
#include <hip/hip_fp16.h>
#include <cstddef>
#include <cstdint>

#define NM  50000
#define HID 160
#define NEI 8
#define AST 168     // padded LDS row stride (ushorts): 336B rows, conflict-benign b128
#define HHROW 480   // hh row bytes: 320 B bf16 h | 160 B fp8(e5m2) hU

// packed-weight offsets (ushort units), bf16 hi-only
#define WPX   0        // [30nt][5ks][64l][8]: Wzx | Wr | Whx
#define WPU   76800    // Ur
#define WPZH  102400   // Wzh
#define WPHH  128000   // Whh

typedef __attribute__((ext_vector_type(8))) short  short8;
typedef __attribute__((ext_vector_type(4))) float  f32x4;

__device__ __forceinline__ ushort f2bf(float f) {
    union { float f; uint32_t u; } v; v.f = f;
    const uint32_t r = v.u + 0x7fffu + ((v.u >> 16) & 1u);   // RNE
    return (ushort)(r >> 16);
}
__device__ __forceinline__ float bf2f(ushort h) {
    union { uint32_t u; float f; } v; v.u = ((uint32_t)h) << 16;
    return v.f;
}
// fp8 e5m2 == truncated f16
__device__ __forceinline__ uint32_t f2e5(float v) {
    union { __half h; ushort u; } c; c.h = __float2half(v);
    const ushort r = c.u + 0x7F + ((c.u >> 8) & 1);
    return (uint32_t)(r >> 8) & 0xFF;
}
__device__ __forceinline__ float e5m2f(uint32_t byte) {
    union { ushort u; __half h; } c; c.u = (ushort)(byte << 8);
    return __half2float(c.h);
}
__device__ __forceinline__ float sigf(float v)     { return 1.f / (1.f + __expf(-v)); }
__device__ __forceinline__ float tanhfast(float v) { return 2.f / (1.f + __expf(-2.f * v)) - 1.f; }

// ---------------- weight pre-pack into MFMA B-fragment-linear order (bf16 hi only)
__global__ __launch_bounds__(256) void pack_weights(
    const float* __restrict__ Wz, const float* __restrict__ Wr,
    const float* __restrict__ Ur, const float* __restrict__ Wh,
    ushort* __restrict__ dst)
{
    const float* src; int off, stride, ntb = 0; ushort* hi;
    switch (blockIdx.x) {
        case 0:  src = Wz; off = 0;   stride = 320; hi = dst + WPX;  ntb = 0;  break;
        case 1:  src = Wr; off = 0;   stride = 160; hi = dst + WPX;  ntb = 10; break;
        case 2:  src = Wh; off = 0;   stride = 320; hi = dst + WPX;  ntb = 20; break;
        case 3:  src = Ur; off = 0;   stride = 160; hi = dst + WPU;  break;
        case 4:  src = Wz; off = 160; stride = 320; hi = dst + WPZH; break;
        default: src = Wh; off = 160; stride = 320; hi = dst + WPHH; break;
    }
    const int t = threadIdx.x, l = t & 63;
    for (int tile = t >> 6; tile < 50; tile += 4) {
        const int ntl = tile / 5, ks = tile % 5;
        const int n = ntl * 16 + (l & 15);
        const int k = ks * 32 + (l >> 4) * 8;
        const float* s = &src[(size_t)n * stride + off + k];
        const size_t o = ((size_t)((ntb + ntl) * 5 + ks) * 64 + l) * 8;
        #pragma unroll
        for (int j = 0; j < 8; ++j) hi[o + j] = f2bf(s[j]);
    }
}

// ---------------- x projections, grid (782,3): y picks {xz, xr, xh} chunk
__global__ __launch_bounds__(256) void xproj_gemm(
    const float* __restrict__ x, const ushort* __restrict__ wpack,
    const float* __restrict__ Wz_b, const float* __restrict__ Wh_b,
    ushort* __restrict__ xproj, int M)
{
    __shared__ ushort As[64 * AST];
    const int t = threadIdx.x, m0 = blockIdx.x * 64, cy = blockIdx.y;

    for (int idx = t; idx < 64 * 40; idx += 256) {
        const int m = idx / 40, k4 = (idx % 40) * 4;
        float4 v = make_float4(0.f, 0.f, 0.f, 0.f);
        if (m0 + m < M) v = *reinterpret_cast<const float4*>(&x[(size_t)(m0 + m) * HID + k4]);
        ushort4 hv;
        hv.x = f2bf(v.x); hv.y = f2bf(v.y); hv.z = f2bf(v.z); hv.w = f2bf(v.w);
        *reinterpret_cast<ushort4*>(&As[m * AST + k4]) = hv;
    }
    __syncthreads();

    const int w = t >> 6, l = t & 63;
    const int ar = (w << 4) + (l & 15);
    const int kg = (l >> 4) << 3;

    f32x4 acc[10];
    #pragma unroll
    for (int nt = 0; nt < 10; ++nt) acc[nt] = (f32x4){0.f, 0.f, 0.f, 0.f};

    const short8* WH = reinterpret_cast<const short8*>(wpack + WPX + cy * 25600);

    #pragma unroll
    for (int ks = 0; ks < 5; ++ks) {
        const short8 a = *reinterpret_cast<const short8*>(&As[ar * AST + ks * 32 + kg]);
        #pragma unroll
        for (int nt = 0; nt < 10; ++nt)
            acc[nt] = __builtin_amdgcn_mfma_f32_16x16x32_bf16(a, WH[(nt * 5 + ks) * 64 + l], acc[nt], 0, 0, 0);
    }
    __syncthreads();

    const int r0l = (w << 4) + ((l >> 4) << 2);
    const int cb = l & 15;
    const float* bias = (cy == 0) ? Wz_b : (cy == 2) ? Wh_b : nullptr;
    #pragma unroll
    for (int nt = 0; nt < 10; ++nt) {
        const int col = nt * 16 + cb;
        const float b = bias ? bias[col] : 0.f;
        #pragma unroll
        for (int r = 0; r < 4; ++r)
            As[(r0l + r) * AST + col] = f2bf(acc[nt][r] + b);
    }
    __syncthreads();
    for (int idx = t; idx < 64 * 20; idx += 256) {
        const int m = idx / 20, g8 = (idx % 20) * 8;
        if (m0 + m < M)
            *reinterpret_cast<short8*>(&xproj[(size_t)(m0 + m) * 480 + cy * 160 + g8]) =
                *reinterpret_cast<const short8*>(&As[m * AST + g8]);
    }
}

// ---------------- hU0: hh[n] = [bf16(h0) | e5m2(h0 @ Ur^T + Ur_b)]
__global__ __launch_bounds__(256, 3) void hU0_gemm(
    const float* __restrict__ h0, const ushort* __restrict__ wpack,
    const float* __restrict__ Ur_b, uint8_t* __restrict__ hh, int M)
{
    __shared__ ushort As[64 * AST];
    __shared__ uint8_t HuB[64 * 160];
    const int t = threadIdx.x, m0 = blockIdx.x * 64;

    for (int idx = t; idx < 64 * 40; idx += 256) {
        const int m = idx / 40, k4 = (idx % 40) * 4;
        float4 v = make_float4(0.f, 0.f, 0.f, 0.f);
        if (m0 + m < M) v = *reinterpret_cast<const float4*>(&h0[(size_t)(m0 + m) * HID + k4]);
        ushort4 hv;
        hv.x = f2bf(v.x); hv.y = f2bf(v.y); hv.z = f2bf(v.z); hv.w = f2bf(v.w);
        *reinterpret_cast<ushort4*>(&As[m * AST + k4]) = hv;
    }
    __syncthreads();

    for (int idx = t; idx < 64 * 20; idx += 256) {
        const int m = idx / 20, g8 = (idx % 20) * 8;
        if (m0 + m < M)
            *reinterpret_cast<short8*>(hh + (size_t)(m0 + m) * HHROW + g8 * 2) =
                *reinterpret_cast<const short8*>(&As[m * AST + g8]);
    }

    const int w = t >> 6, l = t & 63;
    const int ar = (w << 4) + (l & 15);
    const int kg = (l >> 4) << 3;

    f32x4 acc[10];
    #pragma unroll
    for (int nt = 0; nt < 10; ++nt) acc[nt] = (f32x4){0.f, 0.f, 0.f, 0.f};

    const short8* WH = reinterpret_cast<const short8*>(wpack + WPU);

    #pragma unroll
    for (int ks = 0; ks < 5; ++ks) {
        const short8 a = *reinterpret_cast<const short8*>(&As[ar * AST + ks * 32 + kg]);
        #pragma unroll
        for (int nt = 0; nt < 10; ++nt)
            acc[nt] = __builtin_amdgcn_mfma_f32_16x16x32_bf16(a, WH[(nt * 5 + ks) * 64 + l], acc[nt], 0, 0, 0);
    }

    const int r0l = (w << 4) + ((l >> 4) << 2);
    const int cb = l & 15;
    #pragma unroll
    for (int nt = 0; nt < 10; ++nt) {
        const int col = nt * 16 + cb;
        const float b = Ur_b[col];
        #pragma unroll
        for (int r = 0; r < 4; ++r)
            HuB[(r0l + r) * 160 + col] = (uint8_t)f2e5(acc[nt][r] + b);
    }
    __syncthreads();
    for (int idx = t; idx < 64 * 10; idx += 256) {
        const int m = idx / 10, g16 = (idx % 10) * 16;
        if (m0 + m < M)
            *reinterpret_cast<uint4*>(hh + (size_t)(m0 + m) * HHROW + 320 + g16) =
                *reinterpret_cast<const uint4*>(&HuB[m * 160 + g16]);
    }
}

// ---------------- standalone gather: high-occupancy, no barriers/phases.
// 16 rows/block x 20 slots = 320 threads; 20 consecutive lanes read contiguous
// 320 B of each gathered row. sumh/sgh written bf16.
__global__ __launch_bounds__(320) void gather_kernel(
    const uint8_t* __restrict__ hh,     // [N][480B]: bf16 h | e5m2 hU
    const ushort* __restrict__ xproj,   // [N][480] bf16: xz | xr | xh
    const int*    __restrict__ graph,
    ushort* __restrict__ sumh,          // [N][160] bf16
    ushort* __restrict__ sgh)           // [N][160] bf16
{
    const int t = threadIdx.x;
    const int n = blockIdx.x * 16 + t / 20;     // 3125*16 == 50000 exactly
    const int g8 = (t % 20) * 8;

    const short8 xr8 = *reinterpret_cast<const short8*>(&xproj[(size_t)n * 480 + 160 + g8]);
    const int4 ga = *reinterpret_cast<const int4*>(&graph[(size_t)n * NEI]);
    const int4 gb = *reinterpret_cast<const int4*>(&graph[(size_t)n * NEI + 4]);
    const int gi[8] = {ga.x, ga.y, ga.z, ga.w, gb.x, gb.y, gb.z, gb.w};

    short8 hv[NEI]; uint2 hu[NEI];
    #pragma unroll
    for (int k = 0; k < NEI; ++k) {
        const uint8_t* row = hh + (size_t)gi[k] * HHROW;
        hv[k] = *reinterpret_cast<const short8*>(row + g8 * 2);
        hu[k] = *reinterpret_cast<const uint2*>(row + 320 + g8);
    }

    float s[8], g[8];
    #pragma unroll
    for (int j = 0; j < 8; ++j) { s[j] = 0.f; g[j] = 0.f; }
    #pragma unroll
    for (int k = 0; k < NEI; ++k) {
        #pragma unroll
        for (int j = 0; j < 8; ++j) {
            const uint32_t hub = ((j < 4 ? hu[k].x >> (8 * j) : hu[k].y >> (8 * (j - 4))) & 0xFFu);
            const float h = bf2f((ushort)hv[k][j]);
            const float rg = sigf(bf2f((ushort)xr8[j]) + e5m2f(hub));
            s[j] += h;
            g[j] = fmaf(rg, h, g[j]);
        }
    }
    short8 sv, gv;
    #pragma unroll
    for (int j = 0; j < 8; ++j) { sv[j] = (short)f2bf(s[j]); gv[j] = (short)f2bf(g[j]); }
    *reinterpret_cast<short8*>(&sumh[(size_t)n * HID + g8]) = sv;
    *reinterpret_cast<short8*>(&sgh [(size_t)n * HID + g8]) = gv;
}

// ---------------- zh-GEMM + gate update -> out / hh_next (+ next-iter Ur-GEMM)
__global__ __launch_bounds__(256, 3) void gemm_zh(
    const ushort* __restrict__ sumh, const ushort* __restrict__ sgh,
    const ushort* __restrict__ xproj, const ushort* __restrict__ wpack,
    const float* __restrict__ Ur_b,
    float*   __restrict__ out,          // written only if write_out
    uint8_t* __restrict__ hh_next,      // written only if do_next
    int write_out, int do_next, int M)
{
    __shared__ ushort Az[64 * AST];     // bf16 sumh, later bf16 h_out
    __shared__ ushort Ag[64 * AST];     // bf16 sgh, later fp8 hU_out bytes
    const int t = threadIdx.x, m0 = blockIdx.x * 64;

    for (int idx = t; idx < 64 * 20; idx += 256) {
        const int m = idx / 20, g8 = (idx % 20) * 8;
        if (m0 + m < M) {
            *reinterpret_cast<short8*>(&Az[m * AST + g8]) =
                *reinterpret_cast<const short8*>(&sumh[(size_t)(m0 + m) * HID + g8]);
            *reinterpret_cast<short8*>(&Ag[m * AST + g8]) =
                *reinterpret_cast<const short8*>(&sgh[(size_t)(m0 + m) * HID + g8]);
        }
    }
    __syncthreads();

    const int w = t >> 6, l = t & 63;
    const int ar = (w << 4) + (l & 15);
    const int kg = (l >> 4) << 3;

    f32x4 accz[10], acch[10];
    #pragma unroll
    for (int nt = 0; nt < 10; ++nt) {
        accz[nt] = (f32x4){0.f, 0.f, 0.f, 0.f};
        acch[nt] = (f32x4){0.f, 0.f, 0.f, 0.f};
    }

    {
        const short8* ZH = reinterpret_cast<const short8*>(wpack + WPZH);
        const short8* HHm = reinterpret_cast<const short8*>(wpack + WPHH);
        #pragma unroll
        for (int ks = 0; ks < 5; ++ks) {
            const short8 az = *reinterpret_cast<const short8*>(&Az[ar * AST + ks * 32 + kg]);
            const short8 ag = *reinterpret_cast<const short8*>(&Ag[ar * AST + ks * 32 + kg]);
            #pragma unroll
            for (int nt = 0; nt < 10; ++nt) {
                const int bi = (nt * 5 + ks) * 64 + l;
                accz[nt] = __builtin_amdgcn_mfma_f32_16x16x32_bf16(az, ZH[bi], accz[nt], 0, 0, 0);
                acch[nt] = __builtin_amdgcn_mfma_f32_16x16x32_bf16(ag, HHm[bi], acch[nt], 0, 0, 0);
            }
        }
    }

    // epilogue: v = (1-z)*sumh + z*tanh(.)
    const int r0l = (w << 4) + ((l >> 4) << 2);
    const int cb = l & 15;
    #pragma unroll
    for (int nt = 0; nt < 10; ++nt) {
        const int col = nt * 16 + cb;
        #pragma unroll
        for (int r = 0; r < 4; ++r) {
            const int m = m0 + r0l + r;
            float v = 0.f;
            if (m < M) {
                const float z = sigf(accz[nt][r] + bf2f(xproj[(size_t)m * 480 + col]));
                const float p = tanhfast(acch[nt][r] + bf2f(xproj[(size_t)m * 480 + 320 + col]));
                const float s = bf2f(Az[(r0l + r) * AST + col]);
                v = (1.f - z) * s + z * p;
                if (m == 0) v = 0.f;
                if (write_out) out[(size_t)m * HID + col] = v;
            }
            accz[nt][r] = v;
        }
    }

    if (!do_next) return;

    __syncthreads();
    #pragma unroll
    for (int nt = 0; nt < 10; ++nt) {
        const int col = nt * 16 + cb;
        #pragma unroll
        for (int r = 0; r < 4; ++r)
            Az[(r0l + r) * AST + col] = f2bf(accz[nt][r]);   // bf16 h_out
    }
    __syncthreads();

    for (int idx = t; idx < 64 * 20; idx += 256) {
        const int m = idx / 20, g8 = (idx % 20) * 8;
        if (m0 + m < M)
            *reinterpret_cast<short8*>(hh_next + (size_t)(m0 + m) * HHROW + g8 * 2) =
                *reinterpret_cast<const short8*>(&Az[m * AST + g8]);
    }

    #pragma unroll
    for (int nt = 0; nt < 10; ++nt) acch[nt] = (f32x4){0.f, 0.f, 0.f, 0.f};
    {
        const short8* WH = reinterpret_cast<const short8*>(wpack + WPU);
        #pragma unroll
        for (int ks = 0; ks < 5; ++ks) {
            const short8 a = *reinterpret_cast<const short8*>(&Az[ar * AST + ks * 32 + kg]);
            #pragma unroll
            for (int nt = 0; nt < 10; ++nt)
                acch[nt] = __builtin_amdgcn_mfma_f32_16x16x32_bf16(a, WH[(nt * 5 + ks) * 64 + l], acch[nt], 0, 0, 0);
        }
    }
    __syncthreads();   // Ag MFMA reads done; reuse as byte buffer
    uint8_t* Agb = reinterpret_cast<uint8_t*>(Ag);
    #pragma unroll
    for (int nt = 0; nt < 10; ++nt) {
        const int col = nt * 16 + cb;
        const float b = Ur_b[col];
        #pragma unroll
        for (int r = 0; r < 4; ++r)
            Agb[(r0l + r) * 160 + col] = (uint8_t)f2e5(acch[nt][r] + b);
    }
    __syncthreads();
    for (int idx = t; idx < 64 * 10; idx += 256) {
        const int m = idx / 10, g16 = (idx % 10) * 16;
        if (m0 + m < M)
            *reinterpret_cast<uint4*>(hh_next + (size_t)(m0 + m) * HHROW + 320 + g16) =
                *reinterpret_cast<const uint4*>(&Agb[m * 160 + g16]);
    }
}

extern "C" void kernel_launch(void* const* d_in, const int* in_sizes, int n_in,
                              void* d_out, int out_size, void* d_ws, size_t ws_size,
                              hipStream_t stream)
{
    const float* h0   = (const float*)d_in[0];
    const float* x    = (const float*)d_in[1];
    const int*   grf  = (const int*)  d_in[2];
    const float* Wz_w = (const float*)d_in[3];
    const float* Wz_b = (const float*)d_in[4];
    const float* Wr_w = (const float*)d_in[5];
    const float* Ur_w = (const float*)d_in[6];
    const float* Ur_b = (const float*)d_in[7];
    const float* Wh_w = (const float*)d_in[8];
    const float* Wh_b = (const float*)d_in[9];
    float* out = (float*)d_out;

    const size_t per = (size_t)NM * HID;
    ushort*  xproj = (ushort*)d_ws;                        // 48 MB
    uint8_t* hh_a  = (uint8_t*)(xproj + per * 3);          // 24 MB
    uint8_t* hh_b  = hh_a + (size_t)NM * HHROW;            // 24 MB
    ushort*  sumh  = (ushort*)(hh_b + (size_t)NM * HHROW); // 16 MB
    ushort*  sgh   = sumh + per;                           // 16 MB
    ushort*  wpack = sgh + per;                            // 0.3 MB

    const dim3 gb((NM + 63) / 64), gt(256);                // 782 blocks
    const dim3 sb(NM / 16), st(320);                       // 3125 blocks

    pack_weights<<<6, 256, 0, stream>>>(Wz_w, Wr_w, Ur_w, Wh_w, wpack);
    xproj_gemm<<<dim3(gb.x, 3), gt, 0, stream>>>(x, wpack, Wz_b, Wh_b, xproj, NM);
    hU0_gemm<<<gb, gt, 0, stream>>>(h0, wpack, Ur_b, hh_a, NM);

    gather_kernel<<<sb, st, 0, stream>>>(hh_a, xproj, grf, sumh, sgh);
    gemm_zh<<<gb, gt, 0, stream>>>(sumh, sgh, xproj, wpack, Ur_b, out, hh_b, 0, 1, NM);
    gather_kernel<<<sb, st, 0, stream>>>(hh_b, xproj, grf, sumh, sgh);
    gemm_zh<<<gb, gt, 0, stream>>>(sumh, sgh, xproj, wpack, Ur_b, out, hh_a, 0, 1, NM);
    gather_kernel<<<sb, st, 0, stream>>>(hh_a, xproj, grf, sumh, sgh);
    gemm_zh<<<gb, gt, 0, stream>>>(sumh, sgh, xproj, wpack, Ur_b, out, hh_b, 1, 0, NM);
}

// Round 9
// 378.772 us; speedup vs baseline: 1.5417x; 1.0398x over previous
//
#include <hip/hip_runtime.h>
#include <hip/hip_fp16.h>
#include <cstddef>
#include <cstdint>

#define NM  50000
#define HID 160
#define NEI 8
#define AST 168     // padded LDS row stride (ushorts): 336B rows, conflict-benign b128
#define HHROW 480   // hh row bytes: 320 B bf16 h | 160 B fp8(e5m2) hU
#define NBLK 1563   // ceil(50000/32)

// packed-weight offsets (ushort units), bf16 hi-only
#define WPX   0        // [30nt][5ks][64l][8]: Wzx | Wr | Whx
#define WPU   76800    // Ur
#define WPZH  102400   // Wzh
#define WPHH  128000   // Whh

typedef __attribute__((ext_vector_type(8))) short  short8;
typedef __attribute__((ext_vector_type(4))) float  f32x4;
typedef __attribute__((ext_vector_type(4))) ushort ushort4v;

__device__ __forceinline__ ushort f2bf(float f) {
    union { float f; uint32_t u; } v; v.f = f;
    const uint32_t r = v.u + 0x7fffu + ((v.u >> 16) & 1u);   // RNE
    return (ushort)(r >> 16);
}
__device__ __forceinline__ float bf2f(ushort h) {
    union { uint32_t u; float f; } v; v.u = ((uint32_t)h) << 16;
    return v.f;
}
// fp8 e5m2 == truncated f16
__device__ __forceinline__ uint32_t f2e5(float v) {
    union { __half h; ushort u; } c; c.h = __float2half(v);
    const ushort r = c.u + 0x7F + ((c.u >> 8) & 1);
    return (uint32_t)(r >> 8) & 0xFF;
}
__device__ __forceinline__ float e5m2f(uint32_t byte) {
    union { ushort u; __half h; } c; c.u = (ushort)(byte << 8);
    return __half2float(c.h);
}
__device__ __forceinline__ float sigf(float v)     { return 1.f / (1.f + __expf(-v)); }
__device__ __forceinline__ float tanhfast(float v) { return 2.f / (1.f + __expf(-2.f * v)) - 1.f; }

// ---------------- weight pre-pack into MFMA B-fragment-linear order (bf16 hi only)
__global__ __launch_bounds__(256) void pack_weights(
    const float* __restrict__ Wz, const float* __restrict__ Wr,
    const float* __restrict__ Ur, const float* __restrict__ Wh,
    ushort* __restrict__ dst)
{
    const float* src; int off, stride, ntb = 0; ushort* hi;
    switch (blockIdx.x) {
        case 0:  src = Wz; off = 0;   stride = 320; hi = dst + WPX;  ntb = 0;  break;
        case 1:  src = Wr; off = 0;   stride = 160; hi = dst + WPX;  ntb = 10; break;
        case 2:  src = Wh; off = 0;   stride = 320; hi = dst + WPX;  ntb = 20; break;
        case 3:  src = Ur; off = 0;   stride = 160; hi = dst + WPU;  break;
        case 4:  src = Wz; off = 160; stride = 320; hi = dst + WPZH; break;
        default: src = Wh; off = 160; stride = 320; hi = dst + WPHH; break;
    }
    const int t = threadIdx.x, l = t & 63;
    for (int tile = t >> 6; tile < 50; tile += 4) {
        const int ntl = tile / 5, ks = tile % 5;
        const int n = ntl * 16 + (l & 15);
        const int k = ks * 32 + (l >> 4) * 8;
        const float* s = &src[(size_t)n * stride + off + k];
        const size_t o = ((size_t)((ntb + ntl) * 5 + ks) * 64 + l) * 8;
        #pragma unroll
        for (int j = 0; j < 8; ++j) hi[o + j] = f2bf(s[j]);
    }
}

// ---------------- x projections, grid (NBLK, 3), 32-row tiles.
// cy=1 (xr): row-major [N][160]. cy=0/2 (xz/xh): C-frag-linear
// [nblk][wrow][wcol][nt(5)][lane(64)][r(4)] so gemm_zh's epilogue reads ushort4.
__global__ __launch_bounds__(256) void xproj_gemm(
    const float* __restrict__ x, const ushort* __restrict__ wpack,
    const float* __restrict__ Wz_b, const float* __restrict__ Wh_b,
    ushort* __restrict__ xr, ushort* __restrict__ xzf, ushort* __restrict__ xhf,
    int M)
{
    __shared__ ushort As[32 * AST];
    const int t = threadIdx.x, m0 = blockIdx.x * 32, cy = blockIdx.y;

    for (int idx = t; idx < 32 * 40; idx += 256) {
        const int m = idx / 40, k4 = (idx % 40) * 4;
        float4 v = make_float4(0.f, 0.f, 0.f, 0.f);
        if (m0 + m < M) v = *reinterpret_cast<const float4*>(&x[(size_t)(m0 + m) * HID + k4]);
        ushort4 hv;
        hv.x = f2bf(v.x); hv.y = f2bf(v.y); hv.z = f2bf(v.z); hv.w = f2bf(v.w);
        *reinterpret_cast<ushort4*>(&As[m * AST + k4]) = hv;
    }
    __syncthreads();

    const int w = t >> 6, l = t & 63;
    const int wrow = w & 1, wcol = w >> 1;
    const int ar = wrow * 16 + (l & 15);
    const int kg = (l >> 4) << 3;

    f32x4 acc[5];
    #pragma unroll
    for (int nt = 0; nt < 5; ++nt) acc[nt] = (f32x4){0.f, 0.f, 0.f, 0.f};

    const short8* WH = reinterpret_cast<const short8*>(wpack + WPX + cy * 25600);

    #pragma unroll
    for (int ks = 0; ks < 5; ++ks) {
        const short8 a = *reinterpret_cast<const short8*>(&As[ar * AST + ks * 32 + kg]);
        #pragma unroll
        for (int nt = 0; nt < 5; ++nt)
            acc[nt] = __builtin_amdgcn_mfma_f32_16x16x32_bf16(a, WH[(((wcol * 5 + nt) * 5 + ks) << 6) + l], acc[nt], 0, 0, 0);
    }

    const int r0l = wrow * 16 + ((l >> 4) << 2);
    const int cb = l & 15;

    if (cy == 1) {
        // xr: row-major via LDS repack
        __syncthreads();
        #pragma unroll
        for (int nt = 0; nt < 5; ++nt) {
            const int col = (wcol * 5 + nt) * 16 + cb;
            #pragma unroll
            for (int r = 0; r < 4; ++r)
                As[(r0l + r) * AST + col] = f2bf(acc[nt][r]);
        }
        __syncthreads();
        for (int idx = t; idx < 32 * 20; idx += 256) {
            const int m = idx / 20, g8 = (idx % 20) * 8;
            if (m0 + m < M)
                *reinterpret_cast<short8*>(&xr[(size_t)(m0 + m) * HID + g8]) =
                    *reinterpret_cast<const short8*>(&As[m * AST + g8]);
        }
    } else {
        const float* bias = (cy == 0) ? Wz_b : Wh_b;
        ushort* dst = (cy == 0) ? xzf : xhf;
        const size_t fragbase = ((size_t)blockIdx.x * 2 + wrow) * 2 + wcol;
        #pragma unroll
        for (int nt = 0; nt < 5; ++nt) {
            const float b = bias[(wcol * 5 + nt) * 16 + cb];
            ushort4v v;
            #pragma unroll
            for (int r = 0; r < 4; ++r) v[r] = f2bf(acc[nt][r] + b);
            *reinterpret_cast<ushort4v*>(&dst[((fragbase * 5 + nt) * 64 + l) * 4]) = v;
        }
    }
}

// ---------------- hU0: hh[n] = [bf16(h0) | e5m2(h0 @ Ur^T + Ur_b)]
__global__ __launch_bounds__(256, 3) void hU0_gemm(
    const float* __restrict__ h0, const ushort* __restrict__ wpack,
    const float* __restrict__ Ur_b, uint8_t* __restrict__ hh, int M)
{
    __shared__ ushort As[64 * AST];
    __shared__ uint8_t HuB[64 * 160];
    const int t = threadIdx.x, m0 = blockIdx.x * 64;

    for (int idx = t; idx < 64 * 40; idx += 256) {
        const int m = idx / 40, k4 = (idx % 40) * 4;
        float4 v = make_float4(0.f, 0.f, 0.f, 0.f);
        if (m0 + m < M) v = *reinterpret_cast<const float4*>(&h0[(size_t)(m0 + m) * HID + k4]);
        ushort4 hv;
        hv.x = f2bf(v.x); hv.y = f2bf(v.y); hv.z = f2bf(v.z); hv.w = f2bf(v.w);
        *reinterpret_cast<ushort4*>(&As[m * AST + k4]) = hv;
    }
    __syncthreads();

    for (int idx = t; idx < 64 * 20; idx += 256) {
        const int m = idx / 20, g8 = (idx % 20) * 8;
        if (m0 + m < M)
            *reinterpret_cast<short8*>(hh + (size_t)(m0 + m) * HHROW + g8 * 2) =
                *reinterpret_cast<const short8*>(&As[m * AST + g8]);
    }

    const int w = t >> 6, l = t & 63;
    const int ar = (w << 4) + (l & 15);
    const int kg = (l >> 4) << 3;

    f32x4 acc[10];
    #pragma unroll
    for (int nt = 0; nt < 10; ++nt) acc[nt] = (f32x4){0.f, 0.f, 0.f, 0.f};

    const short8* WH = reinterpret_cast<const short8*>(wpack + WPU);

    #pragma unroll
    for (int ks = 0; ks < 5; ++ks) {
        const short8 a = *reinterpret_cast<const short8*>(&As[ar * AST + ks * 32 + kg]);
        #pragma unroll
        for (int nt = 0; nt < 10; ++nt)
            acc[nt] = __builtin_amdgcn_mfma_f32_16x16x32_bf16(a, WH[(nt * 5 + ks) * 64 + l], acc[nt], 0, 0, 0);
    }

    const int r0l = (w << 4) + ((l >> 4) << 2);
    const int cb = l & 15;
    #pragma unroll
    for (int nt = 0; nt < 10; ++nt) {
        const int col = nt * 16 + cb;
        const float b = Ur_b[col];
        #pragma unroll
        for (int r = 0; r < 4; ++r)
            HuB[(r0l + r) * 160 + col] = (uint8_t)f2e5(acc[nt][r] + b);
    }
    __syncthreads();
    for (int idx = t; idx < 64 * 10; idx += 256) {
        const int m = idx / 10, g16 = (idx % 10) * 16;
        if (m0 + m < M)
            *reinterpret_cast<uint4*>(hh + (size_t)(m0 + m) * HHROW + 320 + g16) =
                *reinterpret_cast<const uint4*>(&HuB[m * 160 + g16]);
    }
}

// ---------------- standalone gather: high-occupancy, no barriers/phases.
__global__ __launch_bounds__(320) void gather_kernel(
    const uint8_t* __restrict__ hh,     // [N][480B]: bf16 h | e5m2 hU
    const ushort* __restrict__ xr,      // [N][160] bf16
    const int*    __restrict__ graph,
    ushort* __restrict__ sumh,          // [N][160] bf16
    ushort* __restrict__ sgh)           // [N][160] bf16
{
    const int t = threadIdx.x;
    const int n = blockIdx.x * 16 + t / 20;     // 3125*16 == 50000 exactly
    const int g8 = (t % 20) * 8;

    const short8 xr8 = *reinterpret_cast<const short8*>(&xr[(size_t)n * HID + g8]);
    const int4 ga = *reinterpret_cast<const int4*>(&graph[(size_t)n * NEI]);
    const int4 gb = *reinterpret_cast<const int4*>(&graph[(size_t)n * NEI + 4]);
    const int gi[8] = {ga.x, ga.y, ga.z, ga.w, gb.x, gb.y, gb.z, gb.w};

    short8 hv[NEI]; uint2 hu[NEI];
    #pragma unroll
    for (int k = 0; k < NEI; ++k) {
        const uint8_t* row = hh + (size_t)gi[k] * HHROW;
        hv[k] = *reinterpret_cast<const short8*>(row + g8 * 2);
        hu[k] = *reinterpret_cast<const uint2*>(row + 320 + g8);
    }

    float s[8], g[8];
    #pragma unroll
    for (int j = 0; j < 8; ++j) { s[j] = 0.f; g[j] = 0.f; }
    #pragma unroll
    for (int k = 0; k < NEI; ++k) {
        #pragma unroll
        for (int j = 0; j < 8; ++j) {
            const uint32_t hub = ((j < 4 ? hu[k].x >> (8 * j) : hu[k].y >> (8 * (j - 4))) & 0xFFu);
            const float h = bf2f((ushort)hv[k][j]);
            const float rg = sigf(bf2f((ushort)xr8[j]) + e5m2f(hub));
            s[j] += h;
            g[j] = fmaf(rg, h, g[j]);
        }
    }
    short8 sv, gv;
    #pragma unroll
    for (int j = 0; j < 8; ++j) { sv[j] = (short)f2bf(s[j]); gv[j] = (short)f2bf(g[j]); }
    *reinterpret_cast<short8*>(&sumh[(size_t)n * HID + g8]) = sv;
    *reinterpret_cast<short8*>(&sgh [(size_t)n * HID + g8]) = gv;
}

// ---------------- zh-GEMM + gate update (+ next-iter Ur-GEMM), 32-row tiles.
// grid NBLK (6.1 blocks/CU), LDS 21.5 KB, epilogue addends via frag-linear ushort4.
__global__ __launch_bounds__(256, 6) void gemm_zh(
    const ushort* __restrict__ sumh, const ushort* __restrict__ sgh,
    const ushort* __restrict__ xzf, const ushort* __restrict__ xhf,
    const ushort* __restrict__ wpack, const float* __restrict__ Ur_b,
    float*   __restrict__ out,          // written only if write_out
    uint8_t* __restrict__ hh_next,      // written only if do_next
    int write_out, int do_next, int M)
{
    __shared__ ushort Az[32 * AST];     // bf16 sumh, later bf16 h_out
    __shared__ ushort Ag[32 * AST];     // bf16 sgh, later fp8 hU_out bytes
    const int t = threadIdx.x, m0 = blockIdx.x * 32;

    for (int idx = t; idx < 32 * 20; idx += 256) {
        const int m = idx / 20, g8 = (idx % 20) * 8;
        short8 a = (short8){0,0,0,0,0,0,0,0}, b = a;
        if (m0 + m < M) {
            a = *reinterpret_cast<const short8*>(&sumh[(size_t)(m0 + m) * HID + g8]);
            b = *reinterpret_cast<const short8*>(&sgh [(size_t)(m0 + m) * HID + g8]);
        }
        *reinterpret_cast<short8*>(&Az[m * AST + g8]) = a;
        *reinterpret_cast<short8*>(&Ag[m * AST + g8]) = b;
    }
    __syncthreads();

    const int w = t >> 6, l = t & 63;
    const int wrow = w & 1, wcol = w >> 1;
    const int ar = wrow * 16 + (l & 15);
    const int kg = (l >> 4) << 3;

    f32x4 accz[5], acch[5];
    #pragma unroll
    for (int nt = 0; nt < 5; ++nt) {
        accz[nt] = (f32x4){0.f, 0.f, 0.f, 0.f};
        acch[nt] = (f32x4){0.f, 0.f, 0.f, 0.f};
    }

    {
        const short8* ZH = reinterpret_cast<const short8*>(wpack + WPZH);
        const short8* HHm = reinterpret_cast<const short8*>(wpack + WPHH);
        #pragma unroll
        for (int ks = 0; ks < 5; ++ks) {
            const short8 az = *reinterpret_cast<const short8*>(&Az[ar * AST + ks * 32 + kg]);
            const short8 ag = *reinterpret_cast<const short8*>(&Ag[ar * AST + ks * 32 + kg]);
            #pragma unroll
            for (int nt = 0; nt < 5; ++nt) {
                const int bi = (((wcol * 5 + nt) * 5 + ks) << 6) + l;
                accz[nt] = __builtin_amdgcn_mfma_f32_16x16x32_bf16(az, ZH[bi], accz[nt], 0, 0, 0);
                acch[nt] = __builtin_amdgcn_mfma_f32_16x16x32_bf16(ag, HHm[bi], acch[nt], 0, 0, 0);
            }
        }
    }

    // epilogue: v = (1-z)*sumh + z*tanh(.)  (frag-linear xz/xh addends)
    const int r0l = wrow * 16 + ((l >> 4) << 2);
    const int cb = l & 15;
    const size_t fragbase = ((size_t)blockIdx.x * 2 + wrow) * 2 + wcol;
    #pragma unroll
    for (int nt = 0; nt < 5; ++nt) {
        const int col = (wcol * 5 + nt) * 16 + cb;
        const ushort4v xz4 = *reinterpret_cast<const ushort4v*>(&xzf[((fragbase * 5 + nt) * 64 + l) * 4]);
        const ushort4v xh4 = *reinterpret_cast<const ushort4v*>(&xhf[((fragbase * 5 + nt) * 64 + l) * 4]);
        #pragma unroll
        for (int r = 0; r < 4; ++r) {
            const int m = m0 + r0l + r;
            float v = 0.f;
            if (m < M) {
                const float z = sigf(accz[nt][r] + bf2f(xz4[r]));
                const float p = tanhfast(acch[nt][r] + bf2f(xh4[r]));
                const float s = bf2f(Az[(r0l + r) * AST + col]);
                v = (1.f - z) * s + z * p;
                if (m == 0) v = 0.f;
                if (write_out) out[(size_t)m * HID + col] = v;
            }
            accz[nt][r] = v;
        }
    }

    if (!do_next) return;

    __syncthreads();
    #pragma unroll
    for (int nt = 0; nt < 5; ++nt) {
        const int col = (wcol * 5 + nt) * 16 + cb;
        #pragma unroll
        for (int r = 0; r < 4; ++r)
            Az[(r0l + r) * AST + col] = f2bf(accz[nt][r]);   // bf16 h_out
    }
    __syncthreads();

    for (int idx = t; idx < 32 * 20; idx += 256) {
        const int m = idx / 20, g8 = (idx % 20) * 8;
        if (m0 + m < M)
            *reinterpret_cast<short8*>(hh_next + (size_t)(m0 + m) * HHROW + g8 * 2) =
                *reinterpret_cast<const short8*>(&Az[m * AST + g8]);
    }

    #pragma unroll
    for (int nt = 0; nt < 5; ++nt) acch[nt] = (f32x4){0.f, 0.f, 0.f, 0.f};
    {
        const short8* WH = reinterpret_cast<const short8*>(wpack + WPU);
        #pragma unroll
        for (int ks = 0; ks < 5; ++ks) {
            const short8 a = *reinterpret_cast<const short8*>(&Az[ar * AST + ks * 32 + kg]);
            #pragma unroll
            for (int nt = 0; nt < 5; ++nt)
                acch[nt] = __builtin_amdgcn_mfma_f32_16x16x32_bf16(a, WH[(((wcol * 5 + nt) * 5 + ks) << 6) + l], acch[nt], 0, 0, 0);
        }
    }
    __syncthreads();   // Ag MFMA reads long done; reuse as byte buffer
    uint8_t* Agb = reinterpret_cast<uint8_t*>(Ag);
    #pragma unroll
    for (int nt = 0; nt < 5; ++nt) {
        const int col = (wcol * 5 + nt) * 16 + cb;
        const float b = Ur_b[col];
        #pragma unroll
        for (int r = 0; r < 4; ++r)
            Agb[(r0l + r) * 160 + col] = (uint8_t)f2e5(acch[nt][r] + b);
    }
    __syncthreads();
    for (int idx = t; idx < 32 * 10; idx += 256) {
        const int m = idx / 10, g16 = (idx % 10) * 16;
        if (m0 + m < M)
            *reinterpret_cast<uint4*>(hh_next + (size_t)(m0 + m) * HHROW + 320 + g16) =
                *reinterpret_cast<const uint4*>(&Agb[m * 160 + g16]);
    }
}

extern "C" void kernel_launch(void* const* d_in, const int* in_sizes, int n_in,
                              void* d_out, int out_size, void* d_ws, size_t ws_size,
                              hipStream_t stream)
{
    const float* h0   = (const float*)d_in[0];
    const float* x    = (const float*)d_in[1];
    const int*   grf  = (const int*)  d_in[2];
    const float* Wz_w = (const float*)d_in[3];
    const float* Wz_b = (const float*)d_in[4];
    const float* Wr_w = (const float*)d_in[5];
    const float* Ur_w = (const float*)d_in[6];
    const float* Ur_b = (const float*)d_in[7];
    const float* Wh_w = (const float*)d_in[8];
    const float* Wh_b = (const float*)d_in[9];
    float* out = (float*)d_out;

    const size_t per  = (size_t)NM * HID;        // 8,000,000
    const size_t fsz  = (size_t)NBLK * 5120;     // frag-linear per-array ushorts
    ushort*  xr    = (ushort*)d_ws;                        // 16 MB
    ushort*  xzf   = xr + per;                             // 16 MB
    ushort*  xhf   = xzf + fsz;                            // 16 MB
    uint8_t* hh_a  = (uint8_t*)(xhf + fsz);                // 24 MB
    uint8_t* hh_b  = hh_a + (size_t)NM * HHROW;            // 24 MB
    ushort*  sumh  = (ushort*)(hh_b + (size_t)NM * HHROW); // 16 MB
    ushort*  sgh   = sumh + per;                           // 16 MB
    ushort*  wpack = sgh + per;                            // 0.3 MB

    const dim3 gb64((NM + 63) / 64), gt(256);              // 782 blocks
    const dim3 zb(NBLK);                                   // 1563 blocks
    const dim3 sb(NM / 16), st(320);                       // 3125 blocks

    pack_weights<<<6, 256, 0, stream>>>(Wz_w, Wr_w, Ur_w, Wh_w, wpack);
    xproj_gemm<<<dim3(NBLK, 3), gt, 0, stream>>>(x, wpack, Wz_b, Wh_b, xr, xzf, xhf, NM);
    hU0_gemm<<<gb64, gt, 0, stream>>>(h0, wpack, Ur_b, hh_a, NM);

    gather_kernel<<<sb, st, 0, stream>>>(hh_a, xr, grf, sumh, sgh);
    gemm_zh<<<zb, gt, 0, stream>>>(sumh, sgh, xzf, xhf, wpack, Ur_b, out, hh_b, 0, 1, NM);
    gather_kernel<<<sb, st, 0, stream>>>(hh_b, xr, grf, sumh, sgh);
    gemm_zh<<<zb, gt, 0, stream>>>(sumh, sgh, xzf, xhf, wpack, Ur_b, out, hh_a, 0, 1, NM);
    gather_kernel<<<sb, st, 0, stream>>>(hh_a, xr, grf, sumh, sgh);
    gemm_zh<<<zb, gt, 0, stream>>>(sumh, sgh, xzf, xhf, wpack, Ur_b, out, hh_b, 1, 0, NM);
}

// Round 10
// 306.534 us; speedup vs baseline: 1.9050x; 1.2357x over previous
//
#include <hip/hip_runtime.h>
#include <hip/hip_fp16.h>
#include <cstddef>
#include <cstdint>

#define NM  50000
#define HID 160
#define NEI 8
#define AST 168     // padded LDS row stride (ushorts)
#define HHROW 480   // hh row bytes: 320 B bf16 h | 160 B fp8(e5m2) hU
#define NBLK 1563   // ceil(50000/32) 32-row tiles

// packed-weight offsets (ushort units), bf16 hi-only
#define WPX   0        // [30nt][5ks][64l][8]: Wzx | Wr | Whx
#define WPU   76800    // Ur
#define WPZH  102400   // Wzh
#define WPHH  128000   // Whh

typedef __attribute__((ext_vector_type(8))) short  short8;
typedef __attribute__((ext_vector_type(4))) float  f32x4;
typedef __attribute__((ext_vector_type(4))) ushort ushort4v;

__device__ __forceinline__ ushort f2bf(float f) {
    union { float f; uint32_t u; } v; v.f = f;
    const uint32_t r = v.u + 0x7fffu + ((v.u >> 16) & 1u);   // RNE
    return (ushort)(r >> 16);
}
__device__ __forceinline__ float bf2f(ushort h) {
    union { uint32_t u; float f; } v; v.u = ((uint32_t)h) << 16;
    return v.f;
}
// fp8 e5m2 == truncated f16
__device__ __forceinline__ uint32_t f2e5(float v) {
    union { __half h; ushort u; } c; c.h = __float2half(v);
    const ushort r = c.u + 0x7F + ((c.u >> 8) & 1);
    return (uint32_t)(r >> 8) & 0xFF;
}
__device__ __forceinline__ float e5m2f(uint32_t byte) {
    union { ushort u; __half h; } c; c.u = (ushort)(byte << 8);
    return __half2float(c.h);
}
__device__ __forceinline__ float sigf(float v)     { return 1.f / (1.f + __expf(-v)); }
__device__ __forceinline__ float tanhfast(float v) { return 2.f / (1.f + __expf(-2.f * v)) - 1.f; }

// A-frag-linear slot for element block (row n, cols [8*c8, 8*c8+8)), 32-row tiles
__device__ __forceinline__ size_t afrag_idx(int n, int c8) {
    const int tile = n >> 5, mrow = n & 31;
    const int wrow = mrow >> 4, q = c8 >> 2;
    const int lane = (mrow & 15) + ((c8 & 3) << 4);
    return (size_t)((tile * 2 + wrow) * 5 + q) * 64 + lane;
}

// ---------------- weight pre-pack into MFMA B-fragment-linear order (bf16 hi only)
__global__ __launch_bounds__(256) void pack_weights(
    const float* __restrict__ Wz, const float* __restrict__ Wr,
    const float* __restrict__ Ur, const float* __restrict__ Wh,
    ushort* __restrict__ dst)
{
    const float* src; int off, stride, ntb = 0; ushort* hi;
    switch (blockIdx.x) {
        case 0:  src = Wz; off = 0;   stride = 320; hi = dst + WPX;  ntb = 0;  break;
        case 1:  src = Wr; off = 0;   stride = 160; hi = dst + WPX;  ntb = 10; break;
        case 2:  src = Wh; off = 0;   stride = 320; hi = dst + WPX;  ntb = 20; break;
        case 3:  src = Ur; off = 0;   stride = 160; hi = dst + WPU;  break;
        case 4:  src = Wz; off = 160; stride = 320; hi = dst + WPZH; break;
        default: src = Wh; off = 160; stride = 320; hi = dst + WPHH; break;
    }
    const int t = threadIdx.x, l = t & 63;
    for (int tile = t >> 6; tile < 50; tile += 4) {
        const int ntl = tile / 5, ks = tile % 5;
        const int n = ntl * 16 + (l & 15);
        const int k = ks * 32 + (l >> 4) * 8;
        const float* s = &src[(size_t)n * stride + off + k];
        const size_t o = ((size_t)((ntb + ntl) * 5 + ks) * 64 + l) * 8;
        #pragma unroll
        for (int j = 0; j < 8; ++j) hi[o + j] = f2bf(s[j]);
    }
}

// ---------------- x projections, grid (NBLK, 3), 32-row tiles.
__global__ __launch_bounds__(256) void xproj_gemm(
    const float* __restrict__ x, const ushort* __restrict__ wpack,
    const float* __restrict__ Wz_b, const float* __restrict__ Wh_b,
    ushort* __restrict__ xr, ushort* __restrict__ xzf, ushort* __restrict__ xhf,
    int M)
{
    __shared__ ushort As[32 * AST];
    const int t = threadIdx.x, m0 = blockIdx.x * 32, cy = blockIdx.y;

    for (int idx = t; idx < 32 * 40; idx += 256) {
        const int m = idx / 40, k4 = (idx % 40) * 4;
        float4 v = make_float4(0.f, 0.f, 0.f, 0.f);
        if (m0 + m < M) v = *reinterpret_cast<const float4*>(&x[(size_t)(m0 + m) * HID + k4]);
        ushort4 hv;
        hv.x = f2bf(v.x); hv.y = f2bf(v.y); hv.z = f2bf(v.z); hv.w = f2bf(v.w);
        *reinterpret_cast<ushort4*>(&As[m * AST + k4]) = hv;
    }
    __syncthreads();

    const int w = t >> 6, l = t & 63;
    const int wrow = w & 1, wcol = w >> 1;
    const int ar = wrow * 16 + (l & 15);
    const int kg = (l >> 4) << 3;

    f32x4 acc[5];
    #pragma unroll
    for (int nt = 0; nt < 5; ++nt) acc[nt] = (f32x4){0.f, 0.f, 0.f, 0.f};

    const short8* WH = reinterpret_cast<const short8*>(wpack + WPX + cy * 25600);

    #pragma unroll
    for (int ks = 0; ks < 5; ++ks) {
        const short8 a = *reinterpret_cast<const short8*>(&As[ar * AST + ks * 32 + kg]);
        #pragma unroll
        for (int nt = 0; nt < 5; ++nt)
            acc[nt] = __builtin_amdgcn_mfma_f32_16x16x32_bf16(a, WH[(((wcol * 5 + nt) * 5 + ks) << 6) + l], acc[nt], 0, 0, 0);
    }

    const int r0l = wrow * 16 + ((l >> 4) << 2);
    const int cb = l & 15;

    if (cy == 1) {
        __syncthreads();
        #pragma unroll
        for (int nt = 0; nt < 5; ++nt) {
            const int col = (wcol * 5 + nt) * 16 + cb;
            #pragma unroll
            for (int r = 0; r < 4; ++r)
                As[(r0l + r) * AST + col] = f2bf(acc[nt][r]);
        }
        __syncthreads();
        for (int idx = t; idx < 32 * 20; idx += 256) {
            const int m = idx / 20, g8 = (idx % 20) * 8;
            if (m0 + m < M)
                *reinterpret_cast<short8*>(&xr[(size_t)(m0 + m) * HID + g8]) =
                    *reinterpret_cast<const short8*>(&As[m * AST + g8]);
        }
    } else {
        const float* bias = (cy == 0) ? Wz_b : Wh_b;
        ushort* dst = (cy == 0) ? xzf : xhf;
        const size_t fragbase = ((size_t)blockIdx.x * 2 + wrow) * 2 + wcol;
        #pragma unroll
        for (int nt = 0; nt < 5; ++nt) {
            const float b = bias[(wcol * 5 + nt) * 16 + cb];
            ushort4v v;
            #pragma unroll
            for (int r = 0; r < 4; ++r) v[r] = f2bf(acc[nt][r] + b);
            *reinterpret_cast<ushort4v*>(&dst[((fragbase * 5 + nt) * 64 + l) * 4]) = v;
        }
    }
}

// ---------------- hU0: hh[n] = [bf16(h0) | e5m2(h0 @ Ur^T + Ur_b)]
__global__ __launch_bounds__(256, 3) void hU0_gemm(
    const float* __restrict__ h0, const ushort* __restrict__ wpack,
    const float* __restrict__ Ur_b, uint8_t* __restrict__ hh, int M)
{
    __shared__ ushort As[64 * AST];
    __shared__ uint8_t HuB[64 * 160];
    const int t = threadIdx.x, m0 = blockIdx.x * 64;

    for (int idx = t; idx < 64 * 40; idx += 256) {
        const int m = idx / 40, k4 = (idx % 40) * 4;
        float4 v = make_float4(0.f, 0.f, 0.f, 0.f);
        if (m0 + m < M) v = *reinterpret_cast<const float4*>(&h0[(size_t)(m0 + m) * HID + k4]);
        ushort4 hv;
        hv.x = f2bf(v.x); hv.y = f2bf(v.y); hv.z = f2bf(v.z); hv.w = f2bf(v.w);
        *reinterpret_cast<ushort4*>(&As[m * AST + k4]) = hv;
    }
    __syncthreads();

    for (int idx = t; idx < 64 * 20; idx += 256) {
        const int m = idx / 20, g8 = (idx % 20) * 8;
        if (m0 + m < M)
            *reinterpret_cast<short8*>(hh + (size_t)(m0 + m) * HHROW + g8 * 2) =
                *reinterpret_cast<const short8*>(&As[m * AST + g8]);
    }

    const int w = t >> 6, l = t & 63;
    const int ar = (w << 4) + (l & 15);
    const int kg = (l >> 4) << 3;

    f32x4 acc[10];
    #pragma unroll
    for (int nt = 0; nt < 10; ++nt) acc[nt] = (f32x4){0.f, 0.f, 0.f, 0.f};

    const short8* WH = reinterpret_cast<const short8*>(wpack + WPU);

    #pragma unroll
    for (int ks = 0; ks < 5; ++ks) {
        const short8 a = *reinterpret_cast<const short8*>(&As[ar * AST + ks * 32 + kg]);
        #pragma unroll
        for (int nt = 0; nt < 10; ++nt)
            acc[nt] = __builtin_amdgcn_mfma_f32_16x16x32_bf16(a, WH[(nt * 5 + ks) * 64 + l], acc[nt], 0, 0, 0);
    }

    const int r0l = (w << 4) + ((l >> 4) << 2);
    const int cb = l & 15;
    #pragma unroll
    for (int nt = 0; nt < 10; ++nt) {
        const int col = nt * 16 + cb;
        const float b = Ur_b[col];
        #pragma unroll
        for (int r = 0; r < 4; ++r)
            HuB[(r0l + r) * 160 + col] = (uint8_t)f2e5(acc[nt][r] + b);
    }
    __syncthreads();
    for (int idx = t; idx < 64 * 10; idx += 256) {
        const int m = idx / 10, g16 = (idx % 10) * 16;
        if (m0 + m < M)
            *reinterpret_cast<uint4*>(hh + (size_t)(m0 + m) * HHROW + 320 + g16) =
                *reinterpret_cast<const uint4*>(&HuB[m * 160 + g16]);
    }
}

// ---------------- standalone gather -> writes sumh/sgh in A-frag-linear layout
__global__ __launch_bounds__(320) void gather_kernel(
    const uint8_t* __restrict__ hh,     // [N][480B]: bf16 h | e5m2 hU
    const ushort* __restrict__ xr,      // [N][160] bf16
    const int*    __restrict__ graph,
    ushort* __restrict__ sumhf,         // frag-linear bf16
    ushort* __restrict__ sghf)          // frag-linear bf16
{
    const int t = threadIdx.x;
    const int n = blockIdx.x * 16 + t / 20;     // 3125*16 == 50000 exactly
    const int c8 = t % 20, g8 = c8 * 8;

    const short8 xr8 = *reinterpret_cast<const short8*>(&xr[(size_t)n * HID + g8]);
    const int4 ga = *reinterpret_cast<const int4*>(&graph[(size_t)n * NEI]);
    const int4 gb = *reinterpret_cast<const int4*>(&graph[(size_t)n * NEI + 4]);
    const int gi[8] = {ga.x, ga.y, ga.z, ga.w, gb.x, gb.y, gb.z, gb.w};

    short8 hv[NEI]; uint2 hu[NEI];
    #pragma unroll
    for (int k = 0; k < NEI; ++k) {
        const uint8_t* row = hh + (size_t)gi[k] * HHROW;
        hv[k] = *reinterpret_cast<const short8*>(row + g8 * 2);
        hu[k] = *reinterpret_cast<const uint2*>(row + 320 + g8);
    }

    float s[8], g[8];
    #pragma unroll
    for (int j = 0; j < 8; ++j) { s[j] = 0.f; g[j] = 0.f; }
    #pragma unroll
    for (int k = 0; k < NEI; ++k) {
        #pragma unroll
        for (int j = 0; j < 8; ++j) {
            const uint32_t hub = ((j < 4 ? hu[k].x >> (8 * j) : hu[k].y >> (8 * (j - 4))) & 0xFFu);
            const float h = bf2f((ushort)hv[k][j]);
            const float rg = sigf(bf2f((ushort)xr8[j]) + e5m2f(hub));
            s[j] += h;
            g[j] = fmaf(rg, h, g[j]);
        }
    }
    short8 sv, gv;
    #pragma unroll
    for (int j = 0; j < 8; ++j) { sv[j] = (short)f2bf(s[j]); gv[j] = (short)f2bf(g[j]); }
    const size_t fi = afrag_idx(n, c8);
    reinterpret_cast<short8*>(sumhf)[fi] = sv;
    reinterpret_cast<short8*>(sghf)[fi] = gv;
}

// ---------------- zh-GEMM + update (+ next-iter Ur tail), frag-direct A operands.
// No staging barrier: A-frags, addend-frags all loaded straight from global at
// entry; sum_h at C-layout recovered via identity-MFMA transpose (exact).
__global__ __launch_bounds__(256, 3) void gemm_zh(
    const ushort* __restrict__ sumhf, const ushort* __restrict__ sghf,
    const ushort* __restrict__ xzf, const ushort* __restrict__ xhf,
    const ushort* __restrict__ wpack, const float* __restrict__ Ur_b,
    float*   __restrict__ out,          // written only if write_out
    uint8_t* __restrict__ hh_next,      // written only if do_next
    int write_out, int do_next, int M)
{
    __shared__ ushort Az[32 * AST];     // tail only: h_out repack, then e5m2 bytes
    const int t = threadIdx.x, tile = blockIdx.x, m0 = tile * 32;
    const int w = t >> 6, l = t & 63;
    const int wrow = w & 1, wcol = w >> 1;

    // ---- issue ALL global reads up front (no barrier before MFMA) ----
    const size_t abase = (size_t)(tile * 2 + wrow) * 5 * 64 + l;
    const short8* SA = reinterpret_cast<const short8*>(sumhf);
    const short8* SG = reinterpret_cast<const short8*>(sghf);
    short8 az[5], ag[5];
    #pragma unroll
    for (int ks = 0; ks < 5; ++ks) {
        az[ks] = SA[abase + (size_t)ks * 64];
        ag[ks] = SG[abase + (size_t)ks * 64];
    }
    const size_t fragbase = ((size_t)tile * 2 + wrow) * 2 + wcol;
    ushort4v xz4[5], xh4[5];
    #pragma unroll
    for (int nt = 0; nt < 5; ++nt) {
        xz4[nt] = *reinterpret_cast<const ushort4v*>(&xzf[((fragbase * 5 + nt) * 64 + l) * 4]);
        xh4[nt] = *reinterpret_cast<const ushort4v*>(&xhf[((fragbase * 5 + nt) * 64 + l) * 4]);
    }

    // ---- identity B-frags for A->C transpose (one-hot bf16 1.0) ----
    const int hot0 = ((l >> 4) == ((l >> 3) & 1))     ? (l & 7) : -1;
    const int hot1 = ((l >> 4) == 2 + ((l >> 3) & 1)) ? (l & 7) : -1;
    short8 IF0, IF1;
    #pragma unroll
    for (int j = 0; j < 8; ++j) {
        IF0[j] = (short)((j == hot0) ? 0x3F80 : 0);
        IF1[j] = (short)((j == hot1) ? 0x3F80 : 0);
    }

    f32x4 accz[5], acch[5], accs[5];
    #pragma unroll
    for (int nt = 0; nt < 5; ++nt) {
        accz[nt] = (f32x4){0.f, 0.f, 0.f, 0.f};
        acch[nt] = (f32x4){0.f, 0.f, 0.f, 0.f};
        accs[nt] = (f32x4){0.f, 0.f, 0.f, 0.f};
    }

    {
        const short8* ZH = reinterpret_cast<const short8*>(wpack + WPZH);
        const short8* HHm = reinterpret_cast<const short8*>(wpack + WPHH);
        #pragma unroll
        for (int ks = 0; ks < 5; ++ks) {
            #pragma unroll
            for (int nt = 0; nt < 5; ++nt) {
                const int bi = (((wcol * 5 + nt) * 5 + ks) << 6) + l;
                accz[nt] = __builtin_amdgcn_mfma_f32_16x16x32_bf16(az[ks], ZH[bi], accz[nt], 0, 0, 0);
                acch[nt] = __builtin_amdgcn_mfma_f32_16x16x32_bf16(ag[ks], HHm[bi], acch[nt], 0, 0, 0);
            }
        }
        // sum_h -> C layout via identity (ct = wcol*5+nt; q=ct>>1, p=ct&1)
        if (wcol == 0) {
            accs[0] = __builtin_amdgcn_mfma_f32_16x16x32_bf16(az[0], IF0, accs[0], 0, 0, 0);
            accs[1] = __builtin_amdgcn_mfma_f32_16x16x32_bf16(az[0], IF1, accs[1], 0, 0, 0);
            accs[2] = __builtin_amdgcn_mfma_f32_16x16x32_bf16(az[1], IF0, accs[2], 0, 0, 0);
            accs[3] = __builtin_amdgcn_mfma_f32_16x16x32_bf16(az[1], IF1, accs[3], 0, 0, 0);
            accs[4] = __builtin_amdgcn_mfma_f32_16x16x32_bf16(az[2], IF0, accs[4], 0, 0, 0);
        } else {
            accs[0] = __builtin_amdgcn_mfma_f32_16x16x32_bf16(az[2], IF1, accs[0], 0, 0, 0);
            accs[1] = __builtin_amdgcn_mfma_f32_16x16x32_bf16(az[3], IF0, accs[1], 0, 0, 0);
            accs[2] = __builtin_amdgcn_mfma_f32_16x16x32_bf16(az[3], IF1, accs[2], 0, 0, 0);
            accs[3] = __builtin_amdgcn_mfma_f32_16x16x32_bf16(az[4], IF0, accs[3], 0, 0, 0);
            accs[4] = __builtin_amdgcn_mfma_f32_16x16x32_bf16(az[4], IF1, accs[4], 0, 0, 0);
        }
    }

    // ---- epilogue: v = (1-z)*sum_h + z*tanh(.) ----
    const int r0l = wrow * 16 + ((l >> 4) << 2);
    const int cb = l & 15;
    #pragma unroll
    for (int nt = 0; nt < 5; ++nt) {
        const int col = (wcol * 5 + nt) * 16 + cb;
        #pragma unroll
        for (int r = 0; r < 4; ++r) {
            const int m = m0 + r0l + r;
            float v = 0.f;
            if (m < M) {
                const float z = sigf(accz[nt][r] + bf2f(xz4[nt][r]));
                const float p = tanhfast(acch[nt][r] + bf2f(xh4[nt][r]));
                v = (1.f - z) * accs[nt][r] + z * p;
                if (m == 0) v = 0.f;
                if (write_out) out[(size_t)m * HID + col] = v;
            }
            accz[nt][r] = v;
        }
    }

    if (!do_next) return;

    // ---- tail: h_out -> row-major store + Ur-GEMM + e5m2 store ----
    #pragma unroll
    for (int nt = 0; nt < 5; ++nt) {
        const int col = (wcol * 5 + nt) * 16 + cb;
        #pragma unroll
        for (int r = 0; r < 4; ++r)
            Az[(r0l + r) * AST + col] = f2bf(accz[nt][r]);
    }
    __syncthreads();

    for (int idx = t; idx < 32 * 20; idx += 256) {
        const int m = idx / 20, g8 = (idx % 20) * 8;
        if (m0 + m < M)
            *reinterpret_cast<short8*>(hh_next + (size_t)(m0 + m) * HHROW + g8 * 2) =
                *reinterpret_cast<const short8*>(&Az[m * AST + g8]);
    }

    const int ar = wrow * 16 + (l & 15);
    const int kg = (l >> 4) << 3;
    #pragma unroll
    for (int nt = 0; nt < 5; ++nt) acch[nt] = (f32x4){0.f, 0.f, 0.f, 0.f};
    {
        const short8* WH = reinterpret_cast<const short8*>(wpack + WPU);
        #pragma unroll
        for (int ks = 0; ks < 5; ++ks) {
            const short8 a = *reinterpret_cast<const short8*>(&Az[ar * AST + ks * 32 + kg]);
            #pragma unroll
            for (int nt = 0; nt < 5; ++nt)
                acch[nt] = __builtin_amdgcn_mfma_f32_16x16x32_bf16(a, WH[(((wcol * 5 + nt) * 5 + ks) << 6) + l], acch[nt], 0, 0, 0);
        }
    }
    __syncthreads();   // all Az reads done; overlay byte buffer
    uint8_t* Agb = reinterpret_cast<uint8_t*>(Az);
    #pragma unroll
    for (int nt = 0; nt < 5; ++nt) {
        const int col = (wcol * 5 + nt) * 16 + cb;
        const float b = Ur_b[col];
        #pragma unroll
        for (int r = 0; r < 4; ++r)
            Agb[(r0l + r) * 160 + col] = (uint8_t)f2e5(acch[nt][r] + b);
    }
    __syncthreads();
    for (int idx = t; idx < 32 * 10; idx += 256) {
        const int m = idx / 10, g16 = (idx % 10) * 16;
        if (m0 + m < M)
            *reinterpret_cast<uint4*>(hh_next + (size_t)(m0 + m) * HHROW + 320 + g16) =
                *reinterpret_cast<const uint4*>(&Agb[m * 160 + g16]);
    }
}

extern "C" void kernel_launch(void* const* d_in, const int* in_sizes, int n_in,
                              void* d_out, int out_size, void* d_ws, size_t ws_size,
                              hipStream_t stream)
{
    const float* h0   = (const float*)d_in[0];
    const float* x    = (const float*)d_in[1];
    const int*   grf  = (const int*)  d_in[2];
    const float* Wz_w = (const float*)d_in[3];
    const float* Wz_b = (const float*)d_in[4];
    const float* Wr_w = (const float*)d_in[5];
    const float* Ur_w = (const float*)d_in[6];
    const float* Ur_b = (const float*)d_in[7];
    const float* Wh_w = (const float*)d_in[8];
    const float* Wh_b = (const float*)d_in[9];
    float* out = (float*)d_out;

    const size_t per  = (size_t)NM * HID;        // 8,000,000
    const size_t fsz  = (size_t)NBLK * 5120;     // frag-linear array ushorts (xz/xh and sumh/sgh)
    ushort*  xr    = (ushort*)d_ws;                        // 16 MB
    ushort*  xzf   = xr + per;                             // 16 MB
    ushort*  xhf   = xzf + fsz;                            // 16 MB
    uint8_t* hh_a  = (uint8_t*)(xhf + fsz);                // 24 MB
    uint8_t* hh_b  = hh_a + (size_t)NM * HHROW;            // 24 MB
    ushort*  sumhf = (ushort*)(hh_b + (size_t)NM * HHROW); // 16 MB
    ushort*  sghf  = sumhf + fsz;                          // 16 MB
    ushort*  wpack = sghf + fsz;                           // 0.3 MB

    const dim3 gb64((NM + 63) / 64), gt(256);              // 782 blocks
    const dim3 zb(NBLK);                                   // 1563 blocks
    const dim3 sb(NM / 16), st(320);                       // 3125 blocks

    pack_weights<<<6, 256, 0, stream>>>(Wz_w, Wr_w, Ur_w, Wh_w, wpack);
    xproj_gemm<<<dim3(NBLK, 3), gt, 0, stream>>>(x, wpack, Wz_b, Wh_b, xr, xzf, xhf, NM);
    hU0_gemm<<<gb64, gt, 0, stream>>>(h0, wpack, Ur_b, hh_a, NM);

    gather_kernel<<<sb, st, 0, stream>>>(hh_a, xr, grf, sumhf, sghf);
    gemm_zh<<<zb, gt, 0, stream>>>(sumhf, sghf, xzf, xhf, wpack, Ur_b, out, hh_b, 0, 1, NM);
    gather_kernel<<<sb, st, 0, stream>>>(hh_b, xr, grf, sumhf, sghf);
    gemm_zh<<<zb, gt, 0, stream>>>(sumhf, sghf, xzf, xhf, wpack, Ur_b, out, hh_a, 0, 1, NM);
    gather_kernel<<<sb, st, 0, stream>>>(hh_a, xr, grf, sumhf, sghf);
    gemm_zh<<<zb, gt, 0, stream>>>(sumhf, sghf, xzf, xhf, wpack, Ur_b, out, hh_b, 1, 0, NM);
}

// Round 11
// 295.545 us; speedup vs baseline: 1.9758x; 1.0372x over previous
//
#include <hip/hip_runtime.h>
#include <hip/hip_fp16.h>
#include <cstddef>
#include <cstdint>

#define NM  50000
#define HID 160
#define NEI 8
#define AST 168     // padded LDS row stride (ushorts)
#define HHROW 480   // hh row bytes: 320 B bf16 h | 160 B fp8(e5m2) hU
#define NBLK 1563   // ceil(50000/32) 32-row tiles

// packed-weight offsets (ushort units), bf16 hi-only
#define WPX   0        // [30nt][5ks][64l][8]: Wzx | Wr | Whx
#define WPU   76800    // Ur
#define WPZH  102400   // Wzh
#define WPHH  128000   // Whh

typedef __attribute__((ext_vector_type(8))) short  short8;
typedef __attribute__((ext_vector_type(4))) float  f32x4;
typedef __attribute__((ext_vector_type(2))) float  float2v;
typedef __attribute__((ext_vector_type(4))) ushort ushort4v;

__device__ __forceinline__ ushort f2bf(float f) {
    union { float f; uint32_t u; } v; v.f = f;
    const uint32_t r = v.u + 0x7fffu + ((v.u >> 16) & 1u);   // RNE
    return (ushort)(r >> 16);
}
__device__ __forceinline__ float bf2f(ushort h) {
    union { uint32_t u; float f; } v; v.u = ((uint32_t)h) << 16;
    return v.f;
}
// fp8 e5m2 == truncated f16 (OCP bf8)
__device__ __forceinline__ uint32_t f2e5(float v) {
    union { __half h; ushort u; } c; c.h = __float2half(v);
    const ushort r = c.u + 0x7F + ((c.u >> 8) & 1);
    return (uint32_t)(r >> 8) & 0xFF;
}
__device__ __forceinline__ float e5m2f(uint32_t byte) {
    union { ushort u; __half h; } c; c.u = (ushort)(byte << 8);
    return __half2float(c.h);
}

#if defined(__has_builtin)
#  if __has_builtin(__builtin_amdgcn_cvt_pk_f32_bf8)
#    define HAS_HW_BF8 1
#  else
#    define HAS_HW_BF8 0
#  endif
#else
#  define HAS_HW_BF8 0
#endif

// decode 2 e5m2 bytes (word HI of w) -> 2 f32; HW path is 1 VALU op
template<bool HI>
__device__ __forceinline__ float2v bf8pair(uint32_t w) {
#if HAS_HW_BF8
    return __builtin_amdgcn_cvt_pk_f32_bf8((int)w, HI);
#else
    const uint32_t sh = HI ? 16u : 0u;
    float2v r;
    r[0] = e5m2f((w >> sh) & 0xFFu);
    r[1] = e5m2f((w >> (sh + 8)) & 0xFFu);
    return r;
#endif
}

__device__ __forceinline__ float sigf(float v)     { return 1.f / (1.f + __expf(-v)); }
__device__ __forceinline__ float tanhfast(float v) { return 2.f / (1.f + __expf(-2.f * v)) - 1.f; }

// A-frag-linear slot for element block (row n, cols [8*c8, 8*c8+8)), 32-row tiles
__device__ __forceinline__ size_t afrag_idx(int n, int c8) {
    const int tile = n >> 5, mrow = n & 31;
    const int wrow = mrow >> 4, q = c8 >> 2;
    const int lane = (mrow & 15) + ((c8 & 3) << 4);
    return (size_t)((tile * 2 + wrow) * 5 + q) * 64 + lane;
}

// ---------------- weight pre-pack into MFMA B-fragment-linear order (bf16 hi only)
__global__ __launch_bounds__(256) void pack_weights(
    const float* __restrict__ Wz, const float* __restrict__ Wr,
    const float* __restrict__ Ur, const float* __restrict__ Wh,
    ushort* __restrict__ dst)
{
    const float* src; int off, stride, ntb = 0; ushort* hi;
    switch (blockIdx.x) {
        case 0:  src = Wz; off = 0;   stride = 320; hi = dst + WPX;  ntb = 0;  break;
        case 1:  src = Wr; off = 0;   stride = 160; hi = dst + WPX;  ntb = 10; break;
        case 2:  src = Wh; off = 0;   stride = 320; hi = dst + WPX;  ntb = 20; break;
        case 3:  src = Ur; off = 0;   stride = 160; hi = dst + WPU;  break;
        case 4:  src = Wz; off = 160; stride = 320; hi = dst + WPZH; break;
        default: src = Wh; off = 160; stride = 320; hi = dst + WPHH; break;
    }
    const int t = threadIdx.x, l = t & 63;
    for (int tile = t >> 6; tile < 50; tile += 4) {
        const int ntl = tile / 5, ks = tile % 5;
        const int n = ntl * 16 + (l & 15);
        const int k = ks * 32 + (l >> 4) * 8;
        const float* s = &src[(size_t)n * stride + off + k];
        const size_t o = ((size_t)((ntb + ntl) * 5 + ks) * 64 + l) * 8;
        #pragma unroll
        for (int j = 0; j < 8; ++j) hi[o + j] = f2bf(s[j]);
    }
}

// ---------------- x projections, grid (NBLK, 3), 32-row tiles.
__global__ __launch_bounds__(256) void xproj_gemm(
    const float* __restrict__ x, const ushort* __restrict__ wpack,
    const float* __restrict__ Wz_b, const float* __restrict__ Wh_b,
    ushort* __restrict__ xr, ushort* __restrict__ xzf, ushort* __restrict__ xhf,
    int M)
{
    __shared__ ushort As[32 * AST];
    const int t = threadIdx.x, m0 = blockIdx.x * 32, cy = blockIdx.y;

    for (int idx = t; idx < 32 * 40; idx += 256) {
        const int m = idx / 40, k4 = (idx % 40) * 4;
        float4 v = make_float4(0.f, 0.f, 0.f, 0.f);
        if (m0 + m < M) v = *reinterpret_cast<const float4*>(&x[(size_t)(m0 + m) * HID + k4]);
        ushort4 hv;
        hv.x = f2bf(v.x); hv.y = f2bf(v.y); hv.z = f2bf(v.z); hv.w = f2bf(v.w);
        *reinterpret_cast<ushort4*>(&As[m * AST + k4]) = hv;
    }
    __syncthreads();

    const int w = t >> 6, l = t & 63;
    const int wrow = w & 1, wcol = w >> 1;
    const int ar = wrow * 16 + (l & 15);
    const int kg = (l >> 4) << 3;

    f32x4 acc[5];
    #pragma unroll
    for (int nt = 0; nt < 5; ++nt) acc[nt] = (f32x4){0.f, 0.f, 0.f, 0.f};

    const short8* WH = reinterpret_cast<const short8*>(wpack + WPX + cy * 25600);

    #pragma unroll
    for (int ks = 0; ks < 5; ++ks) {
        const short8 a = *reinterpret_cast<const short8*>(&As[ar * AST + ks * 32 + kg]);
        #pragma unroll
        for (int nt = 0; nt < 5; ++nt)
            acc[nt] = __builtin_amdgcn_mfma_f32_16x16x32_bf16(a, WH[(((wcol * 5 + nt) * 5 + ks) << 6) + l], acc[nt], 0, 0, 0);
    }

    const int r0l = wrow * 16 + ((l >> 4) << 2);
    const int cb = l & 15;

    if (cy == 1) {
        __syncthreads();
        #pragma unroll
        for (int nt = 0; nt < 5; ++nt) {
            const int col = (wcol * 5 + nt) * 16 + cb;
            #pragma unroll
            for (int r = 0; r < 4; ++r)
                As[(r0l + r) * AST + col] = f2bf(acc[nt][r]);
        }
        __syncthreads();
        for (int idx = t; idx < 32 * 20; idx += 256) {
            const int m = idx / 20, g8 = (idx % 20) * 8;
            if (m0 + m < M)
                *reinterpret_cast<short8*>(&xr[(size_t)(m0 + m) * HID + g8]) =
                    *reinterpret_cast<const short8*>(&As[m * AST + g8]);
        }
    } else {
        const float* bias = (cy == 0) ? Wz_b : Wh_b;
        ushort* dst = (cy == 0) ? xzf : xhf;
        const size_t fragbase = ((size_t)blockIdx.x * 2 + wrow) * 2 + wcol;
        #pragma unroll
        for (int nt = 0; nt < 5; ++nt) {
            const float b = bias[(wcol * 5 + nt) * 16 + cb];
            ushort4v v;
            #pragma unroll
            for (int r = 0; r < 4; ++r) v[r] = f2bf(acc[nt][r] + b);
            *reinterpret_cast<ushort4v*>(&dst[((fragbase * 5 + nt) * 64 + l) * 4]) = v;
        }
    }
}

// ---------------- hU0: hh[n] = [bf16(h0) | e5m2(h0 @ Ur^T + Ur_b)]
__global__ __launch_bounds__(256, 3) void hU0_gemm(
    const float* __restrict__ h0, const ushort* __restrict__ wpack,
    const float* __restrict__ Ur_b, uint8_t* __restrict__ hh, int M)
{
    __shared__ ushort As[64 * AST];
    __shared__ uint8_t HuB[64 * 160];
    const int t = threadIdx.x, m0 = blockIdx.x * 64;

    for (int idx = t; idx < 64 * 40; idx += 256) {
        const int m = idx / 40, k4 = (idx % 40) * 4;
        float4 v = make_float4(0.f, 0.f, 0.f, 0.f);
        if (m0 + m < M) v = *reinterpret_cast<const float4*>(&h0[(size_t)(m0 + m) * HID + k4]);
        ushort4 hv;
        hv.x = f2bf(v.x); hv.y = f2bf(v.y); hv.z = f2bf(v.z); hv.w = f2bf(v.w);
        *reinterpret_cast<ushort4*>(&As[m * AST + k4]) = hv;
    }
    __syncthreads();

    for (int idx = t; idx < 64 * 20; idx += 256) {
        const int m = idx / 20, g8 = (idx % 20) * 8;
        if (m0 + m < M)
            *reinterpret_cast<short8*>(hh + (size_t)(m0 + m) * HHROW + g8 * 2) =
                *reinterpret_cast<const short8*>(&As[m * AST + g8]);
    }

    const int w = t >> 6, l = t & 63;
    const int ar = (w << 4) + (l & 15);
    const int kg = (l >> 4) << 3;

    f32x4 acc[10];
    #pragma unroll
    for (int nt = 0; nt < 10; ++nt) acc[nt] = (f32x4){0.f, 0.f, 0.f, 0.f};

    const short8* WH = reinterpret_cast<const short8*>(wpack + WPU);

    #pragma unroll
    for (int ks = 0; ks < 5; ++ks) {
        const short8 a = *reinterpret_cast<const short8*>(&As[ar * AST + ks * 32 + kg]);
        #pragma unroll
        for (int nt = 0; nt < 10; ++nt)
            acc[nt] = __builtin_amdgcn_mfma_f32_16x16x32_bf16(a, WH[(nt * 5 + ks) * 64 + l], acc[nt], 0, 0, 0);
    }

    const int r0l = (w << 4) + ((l >> 4) << 2);
    const int cb = l & 15;
    #pragma unroll
    for (int nt = 0; nt < 10; ++nt) {
        const int col = nt * 16 + cb;
        const float b = Ur_b[col];
        #pragma unroll
        for (int r = 0; r < 4; ++r)
            HuB[(r0l + r) * 160 + col] = (uint8_t)f2e5(acc[nt][r] + b);
    }
    __syncthreads();
    for (int idx = t; idx < 64 * 10; idx += 256) {
        const int m = idx / 10, g16 = (idx % 10) * 16;
        if (m0 + m < M)
            *reinterpret_cast<uint4*>(hh + (size_t)(m0 + m) * HHROW + 320 + g16) =
                *reinterpret_cast<const uint4*>(&HuB[m * 160 + g16]);
    }
}

// ---------------- standalone gather -> frag-linear sumh/sgh.
// launch_bounds(320,2): VGPR cap 256 so all 16 gathered loads stay in flight;
// HW bf8 decode (1 op / 2 elems) + pairwise bf16->f32 cuts VALU ~30%.
__global__ __launch_bounds__(320, 2) void gather_kernel(
    const uint8_t* __restrict__ hh,     // [N][480B]: bf16 h | e5m2 hU
    const ushort* __restrict__ xr,      // [N][160] bf16
    const int*    __restrict__ graph,
    ushort* __restrict__ sumhf,         // frag-linear bf16
    ushort* __restrict__ sghf)          // frag-linear bf16
{
    const int t = threadIdx.x;
    const int n = blockIdx.x * 16 + t / 20;     // 3125*16 == 50000 exactly
    const int c8 = t % 20, g8 = c8 * 8;

    const int4 ga = *reinterpret_cast<const int4*>(&graph[(size_t)n * NEI]);
    const int4 gb = *reinterpret_cast<const int4*>(&graph[(size_t)n * NEI + 4]);
    const int gi[8] = {ga.x, ga.y, ga.z, ga.w, gb.x, gb.y, gb.z, gb.w};

    const short8 xr8 = *reinterpret_cast<const short8*>(&xr[(size_t)n * HID + g8]);

    // issue all 16 gathered loads before any compute
    short8 hv[NEI]; uint2 hu[NEI];
    #pragma unroll
    for (int k = 0; k < NEI; ++k) {
        const uint8_t* row = hh + (size_t)gi[k] * HHROW;
        hv[k] = *reinterpret_cast<const short8*>(row + g8 * 2);
        hu[k] = *reinterpret_cast<const uint2*>(row + 320 + g8);
    }

    float xrf[8];
    #pragma unroll
    for (int j = 0; j < 8; ++j) xrf[j] = bf2f((ushort)xr8[j]);

    float s[8], g[8];
    #pragma unroll
    for (int j = 0; j < 8; ++j) { s[j] = 0.f; g[j] = 0.f; }

    #pragma unroll
    for (int k = 0; k < NEI; ++k) {
        const uint32_t* hw = reinterpret_cast<const uint32_t*>(&hv[k]);
        const float2v u01 = bf8pair<false>(hu[k].x);
        const float2v u23 = bf8pair<true >(hu[k].x);
        const float2v u45 = bf8pair<false>(hu[k].y);
        const float2v u67 = bf8pair<true >(hu[k].y);
        const float huf[8] = {u01[0], u01[1], u23[0], u23[1],
                              u45[0], u45[1], u67[0], u67[1]};
        #pragma unroll
        for (int i = 0; i < 4; ++i) {           // element pair (2i, 2i+1)
            union { uint32_t u; float f; } c0, c1;
            c0.u = hw[i] << 16;
            c1.u = hw[i] & 0xFFFF0000u;
            const float r0 = sigf(xrf[2 * i]     + huf[2 * i]);
            const float r1 = sigf(xrf[2 * i + 1] + huf[2 * i + 1]);
            s[2 * i]     += c0.f;
            s[2 * i + 1] += c1.f;
            g[2 * i]     = fmaf(r0, c0.f, g[2 * i]);
            g[2 * i + 1] = fmaf(r1, c1.f, g[2 * i + 1]);
        }
    }

    short8 sv, gv;
    #pragma unroll
    for (int j = 0; j < 8; ++j) { sv[j] = (short)f2bf(s[j]); gv[j] = (short)f2bf(g[j]); }
    const size_t fi = afrag_idx(n, c8);
    reinterpret_cast<short8*>(sumhf)[fi] = sv;
    reinterpret_cast<short8*>(sghf)[fi] = gv;
}

// ---------------- zh-GEMM + update (+ next-iter Ur tail), frag-direct A operands.
__global__ __launch_bounds__(256, 3) void gemm_zh(
    const ushort* __restrict__ sumhf, const ushort* __restrict__ sghf,
    const ushort* __restrict__ xzf, const ushort* __restrict__ xhf,
    const ushort* __restrict__ wpack, const float* __restrict__ Ur_b,
    float*   __restrict__ out,          // written only if write_out
    uint8_t* __restrict__ hh_next,      // written only if do_next
    int write_out, int do_next, int M)
{
    __shared__ ushort Az[32 * AST];     // tail only: h_out repack, then e5m2 bytes
    const int t = threadIdx.x, tile = blockIdx.x, m0 = tile * 32;
    const int w = t >> 6, l = t & 63;
    const int wrow = w & 1, wcol = w >> 1;

    // ---- issue ALL global reads up front (no barrier before MFMA) ----
    const size_t abase = (size_t)(tile * 2 + wrow) * 5 * 64 + l;
    const short8* SA = reinterpret_cast<const short8*>(sumhf);
    const short8* SG = reinterpret_cast<const short8*>(sghf);
    short8 az[5], ag[5];
    #pragma unroll
    for (int ks = 0; ks < 5; ++ks) {
        az[ks] = SA[abase + (size_t)ks * 64];
        ag[ks] = SG[abase + (size_t)ks * 64];
    }
    const size_t fragbase = ((size_t)tile * 2 + wrow) * 2 + wcol;
    ushort4v xz4[5], xh4[5];
    #pragma unroll
    for (int nt = 0; nt < 5; ++nt) {
        xz4[nt] = *reinterpret_cast<const ushort4v*>(&xzf[((fragbase * 5 + nt) * 64 + l) * 4]);
        xh4[nt] = *reinterpret_cast<const ushort4v*>(&xhf[((fragbase * 5 + nt) * 64 + l) * 4]);
    }

    // ---- identity B-frags for A->C transpose (one-hot bf16 1.0) ----
    const int hot0 = ((l >> 4) == ((l >> 3) & 1))     ? (l & 7) : -1;
    const int hot1 = ((l >> 4) == 2 + ((l >> 3) & 1)) ? (l & 7) : -1;
    short8 IF0, IF1;
    #pragma unroll
    for (int j = 0; j < 8; ++j) {
        IF0[j] = (short)((j == hot0) ? 0x3F80 : 0);
        IF1[j] = (short)((j == hot1) ? 0x3F80 : 0);
    }

    f32x4 accz[5], acch[5], accs[5];
    #pragma unroll
    for (int nt = 0; nt < 5; ++nt) {
        accz[nt] = (f32x4){0.f, 0.f, 0.f, 0.f};
        acch[nt] = (f32x4){0.f, 0.f, 0.f, 0.f};
        accs[nt] = (f32x4){0.f, 0.f, 0.f, 0.f};
    }

    {
        const short8* ZH = reinterpret_cast<const short8*>(wpack + WPZH);
        const short8* HHm = reinterpret_cast<const short8*>(wpack + WPHH);
        #pragma unroll
        for (int ks = 0; ks < 5; ++ks) {
            #pragma unroll
            for (int nt = 0; nt < 5; ++nt) {
                const int bi = (((wcol * 5 + nt) * 5 + ks) << 6) + l;
                accz[nt] = __builtin_amdgcn_mfma_f32_16x16x32_bf16(az[ks], ZH[bi], accz[nt], 0, 0, 0);
                acch[nt] = __builtin_amdgcn_mfma_f32_16x16x32_bf16(ag[ks], HHm[bi], acch[nt], 0, 0, 0);
            }
        }
        // sum_h -> C layout via identity (ct = wcol*5+nt; q=ct>>1, p=ct&1)
        if (wcol == 0) {
            accs[0] = __builtin_amdgcn_mfma_f32_16x16x32_bf16(az[0], IF0, accs[0], 0, 0, 0);
            accs[1] = __builtin_amdgcn_mfma_f32_16x16x32_bf16(az[0], IF1, accs[1], 0, 0, 0);
            accs[2] = __builtin_amdgcn_mfma_f32_16x16x32_bf16(az[1], IF0, accs[2], 0, 0, 0);
            accs[3] = __builtin_amdgcn_mfma_f32_16x16x32_bf16(az[1], IF1, accs[3], 0, 0, 0);
            accs[4] = __builtin_amdgcn_mfma_f32_16x16x32_bf16(az[2], IF0, accs[4], 0, 0, 0);
        } else {
            accs[0] = __builtin_amdgcn_mfma_f32_16x16x32_bf16(az[2], IF1, accs[0], 0, 0, 0);
            accs[1] = __builtin_amdgcn_mfma_f32_16x16x32_bf16(az[3], IF0, accs[1], 0, 0, 0);
            accs[2] = __builtin_amdgcn_mfma_f32_16x16x32_bf16(az[3], IF1, accs[2], 0, 0, 0);
            accs[3] = __builtin_amdgcn_mfma_f32_16x16x32_bf16(az[4], IF0, accs[3], 0, 0, 0);
            accs[4] = __builtin_amdgcn_mfma_f32_16x16x32_bf16(az[4], IF1, accs[4], 0, 0, 0);
        }
    }

    // ---- epilogue: v = (1-z)*sum_h + z*tanh(.) ----
    const int r0l = wrow * 16 + ((l >> 4) << 2);
    const int cb = l & 15;
    #pragma unroll
    for (int nt = 0; nt < 5; ++nt) {
        const int col = (wcol * 5 + nt) * 16 + cb;
        #pragma unroll
        for (int r = 0; r < 4; ++r) {
            const int m = m0 + r0l + r;
            float v = 0.f;
            if (m < M) {
                const float z = sigf(accz[nt][r] + bf2f(xz4[nt][r]));
                const float p = tanhfast(acch[nt][r] + bf2f(xh4[nt][r]));
                v = (1.f - z) * accs[nt][r] + z * p;
                if (m == 0) v = 0.f;
                if (write_out) out[(size_t)m * HID + col] = v;
            }
            accz[nt][r] = v;
        }
    }

    if (!do_next) return;

    // ---- tail: h_out -> row-major store + Ur-GEMM + e5m2 store ----
    #pragma unroll
    for (int nt = 0; nt < 5; ++nt) {
        const int col = (wcol * 5 + nt) * 16 + cb;
        #pragma unroll
        for (int r = 0; r < 4; ++r)
            Az[(r0l + r) * AST + col] = f2bf(accz[nt][r]);
    }
    __syncthreads();

    for (int idx = t; idx < 32 * 20; idx += 256) {
        const int m = idx / 20, g8 = (idx % 20) * 8;
        if (m0 + m < M)
            *reinterpret_cast<short8*>(hh_next + (size_t)(m0 + m) * HHROW + g8 * 2) =
                *reinterpret_cast<const short8*>(&Az[m * AST + g8]);
    }

    const int ar = wrow * 16 + (l & 15);
    const int kg = (l >> 4) << 3;
    #pragma unroll
    for (int nt = 0; nt < 5; ++nt) acch[nt] = (f32x4){0.f, 0.f, 0.f, 0.f};
    {
        const short8* WH = reinterpret_cast<const short8*>(wpack + WPU);
        #pragma unroll
        for (int ks = 0; ks < 5; ++ks) {
            const short8 a = *reinterpret_cast<const short8*>(&Az[ar * AST + ks * 32 + kg]);
            #pragma unroll
            for (int nt = 0; nt < 5; ++nt)
                acch[nt] = __builtin_amdgcn_mfma_f32_16x16x32_bf16(a, WH[(((wcol * 5 + nt) * 5 + ks) << 6) + l], acch[nt], 0, 0, 0);
        }
    }
    __syncthreads();   // all Az reads done; overlay byte buffer
    uint8_t* Agb = reinterpret_cast<uint8_t*>(Az);
    #pragma unroll
    for (int nt = 0; nt < 5; ++nt) {
        const int col = (wcol * 5 + nt) * 16 + cb;
        const float b = Ur_b[col];
        #pragma unroll
        for (int r = 0; r < 4; ++r)
            Agb[(r0l + r) * 160 + col] = (uint8_t)f2e5(acch[nt][r] + b);
    }
    __syncthreads();
    for (int idx = t; idx < 32 * 10; idx += 256) {
        const int m = idx / 10, g16 = (idx % 10) * 16;
        if (m0 + m < M)
            *reinterpret_cast<uint4*>(hh_next + (size_t)(m0 + m) * HHROW + 320 + g16) =
                *reinterpret_cast<const uint4*>(&Agb[m * 160 + g16]);
    }
}

extern "C" void kernel_launch(void* const* d_in, const int* in_sizes, int n_in,
                              void* d_out, int out_size, void* d_ws, size_t ws_size,
                              hipStream_t stream)
{
    const float* h0   = (const float*)d_in[0];
    const float* x    = (const float*)d_in[1];
    const int*   grf  = (const int*)  d_in[2];
    const float* Wz_w = (const float*)d_in[3];
    const float* Wz_b = (const float*)d_in[4];
    const float* Wr_w = (const float*)d_in[5];
    const float* Ur_w = (const float*)d_in[6];
    const float* Ur_b = (const float*)d_in[7];
    const float* Wh_w = (const float*)d_in[8];
    const float* Wh_b = (const float*)d_in[9];
    float* out = (float*)d_out;

    const size_t per  = (size_t)NM * HID;        // 8,000,000
    const size_t fsz  = (size_t)NBLK * 5120;     // frag-linear array ushorts
    ushort*  xr    = (ushort*)d_ws;                        // 16 MB
    ushort*  xzf   = xr + per;                             // 16 MB
    ushort*  xhf   = xzf + fsz;                            // 16 MB
    uint8_t* hh_a  = (uint8_t*)(xhf + fsz);                // 24 MB
    uint8_t* hh_b  = hh_a + (size_t)NM * HHROW;            // 24 MB
    ushort*  sumhf = (ushort*)(hh_b + (size_t)NM * HHROW); // 16 MB
    ushort*  sghf  = sumhf + fsz;                          // 16 MB
    ushort*  wpack = sghf + fsz;                           // 0.3 MB

    const dim3 gb64((NM + 63) / 64), gt(256);              // 782 blocks
    const dim3 zb(NBLK);                                   // 1563 blocks
    const dim3 sb(NM / 16), st(320);                       // 3125 blocks

    pack_weights<<<6, 256, 0, stream>>>(Wz_w, Wr_w, Ur_w, Wh_w, wpack);
    xproj_gemm<<<dim3(NBLK, 3), gt, 0, stream>>>(x, wpack, Wz_b, Wh_b, xr, xzf, xhf, NM);
    hU0_gemm<<<gb64, gt, 0, stream>>>(h0, wpack, Ur_b, hh_a, NM);

    gather_kernel<<<sb, st, 0, stream>>>(hh_a, xr, grf, sumhf, sghf);
    gemm_zh<<<zb, gt, 0, stream>>>(sumhf, sghf, xzf, xhf, wpack, Ur_b, out, hh_b, 0, 1, NM);
    gather_kernel<<<sb, st, 0, stream>>>(hh_b, xr, grf, sumhf, sghf);
    gemm_zh<<<zb, gt, 0, stream>>>(sumhf, sghf, xzf, xhf, wpack, Ur_b, out, hh_a, 0, 1, NM);
    gather_kernel<<<sb, st, 0, stream>>>(hh_a, xr, grf, sumhf, sghf);
    gemm_zh<<<zb, gt, 0, stream>>>(sumhf, sghf, xzf, xhf, wpack, Ur_b, out, hh_b, 1, 0, NM);
}

// Round 12
// 256.757 us; speedup vs baseline: 2.2743x; 1.1511x over previous
//
#include <hip/hip_runtime.h>
#include <hip/hip_fp16.h>
#include <cstddef>
#include <cstdint>

#define NM  50000
#define HID 160
#define NEI 8
#define AST 168     // padded LDS row stride (ushorts)
#define HHROW 512   // hh row bytes: 320 B bf16 h | 160 B e5m2 hU(-log2e scaled) | 32 pad
#define NBLK 1563   // ceil(50000/32) 32-row tiles

#define NEGL2E (-1.44269504f)

// packed-weight offsets (ushort units), bf16 hi-only
#define WPX   0        // [30nt][5ks][64l][8]: Wzx | Wr | Whx
#define WPU   76800    // Ur
#define WPZH  102400   // Wzh
#define WPHH  128000   // Whh

typedef __attribute__((ext_vector_type(8))) short  short8;
typedef __attribute__((ext_vector_type(4))) float  f32x4;
typedef __attribute__((ext_vector_type(2))) float  float2v;
typedef __attribute__((ext_vector_type(4))) ushort ushort4v;

__device__ __forceinline__ ushort f2bf(float f) {
    union { float f; uint32_t u; } v; v.f = f;
    const uint32_t r = v.u + 0x7fffu + ((v.u >> 16) & 1u);   // RNE
    return (ushort)(r >> 16);
}
__device__ __forceinline__ float bf2f(ushort h) {
    union { uint32_t u; float f; } v; v.u = ((uint32_t)h) << 16;
    return v.f;
}
// fp8 e5m2 == truncated f16 (OCP bf8)
__device__ __forceinline__ uint32_t f2e5(float v) {
    union { __half h; ushort u; } c; c.h = __float2half(v);
    const ushort r = c.u + 0x7F + ((c.u >> 8) & 1);
    return (uint32_t)(r >> 8) & 0xFF;
}
__device__ __forceinline__ float e5m2f(uint32_t byte) {
    union { ushort u; __half h; } c; c.u = (ushort)(byte << 8);
    return __half2float(c.h);
}

#if defined(__has_builtin)
#  if __has_builtin(__builtin_amdgcn_cvt_pk_f32_bf8)
#    define HAS_HW_BF8 1
#  else
#    define HAS_HW_BF8 0
#  endif
#  if __has_builtin(__builtin_amdgcn_exp2f)
#    define HEXP2(x) __builtin_amdgcn_exp2f(x)
#  else
#    define HEXP2(x) exp2f(x)
#  endif
#else
#  define HAS_HW_BF8 0
#  define HEXP2(x) exp2f(x)
#endif

__device__ __forceinline__ float rcpfa(float x) { return __builtin_amdgcn_rcpf(x); }

// decode 2 e5m2 bytes -> 2 f32; HW path is 1 VALU op
template<bool HI>
__device__ __forceinline__ float2v bf8pair(uint32_t w) {
#if HAS_HW_BF8
    return __builtin_amdgcn_cvt_pk_f32_bf8((int)w, HI);
#else
    const uint32_t sh = HI ? 16u : 0u;
    float2v r;
    r[0] = e5m2f((w >> sh) & 0xFFu);
    r[1] = e5m2f((w >> (sh + 8)) & 0xFFu);
    return r;
#endif
}

// fast gate math: v_exp + v_rcp (1 ulp class — fine inside sigmoid/tanh)
__device__ __forceinline__ float sigf(float v)     { return rcpfa(1.f + HEXP2(NEGL2E * v)); }
__device__ __forceinline__ float tanhfast(float v) { return 2.f * rcpfa(1.f + HEXP2(2.f * NEGL2E * v)) - 1.f; }

// A-frag-linear slot for element block (row n, cols [8*c8, 8*c8+8)), 32-row tiles
__device__ __forceinline__ size_t afrag_idx(int n, int c8) {
    const int tile = n >> 5, mrow = n & 31;
    const int wrow = mrow >> 4, q = c8 >> 2;
    const int lane = (mrow & 15) + ((c8 & 3) << 4);
    return (size_t)((tile * 2 + wrow) * 5 + q) * 64 + lane;
}

// ---------------- weight pre-pack into MFMA B-fragment-linear order (bf16 hi only)
__global__ __launch_bounds__(256) void pack_weights(
    const float* __restrict__ Wz, const float* __restrict__ Wr,
    const float* __restrict__ Ur, const float* __restrict__ Wh,
    ushort* __restrict__ dst)
{
    const float* src; int off, stride, ntb = 0; ushort* hi;
    switch (blockIdx.x) {
        case 0:  src = Wz; off = 0;   stride = 320; hi = dst + WPX;  ntb = 0;  break;
        case 1:  src = Wr; off = 0;   stride = 160; hi = dst + WPX;  ntb = 10; break;
        case 2:  src = Wh; off = 0;   stride = 320; hi = dst + WPX;  ntb = 20; break;
        case 3:  src = Ur; off = 0;   stride = 160; hi = dst + WPU;  break;
        case 4:  src = Wz; off = 160; stride = 320; hi = dst + WPZH; break;
        default: src = Wh; off = 160; stride = 320; hi = dst + WPHH; break;
    }
    const int t = threadIdx.x, l = t & 63;
    for (int tile = t >> 6; tile < 50; tile += 4) {
        const int ntl = tile / 5, ks = tile % 5;
        const int n = ntl * 16 + (l & 15);
        const int k = ks * 32 + (l >> 4) * 8;
        const float* s = &src[(size_t)n * stride + off + k];
        const size_t o = ((size_t)((ntb + ntl) * 5 + ks) * 64 + l) * 8;
        #pragma unroll
        for (int j = 0; j < 8; ++j) hi[o + j] = f2bf(s[j]);
    }
}

// ---------------- x projections, grid (NBLK, 3), 32-row tiles.
// cy==1 (xr) output is pre-scaled by -log2e (feeds only the gate sigmoid).
__global__ __launch_bounds__(256) void xproj_gemm(
    const float* __restrict__ x, const ushort* __restrict__ wpack,
    const float* __restrict__ Wz_b, const float* __restrict__ Wh_b,
    ushort* __restrict__ xr, ushort* __restrict__ xzf, ushort* __restrict__ xhf,
    int M)
{
    __shared__ ushort As[32 * AST];
    const int t = threadIdx.x, m0 = blockIdx.x * 32, cy = blockIdx.y;

    for (int idx = t; idx < 32 * 40; idx += 256) {
        const int m = idx / 40, k4 = (idx % 40) * 4;
        float4 v = make_float4(0.f, 0.f, 0.f, 0.f);
        if (m0 + m < M) v = *reinterpret_cast<const float4*>(&x[(size_t)(m0 + m) * HID + k4]);
        ushort4 hv;
        hv.x = f2bf(v.x); hv.y = f2bf(v.y); hv.z = f2bf(v.z); hv.w = f2bf(v.w);
        *reinterpret_cast<ushort4*>(&As[m * AST + k4]) = hv;
    }
    __syncthreads();

    const int w = t >> 6, l = t & 63;
    const int wrow = w & 1, wcol = w >> 1;
    const int ar = wrow * 16 + (l & 15);
    const int kg = (l >> 4) << 3;

    f32x4 acc[5];
    #pragma unroll
    for (int nt = 0; nt < 5; ++nt) acc[nt] = (f32x4){0.f, 0.f, 0.f, 0.f};

    const short8* WH = reinterpret_cast<const short8*>(wpack + WPX + cy * 25600);

    #pragma unroll
    for (int ks = 0; ks < 5; ++ks) {
        const short8 a = *reinterpret_cast<const short8*>(&As[ar * AST + ks * 32 + kg]);
        #pragma unroll
        for (int nt = 0; nt < 5; ++nt)
            acc[nt] = __builtin_amdgcn_mfma_f32_16x16x32_bf16(a, WH[(((wcol * 5 + nt) * 5 + ks) << 6) + l], acc[nt], 0, 0, 0);
    }

    const int r0l = wrow * 16 + ((l >> 4) << 2);
    const int cb = l & 15;

    if (cy == 1) {
        __syncthreads();
        #pragma unroll
        for (int nt = 0; nt < 5; ++nt) {
            const int col = (wcol * 5 + nt) * 16 + cb;
            #pragma unroll
            for (int r = 0; r < 4; ++r)
                As[(r0l + r) * AST + col] = f2bf(NEGL2E * acc[nt][r]);   // pre-scaled
        }
        __syncthreads();
        for (int idx = t; idx < 32 * 20; idx += 256) {
            const int m = idx / 20, g8 = (idx % 20) * 8;
            if (m0 + m < M)
                *reinterpret_cast<short8*>(&xr[(size_t)(m0 + m) * HID + g8]) =
                    *reinterpret_cast<const short8*>(&As[m * AST + g8]);
        }
    } else {
        const float* bias = (cy == 0) ? Wz_b : Wh_b;
        ushort* dst = (cy == 0) ? xzf : xhf;
        const size_t fragbase = ((size_t)blockIdx.x * 2 + wrow) * 2 + wcol;
        #pragma unroll
        for (int nt = 0; nt < 5; ++nt) {
            const float b = bias[(wcol * 5 + nt) * 16 + cb];
            ushort4v v;
            #pragma unroll
            for (int r = 0; r < 4; ++r) v[r] = f2bf(acc[nt][r] + b);
            *reinterpret_cast<ushort4v*>(&dst[((fragbase * 5 + nt) * 64 + l) * 4]) = v;
        }
    }
}

// ---------------- hU0: hh[n] = [bf16(h0) | e5m2(-log2e*(h0 @ Ur^T + Ur_b))]
__global__ __launch_bounds__(256, 3) void hU0_gemm(
    const float* __restrict__ h0, const ushort* __restrict__ wpack,
    const float* __restrict__ Ur_b, uint8_t* __restrict__ hh, int M)
{
    __shared__ ushort As[64 * AST];
    __shared__ uint8_t HuB[64 * 160];
    const int t = threadIdx.x, m0 = blockIdx.x * 64;

    for (int idx = t; idx < 64 * 40; idx += 256) {
        const int m = idx / 40, k4 = (idx % 40) * 4;
        float4 v = make_float4(0.f, 0.f, 0.f, 0.f);
        if (m0 + m < M) v = *reinterpret_cast<const float4*>(&h0[(size_t)(m0 + m) * HID + k4]);
        ushort4 hv;
        hv.x = f2bf(v.x); hv.y = f2bf(v.y); hv.z = f2bf(v.z); hv.w = f2bf(v.w);
        *reinterpret_cast<ushort4*>(&As[m * AST + k4]) = hv;
    }
    __syncthreads();

    for (int idx = t; idx < 64 * 20; idx += 256) {
        const int m = idx / 20, g8 = (idx % 20) * 8;
        if (m0 + m < M)
            *reinterpret_cast<short8*>(hh + (size_t)(m0 + m) * HHROW + g8 * 2) =
                *reinterpret_cast<const short8*>(&As[m * AST + g8]);
    }

    const int w = t >> 6, l = t & 63;
    const int ar = (w << 4) + (l & 15);
    const int kg = (l >> 4) << 3;

    f32x4 acc[10];
    #pragma unroll
    for (int nt = 0; nt < 10; ++nt) acc[nt] = (f32x4){0.f, 0.f, 0.f, 0.f};

    const short8* WH = reinterpret_cast<const short8*>(wpack + WPU);

    #pragma unroll
    for (int ks = 0; ks < 5; ++ks) {
        const short8 a = *reinterpret_cast<const short8*>(&As[ar * AST + ks * 32 + kg]);
        #pragma unroll
        for (int nt = 0; nt < 10; ++nt)
            acc[nt] = __builtin_amdgcn_mfma_f32_16x16x32_bf16(a, WH[(nt * 5 + ks) * 64 + l], acc[nt], 0, 0, 0);
    }

    const int r0l = (w << 4) + ((l >> 4) << 2);
    const int cb = l & 15;
    #pragma unroll
    for (int nt = 0; nt < 10; ++nt) {
        const int col = nt * 16 + cb;
        const float b = Ur_b[col];
        #pragma unroll
        for (int r = 0; r < 4; ++r)
            HuB[(r0l + r) * 160 + col] = (uint8_t)f2e5(NEGL2E * (acc[nt][r] + b));
    }
    __syncthreads();
    for (int idx = t; idx < 64 * 10; idx += 256) {
        const int m = idx / 10, g16 = (idx % 10) * 16;
        if (m0 + m < M)
            *reinterpret_cast<uint4*>(hh + (size_t)(m0 + m) * HHROW + 320 + g16) =
                *reinterpret_cast<const uint4*>(&HuB[m * 160 + g16]);
    }
}

// ---------------- standalone gather -> frag-linear sumh/sgh.
// sigmoid = v_rcp(1 + v_exp(t)) with t pre-scaled at the producers;
// accumulate in float2 vectors (v_pk_add/v_pk_fma).
__global__ __launch_bounds__(320, 2) void gather_kernel(
    const uint8_t* __restrict__ hh,     // [N][512B]: bf16 h | e5m2 hU(-log2e)
    const ushort* __restrict__ xr,      // [N][160] bf16, -log2e-scaled
    const int*    __restrict__ graph,
    ushort* __restrict__ sumhf,         // frag-linear bf16
    ushort* __restrict__ sghf)          // frag-linear bf16
{
    const int t = threadIdx.x;
    const int n = blockIdx.x * 16 + t / 20;     // 3125*16 == 50000 exactly
    const int c8 = t % 20, g8 = c8 * 8;

    const int4 ga = *reinterpret_cast<const int4*>(&graph[(size_t)n * NEI]);
    const int4 gb = *reinterpret_cast<const int4*>(&graph[(size_t)n * NEI + 4]);
    const int gi[8] = {ga.x, ga.y, ga.z, ga.w, gb.x, gb.y, gb.z, gb.w};

    const short8 xr8 = *reinterpret_cast<const short8*>(&xr[(size_t)n * HID + g8]);

    // issue all 16 gathered loads before any compute
    short8 hv[NEI]; uint2 hu[NEI];
    #pragma unroll
    for (int k = 0; k < NEI; ++k) {
        const uint8_t* row = hh + ((size_t)gi[k] << 9);   // HHROW=512 -> shift
        hv[k] = *reinterpret_cast<const short8*>(row + g8 * 2);
        hu[k] = *reinterpret_cast<const uint2*>(row + 320 + g8);
    }

    float2v xr2[4];
    {
        const uint32_t* xw = reinterpret_cast<const uint32_t*>(&xr8);
        #pragma unroll
        for (int i = 0; i < 4; ++i) {
            union { uint32_t u; float f; } a, b;
            a.u = xw[i] << 16;
            b.u = xw[i] & 0xFFFF0000u;
            xr2[i] = (float2v){a.f, b.f};
        }
    }

    float2v s2[4], g2[4];
    #pragma unroll
    for (int i = 0; i < 4; ++i) { s2[i] = (float2v){0.f, 0.f}; g2[i] = (float2v){0.f, 0.f}; }

    #pragma unroll
    for (int k = 0; k < NEI; ++k) {
        const uint32_t* hw = reinterpret_cast<const uint32_t*>(&hv[k]);
        float2v hu2[4];
        hu2[0] = bf8pair<false>(hu[k].x);
        hu2[1] = bf8pair<true >(hu[k].x);
        hu2[2] = bf8pair<false>(hu[k].y);
        hu2[3] = bf8pair<true >(hu[k].y);
        #pragma unroll
        for (int i = 0; i < 4; ++i) {
            union { uint32_t u; float f; } c0, c1;
            c0.u = hw[i] << 16;
            c1.u = hw[i] & 0xFFFF0000u;
            const float2v c = (float2v){c0.f, c1.f};
            const float2v tt = xr2[i] + hu2[i];                 // v_pk_add
            const float2v d  = (float2v){HEXP2(tt[0]), HEXP2(tt[1])} + (float2v){1.f, 1.f};
            const float2v r  = (float2v){rcpfa(d[0]), rcpfa(d[1])};
            s2[i] += c;                                         // v_pk_add
            g2[i] += r * c;                                     // v_pk_fma
        }
    }

    short8 sv, gv;
    #pragma unroll
    for (int i = 0; i < 4; ++i) {
        sv[2 * i]     = (short)f2bf(s2[i][0]);
        sv[2 * i + 1] = (short)f2bf(s2[i][1]);
        gv[2 * i]     = (short)f2bf(g2[i][0]);
        gv[2 * i + 1] = (short)f2bf(g2[i][1]);
    }
    const size_t fi = afrag_idx(n, c8);
    reinterpret_cast<short8*>(sumhf)[fi] = sv;
    reinterpret_cast<short8*>(sghf)[fi] = gv;
}

// ---------------- zh-GEMM + update (+ next-iter Ur tail), frag-direct A operands.
__global__ __launch_bounds__(256, 3) void gemm_zh(
    const ushort* __restrict__ sumhf, const ushort* __restrict__ sghf,
    const ushort* __restrict__ xzf, const ushort* __restrict__ xhf,
    const ushort* __restrict__ wpack, const float* __restrict__ Ur_b,
    float*   __restrict__ out,          // written only if write_out
    uint8_t* __restrict__ hh_next,      // written only if do_next
    int write_out, int do_next, int M)
{
    __shared__ ushort Az[32 * AST];     // tail only: h_out repack, then e5m2 bytes
    const int t = threadIdx.x, tile = blockIdx.x, m0 = tile * 32;
    const int w = t >> 6, l = t & 63;
    const int wrow = w & 1, wcol = w >> 1;

    // ---- issue ALL global reads up front (no barrier before MFMA) ----
    const size_t abase = (size_t)(tile * 2 + wrow) * 5 * 64 + l;
    const short8* SA = reinterpret_cast<const short8*>(sumhf);
    const short8* SG = reinterpret_cast<const short8*>(sghf);
    short8 az[5], ag[5];
    #pragma unroll
    for (int ks = 0; ks < 5; ++ks) {
        az[ks] = SA[abase + (size_t)ks * 64];
        ag[ks] = SG[abase + (size_t)ks * 64];
    }
    const size_t fragbase = ((size_t)tile * 2 + wrow) * 2 + wcol;
    ushort4v xz4[5], xh4[5];
    #pragma unroll
    for (int nt = 0; nt < 5; ++nt) {
        xz4[nt] = *reinterpret_cast<const ushort4v*>(&xzf[((fragbase * 5 + nt) * 64 + l) * 4]);
        xh4[nt] = *reinterpret_cast<const ushort4v*>(&xhf[((fragbase * 5 + nt) * 64 + l) * 4]);
    }

    // ---- identity B-frags for A->C transpose (one-hot bf16 1.0) ----
    const int hot0 = ((l >> 4) == ((l >> 3) & 1))     ? (l & 7) : -1;
    const int hot1 = ((l >> 4) == 2 + ((l >> 3) & 1)) ? (l & 7) : -1;
    short8 IF0, IF1;
    #pragma unroll
    for (int j = 0; j < 8; ++j) {
        IF0[j] = (short)((j == hot0) ? 0x3F80 : 0);
        IF1[j] = (short)((j == hot1) ? 0x3F80 : 0);
    }

    f32x4 accz[5], acch[5], accs[5];
    #pragma unroll
    for (int nt = 0; nt < 5; ++nt) {
        accz[nt] = (f32x4){0.f, 0.f, 0.f, 0.f};
        acch[nt] = (f32x4){0.f, 0.f, 0.f, 0.f};
        accs[nt] = (f32x4){0.f, 0.f, 0.f, 0.f};
    }

    {
        const short8* ZH = reinterpret_cast<const short8*>(wpack + WPZH);
        const short8* HHm = reinterpret_cast<const short8*>(wpack + WPHH);
        #pragma unroll
        for (int ks = 0; ks < 5; ++ks) {
            #pragma unroll
            for (int nt = 0; nt < 5; ++nt) {
                const int bi = (((wcol * 5 + nt) * 5 + ks) << 6) + l;
                accz[nt] = __builtin_amdgcn_mfma_f32_16x16x32_bf16(az[ks], ZH[bi], accz[nt], 0, 0, 0);
                acch[nt] = __builtin_amdgcn_mfma_f32_16x16x32_bf16(ag[ks], HHm[bi], acch[nt], 0, 0, 0);
            }
        }
        // sum_h -> C layout via identity (ct = wcol*5+nt; q=ct>>1, p=ct&1)
        if (wcol == 0) {
            accs[0] = __builtin_amdgcn_mfma_f32_16x16x32_bf16(az[0], IF0, accs[0], 0, 0, 0);
            accs[1] = __builtin_amdgcn_mfma_f32_16x16x32_bf16(az[0], IF1, accs[1], 0, 0, 0);
            accs[2] = __builtin_amdgcn_mfma_f32_16x16x32_bf16(az[1], IF0, accs[2], 0, 0, 0);
            accs[3] = __builtin_amdgcn_mfma_f32_16x16x32_bf16(az[1], IF1, accs[3], 0, 0, 0);
            accs[4] = __builtin_amdgcn_mfma_f32_16x16x32_bf16(az[2], IF0, accs[4], 0, 0, 0);
        } else {
            accs[0] = __builtin_amdgcn_mfma_f32_16x16x32_bf16(az[2], IF1, accs[0], 0, 0, 0);
            accs[1] = __builtin_amdgcn_mfma_f32_16x16x32_bf16(az[3], IF0, accs[1], 0, 0, 0);
            accs[2] = __builtin_amdgcn_mfma_f32_16x16x32_bf16(az[3], IF1, accs[2], 0, 0, 0);
            accs[3] = __builtin_amdgcn_mfma_f32_16x16x32_bf16(az[4], IF0, accs[3], 0, 0, 0);
            accs[4] = __builtin_amdgcn_mfma_f32_16x16x32_bf16(az[4], IF1, accs[4], 0, 0, 0);
        }
    }

    // ---- epilogue: v = (1-z)*sum_h + z*tanh(.) ----
    const int r0l = wrow * 16 + ((l >> 4) << 2);
    const int cb = l & 15;
    #pragma unroll
    for (int nt = 0; nt < 5; ++nt) {
        const int col = (wcol * 5 + nt) * 16 + cb;
        #pragma unroll
        for (int r = 0; r < 4; ++r) {
            const int m = m0 + r0l + r;
            float v = 0.f;
            if (m < M) {
                const float z = sigf(accz[nt][r] + bf2f(xz4[nt][r]));
                const float p = tanhfast(acch[nt][r] + bf2f(xh4[nt][r]));
                v = (1.f - z) * accs[nt][r] + z * p;
                if (m == 0) v = 0.f;
                if (write_out) out[(size_t)m * HID + col] = v;
            }
            accz[nt][r] = v;
        }
    }

    if (!do_next) return;

    // ---- tail: h_out -> row-major store + Ur-GEMM + e5m2 store ----
    #pragma unroll
    for (int nt = 0; nt < 5; ++nt) {
        const int col = (wcol * 5 + nt) * 16 + cb;
        #pragma unroll
        for (int r = 0; r < 4; ++r)
            Az[(r0l + r) * AST + col] = f2bf(accz[nt][r]);
    }
    __syncthreads();

    for (int idx = t; idx < 32 * 20; idx += 256) {
        const int m = idx / 20, g8 = (idx % 20) * 8;
        if (m0 + m < M)
            *reinterpret_cast<short8*>(hh_next + (size_t)(m0 + m) * HHROW + g8 * 2) =
                *reinterpret_cast<const short8*>(&Az[m * AST + g8]);
    }

    const int ar = wrow * 16 + (l & 15);
    const int kg = (l >> 4) << 3;
    #pragma unroll
    for (int nt = 0; nt < 5; ++nt) acch[nt] = (f32x4){0.f, 0.f, 0.f, 0.f};
    {
        const short8* WH = reinterpret_cast<const short8*>(wpack + WPU);
        #pragma unroll
        for (int ks = 0; ks < 5; ++ks) {
            const short8 a = *reinterpret_cast<const short8*>(&Az[ar * AST + ks * 32 + kg]);
            #pragma unroll
            for (int nt = 0; nt < 5; ++nt)
                acch[nt] = __builtin_amdgcn_mfma_f32_16x16x32_bf16(a, WH[(((wcol * 5 + nt) * 5 + ks) << 6) + l], acch[nt], 0, 0, 0);
        }
    }
    __syncthreads();   // all Az reads done; overlay byte buffer
    uint8_t* Agb = reinterpret_cast<uint8_t*>(Az);
    #pragma unroll
    for (int nt = 0; nt < 5; ++nt) {
        const int col = (wcol * 5 + nt) * 16 + cb;
        const float b = Ur_b[col];
        #pragma unroll
        for (int r = 0; r < 4; ++r)
            Agb[(r0l + r) * 160 + col] = (uint8_t)f2e5(NEGL2E * (acch[nt][r] + b));
    }
    __syncthreads();
    for (int idx = t; idx < 32 * 10; idx += 256) {
        const int m = idx / 10, g16 = (idx % 10) * 16;
        if (m0 + m < M)
            *reinterpret_cast<uint4*>(hh_next + (size_t)(m0 + m) * HHROW + 320 + g16) =
                *reinterpret_cast<const uint4*>(&Agb[m * 160 + g16]);
    }
}

extern "C" void kernel_launch(void* const* d_in, const int* in_sizes, int n_in,
                              void* d_out, int out_size, void* d_ws, size_t ws_size,
                              hipStream_t stream)
{
    const float* h0   = (const float*)d_in[0];
    const float* x    = (const float*)d_in[1];
    const int*   grf  = (const int*)  d_in[2];
    const float* Wz_w = (const float*)d_in[3];
    const float* Wz_b = (const float*)d_in[4];
    const float* Wr_w = (const float*)d_in[5];
    const float* Ur_w = (const float*)d_in[6];
    const float* Ur_b = (const float*)d_in[7];
    const float* Wh_w = (const float*)d_in[8];
    const float* Wh_b = (const float*)d_in[9];
    float* out = (float*)d_out;

    const size_t per  = (size_t)NM * HID;        // 8,000,000
    const size_t fsz  = (size_t)NBLK * 5120;     // frag-linear array ushorts
    ushort*  xr    = (ushort*)d_ws;                        // 16 MB
    ushort*  xzf   = xr + per;                             // 16 MB
    ushort*  xhf   = xzf + fsz;                            // 16 MB
    uint8_t* hh_a  = (uint8_t*)(xhf + fsz);                // 25.6 MB
    uint8_t* hh_b  = hh_a + (size_t)NM * HHROW;            // 25.6 MB
    ushort*  sumhf = (ushort*)(hh_b + (size_t)NM * HHROW); // 16 MB
    ushort*  sghf  = sumhf + fsz;                          // 16 MB
    ushort*  wpack = sghf + fsz;                           // 0.3 MB

    const dim3 gb64((NM + 63) / 64), gt(256);              // 782 blocks
    const dim3 zb(NBLK);                                   // 1563 blocks
    const dim3 sb(NM / 16), st(320);                       // 3125 blocks

    pack_weights<<<6, 256, 0, stream>>>(Wz_w, Wr_w, Ur_w, Wh_w, wpack);
    xproj_gemm<<<dim3(NBLK, 3), gt, 0, stream>>>(x, wpack, Wz_b, Wh_b, xr, xzf, xhf, NM);
    hU0_gemm<<<gb64, gt, 0, stream>>>(h0, wpack, Ur_b, hh_a, NM);

    gather_kernel<<<sb, st, 0, stream>>>(hh_a, xr, grf, sumhf, sghf);
    gemm_zh<<<zb, gt, 0, stream>>>(sumhf, sghf, xzf, xhf, wpack, Ur_b, out, hh_b, 0, 1, NM);
    gather_kernel<<<sb, st, 0, stream>>>(hh_b, xr, grf, sumhf, sghf);
    gemm_zh<<<zb, gt, 0, stream>>>(sumhf, sghf, xzf, xhf, wpack, Ur_b, out, hh_a, 0, 1, NM);
    gather_kernel<<<sb, st, 0, stream>>>(hh_a, xr, grf, sumhf, sghf);
    gemm_zh<<<zb, gt, 0, stream>>>(sumhf, sghf, xzf, xhf, wpack, Ur_b, out, hh_b, 1, 0, NM);
}

// Round 13
// 251.022 us; speedup vs baseline: 2.3262x; 1.0228x over previous
//
#include <hip/hip_runtime.h>
#include <hip/hip_fp16.h>
#include <cstddef>
#include <cstdint>

#define NM  50000
#define HID 160
#define NEI 8
#define AST 168     // padded LDS row stride (ushorts)
#define HHROW 512   // hh row bytes: 320 B bf16 h | 160 B e5m2 hU(-log2e scaled) | 32 pad
#define NBLK 1563   // ceil(50000/32) 32-row tiles

#define NEGL2E (-1.44269504f)

// packed-weight offsets (ushort units), bf16 hi-only
#define WPX   0        // [30nt][5ks][64l][8]: Wzx | Wr | Whx
#define WPU   76800    // Ur
#define WPZH  102400   // Wzh
#define WPHH  128000   // Whh

typedef __attribute__((ext_vector_type(8))) short  short8;
typedef __attribute__((ext_vector_type(4))) float  f32x4;
typedef __attribute__((ext_vector_type(2))) float  float2v;
typedef __attribute__((ext_vector_type(4))) ushort ushort4v;

__device__ __forceinline__ ushort f2bf(float f) {
    union { float f; uint32_t u; } v; v.f = f;
    const uint32_t r = v.u + 0x7fffu + ((v.u >> 16) & 1u);   // RNE
    return (ushort)(r >> 16);
}
__device__ __forceinline__ float bf2f(ushort h) {
    union { uint32_t u; float f; } v; v.u = ((uint32_t)h) << 16;
    return v.f;
}
// fp8 e5m2 == truncated f16 (OCP bf8)
__device__ __forceinline__ uint32_t f2e5(float v) {
    union { __half h; ushort u; } c; c.h = __float2half(v);
    const ushort r = c.u + 0x7F + ((c.u >> 8) & 1);
    return (uint32_t)(r >> 8) & 0xFF;
}
__device__ __forceinline__ float e5m2f(uint32_t byte) {
    union { ushort u; __half h; } c; c.u = (ushort)(byte << 8);
    return __half2float(c.h);
}

#if defined(__has_builtin)
#  if __has_builtin(__builtin_amdgcn_cvt_pk_f32_bf8)
#    define HAS_HW_BF8 1
#  else
#    define HAS_HW_BF8 0
#  endif
#  if __has_builtin(__builtin_amdgcn_exp2f)
#    define HEXP2(x) __builtin_amdgcn_exp2f(x)
#  else
#    define HEXP2(x) exp2f(x)
#  endif
#else
#  define HAS_HW_BF8 0
#  define HEXP2(x) exp2f(x)
#endif

__device__ __forceinline__ float rcpfa(float x) { return __builtin_amdgcn_rcpf(x); }

// decode 2 e5m2 bytes -> 2 f32; HW path is 1 VALU op
template<bool HI>
__device__ __forceinline__ float2v bf8pair(uint32_t w) {
#if HAS_HW_BF8
    return __builtin_amdgcn_cvt_pk_f32_bf8((int)w, HI);
#else
    const uint32_t sh = HI ? 16u : 0u;
    float2v r;
    r[0] = e5m2f((w >> sh) & 0xFFu);
    r[1] = e5m2f((w >> (sh + 8)) & 0xFFu);
    return r;
#endif
}

// fast gate math: v_exp + v_rcp (1 ulp class — fine inside sigmoid/tanh)
__device__ __forceinline__ float sigf(float v)     { return rcpfa(1.f + HEXP2(NEGL2E * v)); }
__device__ __forceinline__ float tanhfast(float v) { return 2.f * rcpfa(1.f + HEXP2(2.f * NEGL2E * v)) - 1.f; }

// A-frag-linear slot for element block (row n, cols [8*c8, 8*c8+8)), 32-row tiles
__device__ __forceinline__ size_t afrag_idx(int n, int c8) {
    const int tile = n >> 5, mrow = n & 31;
    const int wrow = mrow >> 4, q = c8 >> 2;
    const int lane = (mrow & 15) + ((c8 & 3) << 4);
    return (size_t)((tile * 2 + wrow) * 5 + q) * 64 + lane;
}

// ---------------- weight pre-pack into MFMA B-fragment-linear order (bf16 hi only)
__global__ __launch_bounds__(256) void pack_weights(
    const float* __restrict__ Wz, const float* __restrict__ Wr,
    const float* __restrict__ Ur, const float* __restrict__ Wh,
    ushort* __restrict__ dst)
{
    const float* src; int off, stride, ntb = 0; ushort* hi;
    switch (blockIdx.x) {
        case 0:  src = Wz; off = 0;   stride = 320; hi = dst + WPX;  ntb = 0;  break;
        case 1:  src = Wr; off = 0;   stride = 160; hi = dst + WPX;  ntb = 10; break;
        case 2:  src = Wh; off = 0;   stride = 320; hi = dst + WPX;  ntb = 20; break;
        case 3:  src = Ur; off = 0;   stride = 160; hi = dst + WPU;  break;
        case 4:  src = Wz; off = 160; stride = 320; hi = dst + WPZH; break;
        default: src = Wh; off = 160; stride = 320; hi = dst + WPHH; break;
    }
    const int t = threadIdx.x, l = t & 63;
    for (int tile = t >> 6; tile < 50; tile += 4) {
        const int ntl = tile / 5, ks = tile % 5;
        const int n = ntl * 16 + (l & 15);
        const int k = ks * 32 + (l >> 4) * 8;
        const float* s = &src[(size_t)n * stride + off + k];
        const size_t o = ((size_t)((ntb + ntl) * 5 + ks) * 64 + l) * 8;
        #pragma unroll
        for (int j = 0; j < 8; ++j) hi[o + j] = f2bf(s[j]);
    }
}

// ---------------- x projections, SINGLE pass: reads x once, emits all three.
// xz/xh -> C-frag-linear (+bias); xr -> row-major, pre-scaled by -log2e.
__global__ __launch_bounds__(256) void xproj_gemm(
    const float* __restrict__ x, const ushort* __restrict__ wpack,
    const float* __restrict__ Wz_b, const float* __restrict__ Wh_b,
    ushort* __restrict__ xr, ushort* __restrict__ xzf, ushort* __restrict__ xhf,
    int M)
{
    __shared__ ushort As[32 * AST];
    const int t = threadIdx.x, m0 = blockIdx.x * 32;

    for (int idx = t; idx < 32 * 40; idx += 256) {
        const int m = idx / 40, k4 = (idx % 40) * 4;
        float4 v = make_float4(0.f, 0.f, 0.f, 0.f);
        if (m0 + m < M) v = *reinterpret_cast<const float4*>(&x[(size_t)(m0 + m) * HID + k4]);
        ushort4 hv;
        hv.x = f2bf(v.x); hv.y = f2bf(v.y); hv.z = f2bf(v.z); hv.w = f2bf(v.w);
        *reinterpret_cast<ushort4*>(&As[m * AST + k4]) = hv;
    }
    __syncthreads();

    const int w = t >> 6, l = t & 63;
    const int wrow = w & 1, wcol = w >> 1;
    const int ar = wrow * 16 + (l & 15);
    const int kg = (l >> 4) << 3;

    f32x4 accz[5], accr[5], acch[5];
    #pragma unroll
    for (int nt = 0; nt < 5; ++nt) {
        accz[nt] = (f32x4){0.f, 0.f, 0.f, 0.f};
        accr[nt] = (f32x4){0.f, 0.f, 0.f, 0.f};
        acch[nt] = (f32x4){0.f, 0.f, 0.f, 0.f};
    }

    const short8* WZx = reinterpret_cast<const short8*>(wpack + WPX);
    const short8* WRx = reinterpret_cast<const short8*>(wpack + WPX + 25600);
    const short8* WHx = reinterpret_cast<const short8*>(wpack + WPX + 51200);

    #pragma unroll
    for (int ks = 0; ks < 5; ++ks) {
        const short8 a = *reinterpret_cast<const short8*>(&As[ar * AST + ks * 32 + kg]);
        #pragma unroll
        for (int nt = 0; nt < 5; ++nt) {
            const int bi = (((wcol * 5 + nt) * 5 + ks) << 6) + l;
            accz[nt] = __builtin_amdgcn_mfma_f32_16x16x32_bf16(a, WZx[bi], accz[nt], 0, 0, 0);
            accr[nt] = __builtin_amdgcn_mfma_f32_16x16x32_bf16(a, WRx[bi], accr[nt], 0, 0, 0);
            acch[nt] = __builtin_amdgcn_mfma_f32_16x16x32_bf16(a, WHx[bi], acch[nt], 0, 0, 0);
        }
    }

    const int r0l = wrow * 16 + ((l >> 4) << 2);
    const int cb = l & 15;
    const size_t fragbase = ((size_t)blockIdx.x * 2 + wrow) * 2 + wcol;

    // xz / xh: frag-direct stores (+bias)
    #pragma unroll
    for (int nt = 0; nt < 5; ++nt) {
        const int col = (wcol * 5 + nt) * 16 + cb;
        const float bz = Wz_b[col], bh = Wh_b[col];
        ushort4v vz, vh;
        #pragma unroll
        for (int r = 0; r < 4; ++r) {
            vz[r] = f2bf(accz[nt][r] + bz);
            vh[r] = f2bf(acch[nt][r] + bh);
        }
        *reinterpret_cast<ushort4v*>(&xzf[((fragbase * 5 + nt) * 64 + l) * 4]) = vz;
        *reinterpret_cast<ushort4v*>(&xhf[((fragbase * 5 + nt) * 64 + l) * 4]) = vh;
    }

    // xr: row-major via LDS repack, pre-scaled
    __syncthreads();
    #pragma unroll
    for (int nt = 0; nt < 5; ++nt) {
        const int col = (wcol * 5 + nt) * 16 + cb;
        #pragma unroll
        for (int r = 0; r < 4; ++r)
            As[(r0l + r) * AST + col] = f2bf(NEGL2E * accr[nt][r]);
    }
    __syncthreads();
    for (int idx = t; idx < 32 * 20; idx += 256) {
        const int m = idx / 20, g8 = (idx % 20) * 8;
        if (m0 + m < M)
            *reinterpret_cast<short8*>(&xr[(size_t)(m0 + m) * HID + g8]) =
                *reinterpret_cast<const short8*>(&As[m * AST + g8]);
    }
}

// ---------------- hU0: hh[n] = [bf16(h0) | e5m2(-log2e*(h0 @ Ur^T + Ur_b))]
// 32-row tiles, 6 blocks/CU.
__global__ __launch_bounds__(256, 6) void hU0_gemm(
    const float* __restrict__ h0, const ushort* __restrict__ wpack,
    const float* __restrict__ Ur_b, uint8_t* __restrict__ hh, int M)
{
    __shared__ ushort As[32 * AST];
    __shared__ uint8_t HuB[32 * 160];
    const int t = threadIdx.x, m0 = blockIdx.x * 32;

    for (int idx = t; idx < 32 * 40; idx += 256) {
        const int m = idx / 40, k4 = (idx % 40) * 4;
        float4 v = make_float4(0.f, 0.f, 0.f, 0.f);
        if (m0 + m < M) v = *reinterpret_cast<const float4*>(&h0[(size_t)(m0 + m) * HID + k4]);
        ushort4 hv;
        hv.x = f2bf(v.x); hv.y = f2bf(v.y); hv.z = f2bf(v.z); hv.w = f2bf(v.w);
        *reinterpret_cast<ushort4*>(&As[m * AST + k4]) = hv;
    }
    __syncthreads();

    for (int idx = t; idx < 32 * 20; idx += 256) {
        const int m = idx / 20, g8 = (idx % 20) * 8;
        if (m0 + m < M)
            *reinterpret_cast<short8*>(hh + (size_t)(m0 + m) * HHROW + g8 * 2) =
                *reinterpret_cast<const short8*>(&As[m * AST + g8]);
    }

    const int w = t >> 6, l = t & 63;
    const int wrow = w & 1, wcol = w >> 1;
    const int ar = wrow * 16 + (l & 15);
    const int kg = (l >> 4) << 3;

    f32x4 acc[5];
    #pragma unroll
    for (int nt = 0; nt < 5; ++nt) acc[nt] = (f32x4){0.f, 0.f, 0.f, 0.f};

    const short8* WH = reinterpret_cast<const short8*>(wpack + WPU);

    #pragma unroll
    for (int ks = 0; ks < 5; ++ks) {
        const short8 a = *reinterpret_cast<const short8*>(&As[ar * AST + ks * 32 + kg]);
        #pragma unroll
        for (int nt = 0; nt < 5; ++nt)
            acc[nt] = __builtin_amdgcn_mfma_f32_16x16x32_bf16(a, WH[(((wcol * 5 + nt) * 5 + ks) << 6) + l], acc[nt], 0, 0, 0);
    }

    const int r0l = wrow * 16 + ((l >> 4) << 2);
    const int cb = l & 15;
    #pragma unroll
    for (int nt = 0; nt < 5; ++nt) {
        const int col = (wcol * 5 + nt) * 16 + cb;
        const float b = Ur_b[col];
        #pragma unroll
        for (int r = 0; r < 4; ++r)
            HuB[(r0l + r) * 160 + col] = (uint8_t)f2e5(NEGL2E * (acc[nt][r] + b));
    }
    __syncthreads();
    for (int idx = t; idx < 32 * 10; idx += 256) {
        const int m = idx / 10, g16 = (idx % 10) * 16;
        if (m0 + m < M)
            *reinterpret_cast<uint4*>(hh + (size_t)(m0 + m) * HHROW + 320 + g16) =
                *reinterpret_cast<const uint4*>(&HuB[m * 160 + g16]);
    }
}

// ---------------- standalone gather -> frag-linear sumh/sgh.
__global__ __launch_bounds__(320, 2) void gather_kernel(
    const uint8_t* __restrict__ hh,     // [N][512B]: bf16 h | e5m2 hU(-log2e)
    const ushort* __restrict__ xr,      // [N][160] bf16, -log2e-scaled
    const int*    __restrict__ graph,
    ushort* __restrict__ sumhf,         // frag-linear bf16
    ushort* __restrict__ sghf)          // frag-linear bf16
{
    const int t = threadIdx.x;
    const int n = blockIdx.x * 16 + t / 20;     // 3125*16 == 50000 exactly
    const int c8 = t % 20, g8 = c8 * 8;

    const int4 ga = *reinterpret_cast<const int4*>(&graph[(size_t)n * NEI]);
    const int4 gb = *reinterpret_cast<const int4*>(&graph[(size_t)n * NEI + 4]);
    const int gi[8] = {ga.x, ga.y, ga.z, ga.w, gb.x, gb.y, gb.z, gb.w};

    const short8 xr8 = *reinterpret_cast<const short8*>(&xr[(size_t)n * HID + g8]);

    // issue all 16 gathered loads before any compute
    short8 hv[NEI]; uint2 hu[NEI];
    #pragma unroll
    for (int k = 0; k < NEI; ++k) {
        const uint8_t* row = hh + ((size_t)gi[k] << 9);   // HHROW=512 -> shift
        hv[k] = *reinterpret_cast<const short8*>(row + g8 * 2);
        hu[k] = *reinterpret_cast<const uint2*>(row + 320 + g8);
    }

    float2v xr2[4];
    {
        const uint32_t* xw = reinterpret_cast<const uint32_t*>(&xr8);
        #pragma unroll
        for (int i = 0; i < 4; ++i) {
            union { uint32_t u; float f; } a, b;
            a.u = xw[i] << 16;
            b.u = xw[i] & 0xFFFF0000u;
            xr2[i] = (float2v){a.f, b.f};
        }
    }

    float2v s2[4], g2[4];
    #pragma unroll
    for (int i = 0; i < 4; ++i) { s2[i] = (float2v){0.f, 0.f}; g2[i] = (float2v){0.f, 0.f}; }

    #pragma unroll
    for (int k = 0; k < NEI; ++k) {
        const uint32_t* hw = reinterpret_cast<const uint32_t*>(&hv[k]);
        float2v hu2[4];
        hu2[0] = bf8pair<false>(hu[k].x);
        hu2[1] = bf8pair<true >(hu[k].x);
        hu2[2] = bf8pair<false>(hu[k].y);
        hu2[3] = bf8pair<true >(hu[k].y);
        #pragma unroll
        for (int i = 0; i < 4; ++i) {
            union { uint32_t u; float f; } c0, c1;
            c0.u = hw[i] << 16;
            c1.u = hw[i] & 0xFFFF0000u;
            const float2v c = (float2v){c0.f, c1.f};
            const float2v tt = xr2[i] + hu2[i];                 // v_pk_add
            const float2v d  = (float2v){HEXP2(tt[0]), HEXP2(tt[1])} + (float2v){1.f, 1.f};
            const float2v r  = (float2v){rcpfa(d[0]), rcpfa(d[1])};
            s2[i] += c;                                         // v_pk_add
            g2[i] += r * c;                                     // v_pk_fma
        }
    }

    short8 sv, gv;
    #pragma unroll
    for (int i = 0; i < 4; ++i) {
        sv[2 * i]     = (short)f2bf(s2[i][0]);
        sv[2 * i + 1] = (short)f2bf(s2[i][1]);
        gv[2 * i]     = (short)f2bf(g2[i][0]);
        gv[2 * i + 1] = (short)f2bf(g2[i][1]);
    }
    const size_t fi = afrag_idx(n, c8);
    reinterpret_cast<short8*>(sumhf)[fi] = sv;
    reinterpret_cast<short8*>(sghf)[fi] = gv;
}

// ---------------- zh-GEMM + update (+ next-iter Ur tail), frag-direct A operands.
__global__ __launch_bounds__(256, 3) void gemm_zh(
    const ushort* __restrict__ sumhf, const ushort* __restrict__ sghf,
    const ushort* __restrict__ xzf, const ushort* __restrict__ xhf,
    const ushort* __restrict__ wpack, const float* __restrict__ Ur_b,
    float*   __restrict__ out,          // written only if write_out
    uint8_t* __restrict__ hh_next,      // written only if do_next
    int write_out, int do_next, int M)
{
    __shared__ ushort Az[32 * AST];     // tail only: h_out repack, then e5m2 bytes
    const int t = threadIdx.x, tile = blockIdx.x, m0 = tile * 32;
    const int w = t >> 6, l = t & 63;
    const int wrow = w & 1, wcol = w >> 1;

    // ---- issue ALL global reads up front (no barrier before MFMA) ----
    const size_t abase = (size_t)(tile * 2 + wrow) * 5 * 64 + l;
    const short8* SA = reinterpret_cast<const short8*>(sumhf);
    const short8* SG = reinterpret_cast<const short8*>(sghf);
    short8 az[5], ag[5];
    #pragma unroll
    for (int ks = 0; ks < 5; ++ks) {
        az[ks] = SA[abase + (size_t)ks * 64];
        ag[ks] = SG[abase + (size_t)ks * 64];
    }
    const size_t fragbase = ((size_t)tile * 2 + wrow) * 2 + wcol;
    ushort4v xz4[5], xh4[5];
    #pragma unroll
    for (int nt = 0; nt < 5; ++nt) {
        xz4[nt] = *reinterpret_cast<const ushort4v*>(&xzf[((fragbase * 5 + nt) * 64 + l) * 4]);
        xh4[nt] = *reinterpret_cast<const ushort4v*>(&xhf[((fragbase * 5 + nt) * 64 + l) * 4]);
    }

    // ---- identity B-frags for A->C transpose (one-hot bf16 1.0) ----
    const int hot0 = ((l >> 4) == ((l >> 3) & 1))     ? (l & 7) : -1;
    const int hot1 = ((l >> 4) == 2 + ((l >> 3) & 1)) ? (l & 7) : -1;
    short8 IF0, IF1;
    #pragma unroll
    for (int j = 0; j < 8; ++j) {
        IF0[j] = (short)((j == hot0) ? 0x3F80 : 0);
        IF1[j] = (short)((j == hot1) ? 0x3F80 : 0);
    }

    f32x4 accz[5], acch[5], accs[5];
    #pragma unroll
    for (int nt = 0; nt < 5; ++nt) {
        accz[nt] = (f32x4){0.f, 0.f, 0.f, 0.f};
        acch[nt] = (f32x4){0.f, 0.f, 0.f, 0.f};
        accs[nt] = (f32x4){0.f, 0.f, 0.f, 0.f};
    }

    {
        const short8* ZH = reinterpret_cast<const short8*>(wpack + WPZH);
        const short8* HHm = reinterpret_cast<const short8*>(wpack + WPHH);
        #pragma unroll
        for (int ks = 0; ks < 5; ++ks) {
            #pragma unroll
            for (int nt = 0; nt < 5; ++nt) {
                const int bi = (((wcol * 5 + nt) * 5 + ks) << 6) + l;
                accz[nt] = __builtin_amdgcn_mfma_f32_16x16x32_bf16(az[ks], ZH[bi], accz[nt], 0, 0, 0);
                acch[nt] = __builtin_amdgcn_mfma_f32_16x16x32_bf16(ag[ks], HHm[bi], acch[nt], 0, 0, 0);
            }
        }
        // sum_h -> C layout via identity (ct = wcol*5+nt; q=ct>>1, p=ct&1)
        if (wcol == 0) {
            accs[0] = __builtin_amdgcn_mfma_f32_16x16x32_bf16(az[0], IF0, accs[0], 0, 0, 0);
            accs[1] = __builtin_amdgcn_mfma_f32_16x16x32_bf16(az[0], IF1, accs[1], 0, 0, 0);
            accs[2] = __builtin_amdgcn_mfma_f32_16x16x32_bf16(az[1], IF0, accs[2], 0, 0, 0);
            accs[3] = __builtin_amdgcn_mfma_f32_16x16x32_bf16(az[1], IF1, accs[3], 0, 0, 0);
            accs[4] = __builtin_amdgcn_mfma_f32_16x16x32_bf16(az[2], IF0, accs[4], 0, 0, 0);
        } else {
            accs[0] = __builtin_amdgcn_mfma_f32_16x16x32_bf16(az[2], IF1, accs[0], 0, 0, 0);
            accs[1] = __builtin_amdgcn_mfma_f32_16x16x32_bf16(az[3], IF0, accs[1], 0, 0, 0);
            accs[2] = __builtin_amdgcn_mfma_f32_16x16x32_bf16(az[3], IF1, accs[2], 0, 0, 0);
            accs[3] = __builtin_amdgcn_mfma_f32_16x16x32_bf16(az[4], IF0, accs[3], 0, 0, 0);
            accs[4] = __builtin_amdgcn_mfma_f32_16x16x32_bf16(az[4], IF1, accs[4], 0, 0, 0);
        }
    }

    // ---- epilogue: v = (1-z)*sum_h + z*tanh(.) ----
    const int r0l = wrow * 16 + ((l >> 4) << 2);
    const int cb = l & 15;
    #pragma unroll
    for (int nt = 0; nt < 5; ++nt) {
        const int col = (wcol * 5 + nt) * 16 + cb;
        #pragma unroll
        for (int r = 0; r < 4; ++r) {
            const int m = m0 + r0l + r;
            float v = 0.f;
            if (m < M) {
                const float z = sigf(accz[nt][r] + bf2f(xz4[nt][r]));
                const float p = tanhfast(acch[nt][r] + bf2f(xh4[nt][r]));
                v = (1.f - z) * accs[nt][r] + z * p;
                if (m == 0) v = 0.f;
                if (write_out) out[(size_t)m * HID + col] = v;
            }
            accz[nt][r] = v;
        }
    }

    if (!do_next) return;

    // ---- tail: h_out -> row-major store + Ur-GEMM + e5m2 store ----
    #pragma unroll
    for (int nt = 0; nt < 5; ++nt) {
        const int col = (wcol * 5 + nt) * 16 + cb;
        #pragma unroll
        for (int r = 0; r < 4; ++r)
            Az[(r0l + r) * AST + col] = f2bf(accz[nt][r]);
    }
    __syncthreads();

    for (int idx = t; idx < 32 * 20; idx += 256) {
        const int m = idx / 20, g8 = (idx % 20) * 8;
        if (m0 + m < M)
            *reinterpret_cast<short8*>(hh_next + (size_t)(m0 + m) * HHROW + g8 * 2) =
                *reinterpret_cast<const short8*>(&Az[m * AST + g8]);
    }

    const int ar = wrow * 16 + (l & 15);
    const int kg = (l >> 4) << 3;
    #pragma unroll
    for (int nt = 0; nt < 5; ++nt) acch[nt] = (f32x4){0.f, 0.f, 0.f, 0.f};
    {
        const short8* WH = reinterpret_cast<const short8*>(wpack + WPU);
        #pragma unroll
        for (int ks = 0; ks < 5; ++ks) {
            const short8 a = *reinterpret_cast<const short8*>(&Az[ar * AST + ks * 32 + kg]);
            #pragma unroll
            for (int nt = 0; nt < 5; ++nt)
                acch[nt] = __builtin_amdgcn_mfma_f32_16x16x32_bf16(a, WH[(((wcol * 5 + nt) * 5 + ks) << 6) + l], acch[nt], 0, 0, 0);
        }
    }
    __syncthreads();   // all Az reads done; overlay byte buffer
    uint8_t* Agb = reinterpret_cast<uint8_t*>(Az);
    #pragma unroll
    for (int nt = 0; nt < 5; ++nt) {
        const int col = (wcol * 5 + nt) * 16 + cb;
        const float b = Ur_b[col];
        #pragma unroll
        for (int r = 0; r < 4; ++r)
            Agb[(r0l + r) * 160 + col] = (uint8_t)f2e5(NEGL2E * (acch[nt][r] + b));
    }
    __syncthreads();
    for (int idx = t; idx < 32 * 10; idx += 256) {
        const int m = idx / 10, g16 = (idx % 10) * 16;
        if (m0 + m < M)
            *reinterpret_cast<uint4*>(hh_next + (size_t)(m0 + m) * HHROW + 320 + g16) =
                *reinterpret_cast<const uint4*>(&Agb[m * 160 + g16]);
    }
}

extern "C" void kernel_launch(void* const* d_in, const int* in_sizes, int n_in,
                              void* d_out, int out_size, void* d_ws, size_t ws_size,
                              hipStream_t stream)
{
    const float* h0   = (const float*)d_in[0];
    const float* x    = (const float*)d_in[1];
    const int*   grf  = (const int*)  d_in[2];
    const float* Wz_w = (const float*)d_in[3];
    const float* Wz_b = (const float*)d_in[4];
    const float* Wr_w = (const float*)d_in[5];
    const float* Ur_w = (const float*)d_in[6];
    const float* Ur_b = (const float*)d_in[7];
    const float* Wh_w = (const float*)d_in[8];
    const float* Wh_b = (const float*)d_in[9];
    float* out = (float*)d_out;

    const size_t per  = (size_t)NM * HID;        // 8,000,000
    const size_t fsz  = (size_t)NBLK * 5120;     // frag-linear array ushorts
    ushort*  xr    = (ushort*)d_ws;                        // 16 MB
    ushort*  xzf   = xr + per;                             // 16 MB
    ushort*  xhf   = xzf + fsz;                            // 16 MB
    uint8_t* hh_a  = (uint8_t*)(xhf + fsz);                // 25.6 MB
    uint8_t* hh_b  = hh_a + (size_t)NM * HHROW;            // 25.6 MB
    ushort*  sumhf = (ushort*)(hh_b + (size_t)NM * HHROW); // 16 MB
    ushort*  sghf  = sumhf + fsz;                          // 16 MB
    ushort*  wpack = sghf + fsz;                           // 0.3 MB

    const dim3 zb(NBLK), gt(256);                          // 1563 blocks
    const dim3 sb(NM / 16), st(320);                       // 3125 blocks

    pack_weights<<<6, 256, 0, stream>>>(Wz_w, Wr_w, Ur_w, Wh_w, wpack);
    xproj_gemm<<<zb, gt, 0, stream>>>(x, wpack, Wz_b, Wh_b, xr, xzf, xhf, NM);
    hU0_gemm<<<zb, gt, 0, stream>>>(h0, wpack, Ur_b, hh_a, NM);

    gather_kernel<<<sb, st, 0, stream>>>(hh_a, xr, grf, sumhf, sghf);
    gemm_zh<<<zb, gt, 0, stream>>>(sumhf, sghf, xzf, xhf, wpack, Ur_b, out, hh_b, 0, 1, NM);
    gather_kernel<<<sb, st, 0, stream>>>(hh_b, xr, grf, sumhf, sghf);
    gemm_zh<<<zb, gt, 0, stream>>>(sumhf, sghf, xzf, xhf, wpack, Ur_b, out, hh_a, 0, 1, NM);
    gather_kernel<<<sb, st, 0, stream>>>(hh_a, xr, grf, sumhf, sghf);
    gemm_zh<<<zb, gt, 0, stream>>>(sumhf, sghf, xzf, xhf, wpack, Ur_b, out, hh_b, 1, 0, NM);
}